// Round 1
// baseline (4170.618 us; speedup 1.0000x reference)
//
#include <hip/hip_runtime.h>
#include <math.h>

// ---- constants from the reference ----
#define S_SAMPLES 447                      // int(norm([129]*3)/0.5)+1
#define ACT_SHIFT -9.210240366971207f      // log(1/(1-1e-4) - 1)
#define BN_SCALE_C 0.9999950000374997f     // (1+1e-5)^-0.5
#define STEP_VOX 0.015625f                 // STEPSIZE * VOXEL = 0.5 * (2/64)

// ============================================================================
// Kernel 1: fused grid_reg — conv1x1 chain 16->64->64->128 per voxel, BN+PReLU
// folded, pixel-shuffle scatter into channels-last feat (128^3,16) + density.
// ============================================================================
__global__ __launch_bounds__(256) void conv_kernel(
    const float* __restrict__ grid,
    const float* __restrict__ w1, const float* __restrict__ b1,
    const float* __restrict__ g1, const float* __restrict__ bb1, const float* __restrict__ a1,
    const float* __restrict__ w2, const float* __restrict__ b2,
    const float* __restrict__ g2, const float* __restrict__ bb2, const float* __restrict__ a2,
    const float* __restrict__ w3, const float* __restrict__ b3,
    float* __restrict__ feat, float* __restrict__ dens)
{
    const int v = blockIdx.x * 256 + threadIdx.x;     // 0..262143
    const int Z = v & 63, Y = (v >> 6) & 63, X = v >> 12;

    float g[16];
#pragma unroll
    for (int c = 0; c < 16; ++c) g[c] = grid[c * 262144 + v];

    float x1[64];
#pragma unroll
    for (int o = 0; o < 64; ++o) {
        float acc = b1[o];
#pragma unroll
        for (int c = 0; c < 16; ++c) acc = fmaf(w1[o * 16 + c], g[c], acc);
        acc = acc * (BN_SCALE_C * g1[o]) + bb1[o];
        x1[o] = (acc >= 0.0f) ? acc : a1[o] * acc;
    }

    float x2[64];
#pragma unroll
    for (int o = 0; o < 64; ++o) {
        float acc = b2[o];
#pragma unroll
        for (int c = 0; c < 64; ++c) acc = fmaf(w2[o * 80 + c], x1[c], acc);
#pragma unroll
        for (int c = 0; c < 16; ++c) acc = fmaf(w2[o * 80 + 64 + c], g[c], acc);
        acc = acc * (BN_SCALE_C * g2[o]) + bb2[o];
        x2[o] = (acc >= 0.0f) ? acc : a2[o] * acc;
    }

    // conv3 (128 out) + pixel shuffle: up[l, 2X+d2, 2Y+h2, 2Z+w2] = x3[l*8 + d2*4+h2*2+w2]
#pragma unroll 1
    for (int s = 0; s < 8; ++s) {
        const int d2 = (s >> 2) & 1, h2 = (s >> 1) & 1, w2i = s & 1;
        const int ux = 2 * X + d2, uy = 2 * Y + h2, uz = 2 * Z + w2i;
        const int ubase = (ux * 128 + uy) * 128 + uz;
        float x3s[16];
#pragma unroll
        for (int l = 0; l < 16; ++l) {
            const int o = l * 8 + s;
            float acc = b3[o];
#pragma unroll
            for (int c = 0; c < 64; ++c) acc = fmaf(w3[o * 144 + c], x1[c], acc);
#pragma unroll
            for (int c = 0; c < 64; ++c) acc = fmaf(w3[o * 144 + 64 + c], x2[c], acc);
#pragma unroll
            for (int c = 0; c < 16; ++c) acc = fmaf(w3[o * 144 + 128 + c], g[c], acc);
            x3s[l] = acc;
        }
        float* fp = feat + (size_t)ubase * 16;
        ((float4*)fp)[0] = make_float4(x3s[0],  x3s[1],  x3s[2],  x3s[3]);
        ((float4*)fp)[1] = make_float4(x3s[4],  x3s[5],  x3s[6],  x3s[7]);
        ((float4*)fp)[2] = make_float4(x3s[8],  x3s[9],  x3s[10], x3s[11]);
        ((float4*)fp)[3] = make_float4(x3s[12], x3s[13], x3s[14], x3s[15]);
        dens[ubase] = x3s[0];   // density channel (l=0) for the Sobel pass
    }
}

// ============================================================================
// Kernel 2: 5x5x5 Sobel (cross-correlation, zero pad) on density + normalize.
// normals = -sob / max(||sob||, 1e-12), channels-last (128^3, 3).
// ============================================================================
__global__ __launch_bounds__(256) void sobel_kernel(const float* __restrict__ dens,
                                                    float* __restrict__ normals)
{
    const int v = blockIdx.x * 256 + threadIdx.x;
    const int z = v & 127, y = (v >> 7) & 127, x = v >> 14;
    const float hw[5] = {1.f, 4.f, 6.f, 4.f, 1.f};
    const float hd[5] = {-1.f, -2.f, 0.f, 2.f, 1.f};
    float sx = 0.f, sy = 0.f, sz = 0.f;
#pragma unroll
    for (int i = 0; i < 5; ++i) {
        const int xx = x + i - 2;
        if (xx < 0 || xx > 127) continue;
#pragma unroll
        for (int j = 0; j < 5; ++j) {
            const int yy = y + j - 2;
            if (yy < 0 || yy > 127) continue;
            const float* row = dens + (xx * 128 + yy) * 128;
            float sh = 0.f, sd = 0.f;
#pragma unroll
            for (int k = 0; k < 5; ++k) {
                const int zz = z + k - 2;
                if (zz < 0 || zz > 127) continue;
                const float d = row[zz];
                sh = fmaf(hw[k], d, sh);
                sd = fmaf(hd[k], d, sd);
            }
            sx = fmaf(hd[i] * hw[j], sh, sx);
            sy = fmaf(hw[i] * hd[j], sh, sy);
            sz = fmaf(hw[i] * hw[j], sd, sz);
        }
    }
    sx *= (1.f / 72.f); sy *= (1.f / 72.f); sz *= (1.f / 72.f);
    const float n = sqrtf(sx * sx + sy * sy + sz * sz);
    const float inv = 1.f / fmaxf(n, 1e-12f);
    normals[v * 3 + 0] = -sx * inv;
    normals[v * 3 + 1] = -sy * inv;
    normals[v * 3 + 2] = -sz * inv;
}

// ============================================================================
// Kernel 3: per-sample — ray sampling, trilinear (16 ch) + analytic alpha grad,
// normals trilinear, reflection embedding, fully-unrolled MLP 54->64->64->64->3.
// Writes per-sample record: [alpha, rgb(3), nd(3), ns(3), depth, pad] (12 f32).
// ============================================================================
__global__ __launch_bounds__(256) void sample_kernel(
    const float* __restrict__ ro, const float* __restrict__ rd, const float* __restrict__ vd,
    const float* __restrict__ feat, const float* __restrict__ normals,
    const float* __restrict__ mw0, const float* __restrict__ mb0,
    const float* __restrict__ mw1, const float* __restrict__ mb1,
    const float* __restrict__ mw2, const float* __restrict__ mb2,
    const float* __restrict__ mw3, const float* __restrict__ mb3,
    float* __restrict__ sbuf)
{
    const int r = blockIdx.y;
    const int j = blockIdx.x * 256 + threadIdx.x;
    if (j >= S_SAMPLES) return;
    float* so = sbuf + ((size_t)r * S_SAMPLES + j) * 12;

    const float ox = ro[r * 3 + 0], oy = ro[r * 3 + 1], oz = ro[r * 3 + 2];
    const float dx = rd[r * 3 + 0], dy = rd[r * 3 + 1], dz = rd[r * 3 + 2];
    const float vx = vd[r * 3 + 0], vy = vd[r * 3 + 1], vz = vd[r * 3 + 2];

    const float vecx = (dx == 0.f) ? 1e-6f : dx;
    const float vecy = (dy == 0.f) ? 1e-6f : dy;
    const float vecz = (dz == 0.f) ? 1e-6f : dz;
    const float rax = (1.f - ox) / vecx, rbx = (-1.f - ox) / vecx;
    const float ray2 = (1.f - oy) / vecy, rby = (-1.f - oy) / vecy;
    const float raz = (1.f - oz) / vecz, rbz = (-1.f - oz) / vecz;
    float tmin = fmaxf(fmaxf(fminf(rax, rbx), fminf(ray2, rby)), fminf(raz, rbz));
    float tmax = fminf(fminf(fmaxf(rax, rbx), fmaxf(ray2, rby)), fmaxf(raz, rbz));
    tmin = fminf(fmaxf(tmin, 0.2f), 6.0f);
    tmax = fminf(fmaxf(tmax, 0.2f), 6.0f);
    const bool mask_ray = (tmax <= tmin);

    const float ndr = sqrtf(dx * dx + dy * dy + dz * dz);
    const float interpx = tmin + (STEP_VOX * (float)j) / ndr;
    const float px = ox + dx * interpx;
    const float py = oy + dy * interpx;
    const float pz = oz + dz * interpx;
    const bool outbox = mask_ray || (px < -1.f) || (px > 1.f) || (py < -1.f) ||
                        (py > 1.f) || (pz < -1.f) || (pz > 1.f);
    if (outbox) {
#pragma unroll
        for (int t = 0; t < 12; ++t) so[t] = 0.f;
        return;
    }

    const float ux = fminf(fmaxf((px + 1.f) * 63.5f, 0.f), 127.f);
    const float uy = fminf(fmaxf((py + 1.f) * 63.5f, 0.f), 127.f);
    const float uz = fminf(fmaxf((pz + 1.f) * 63.5f, 0.f), 127.f);
    const int ix = min(max((int)floorf(ux), 0), 126);
    const int iy = min(max((int)floorf(uy), 0), 126);
    const int iz = min(max((int)floorf(uz), 0), 126);
    const float fx = ux - (float)ix, fy = uy - (float)iy, fz = uz - (float)iz;

    float acc[16];
#pragma unroll
    for (int t = 0; t < 16; ++t) acc[t] = 0.f;
    float na0 = 0.f, na1 = 0.f, na2 = 0.f;
    float c0v[8];
#pragma unroll
    for (int cn = 0; cn < 8; ++cn) {
        const int adx = cn >> 2, ady = (cn >> 1) & 1, adz = cn & 1;
        const int vox = ((ix + adx) * 128 + (iy + ady)) * 128 + (iz + adz);
        const float w = (adx ? fx : 1.f - fx) * (ady ? fy : 1.f - fy) * (adz ? fz : 1.f - fz);
        const float4* cp = (const float4*)(feat + (size_t)vox * 16);
        const float4 q0 = cp[0], q1 = cp[1], q2 = cp[2], q3 = cp[3];
        c0v[cn] = q0.x;
        acc[0]  = fmaf(w, q0.x, acc[0]);  acc[1]  = fmaf(w, q0.y, acc[1]);
        acc[2]  = fmaf(w, q0.z, acc[2]);  acc[3]  = fmaf(w, q0.w, acc[3]);
        acc[4]  = fmaf(w, q1.x, acc[4]);  acc[5]  = fmaf(w, q1.y, acc[5]);
        acc[6]  = fmaf(w, q1.z, acc[6]);  acc[7]  = fmaf(w, q1.w, acc[7]);
        acc[8]  = fmaf(w, q2.x, acc[8]);  acc[9]  = fmaf(w, q2.y, acc[9]);
        acc[10] = fmaf(w, q2.z, acc[10]); acc[11] = fmaf(w, q2.w, acc[11]);
        acc[12] = fmaf(w, q3.x, acc[12]); acc[13] = fmaf(w, q3.y, acc[13]);
        acc[14] = fmaf(w, q3.z, acc[14]); acc[15] = fmaf(w, q3.w, acc[15]);
        const float* np_ = normals + (size_t)vox * 3;
        na0 = fmaf(w, np_[0], na0);
        na1 = fmaf(w, np_[1], na1);
        na2 = fmaf(w, np_[2], na2);
    }

    // channel-0 trilinear (nested lerp, matches ref) + gradient wrt (fx,fy,fz)
    const float c00 = c0v[0] * (1.f - fz) + c0v[1] * fz;
    const float c01 = c0v[2] * (1.f - fz) + c0v[3] * fz;
    const float c10 = c0v[4] * (1.f - fz) + c0v[5] * fz;
    const float c11 = c0v[6] * (1.f - fz) + c0v[7] * fz;
    const float e0 = c00 * (1.f - fy) + c01 * fy;
    const float e1 = c10 * (1.f - fy) + c11 * fy;
    const float d0 = e0 * (1.f - fx) + e1 * fx;
    const float dfx = e1 - e0;
    const float dfy = (c01 - c00) * (1.f - fx) + (c11 - c10) * fx;
    const float dfz = ((c0v[1] - c0v[0]) * (1.f - fy) + (c0v[3] - c0v[2]) * fy) * (1.f - fx)
                    + ((c0v[5] - c0v[4]) * (1.f - fy) + (c0v[7] - c0v[6]) * fy) * fx;

    // alpha = 1 - exp(-softplus(d0+shift)*0.5); softplus = logaddexp(x,0)
    const float zin = d0 + ACT_SHIFT;
    const float splus = fmaxf(zin, 0.f) + log1pf(expf(-fabsf(zin)));
    const float e = expf(-splus * 0.5f);
    const float alpha = 1.f - e;
    const float sig = 1.f / (1.f + expf(-zin));
    const float dad = e * 0.5f * sig;        // dalpha/dd0
    const float gx = dad * dfx * 63.5f;      // du/dp = (UP-1)/2
    const float gy = dad * dfy * 63.5f;
    const float gz = dad * dfz * 63.5f;
    const float gn = sqrtf(gx * gx + gy * gy + gz * gz);
    const float gi = 1.f / fmaxf(gn, 1e-12f);
    const float ndx = -gx * gi, ndy = -gy * gi, ndz = -gz * gi;

    const float nn = sqrtf(na0 * na0 + na1 * na1 + na2 * na2);
    const float ni = 1.f / fmaxf(nn, 1e-12f);
    const float nsx = -na0 * ni, nsy = -na1 * ni, nsz = -na2 * ni;

    const float dotv = -(vx * ndx + vy * ndy + vz * ndz);
    const float rx = 2.f * dotv * ndx + vx;
    const float ry = 2.f * dotv * ndy + vy;
    const float rz = 2.f * dotv * ndz + vz;

    float hf[54];
#pragma unroll
    for (int t = 0; t < 15; ++t) hf[t] = acc[t + 1];
    hf[15] = rx; hf[16] = ry; hf[17] = rz;
#pragma unroll
    for (int fi = 0; fi < 6; ++fi) {
        const float fr = (float)(1 << fi);
        hf[18 + fi * 6 + 0] = sinf(rx * fr);
        hf[18 + fi * 6 + 1] = sinf(ry * fr);
        hf[18 + fi * 6 + 2] = sinf(rz * fr);
        hf[18 + fi * 6 + 3] = cosf(rx * fr);
        hf[18 + fi * 6 + 4] = cosf(ry * fr);
        hf[18 + fi * 6 + 5] = cosf(rz * fr);
    }

    float h1[64];
#pragma unroll
    for (int o = 0; o < 64; ++o) {
        float a = mb0[o];
#pragma unroll
        for (int c = 0; c < 54; ++c) a = fmaf(hf[c], mw0[c * 64 + o], a);
        h1[o] = fmaxf(a, 0.f);
    }
    float h2[64];
#pragma unroll
    for (int o = 0; o < 64; ++o) {
        float a = mb1[o];
#pragma unroll
        for (int c = 0; c < 64; ++c) a = fmaf(h1[c], mw1[c * 64 + o], a);
        h2[o] = fmaxf(a, 0.f);
    }
    float h3[64];
#pragma unroll
    for (int o = 0; o < 64; ++o) {
        float a = mb2[o];
#pragma unroll
        for (int c = 0; c < 64; ++c) a = fmaf(h2[c], mw2[c * 64 + o], a);
        h3[o] = fmaxf(a, 0.f);
    }
    float rgb[3];
#pragma unroll
    for (int o = 0; o < 3; ++o) {
        float a = mb3[o];
#pragma unroll
        for (int c = 0; c < 64; ++c) a = fmaf(h3[c], mw3[c * 3 + o], a);
        rgb[o] = 1.f / (1.f + expf(-a));
    }

    so[0] = alpha;
    so[1] = rgb[0]; so[2] = rgb[1]; so[3] = rgb[2];
    so[4] = ndx; so[5] = ndy; so[6] = ndz;
    so[7] = nsx; so[8] = nsy; so[9] = nsz;
    so[10] = interpx * ndr;   // depth = ||rays_o - pts||
    so[11] = 0.f;
}

// ============================================================================
// Kernel 4: per-ray compositing. One wave per ray; segmented transmittance
// scan via __shfl_up, then weighted reduce of rgb/depth/acc/nm/sm.
// ============================================================================
__global__ __launch_bounds__(64) void reduce_kernel(const float* __restrict__ sbuf,
                                                    float* __restrict__ out)
{
    const int r = blockIdx.x;
    const int lane = threadIdx.x;
    const int per = (S_SAMPLES + 63) / 64;   // 7
    const int j0 = lane * per;
    const int j1 = min(S_SAMPLES, j0 + per);

    float p = 1.f;
    for (int j = j0; j < j1; ++j) {
        const float a = sbuf[((size_t)r * S_SAMPLES + j) * 12];
        p *= fmaxf(1.f - a, 1e-10f);
    }
    float scan = p;
#pragma unroll
    for (int off = 1; off < 64; off <<= 1) {
        const float nv = __shfl_up(scan, (unsigned)off, 64);
        if (lane >= off) scan *= nv;
    }
    const float total = __shfl(scan, 63, 64);
    float pref = __shfl_up(scan, 1u, 64);
    if (lane == 0) pref = 1.f;

    float s0 = 0, s1 = 0, s2 = 0, s3 = 0, s4 = 0, s5 = 0, s6 = 0, s7 = 0, s8 = 0, s9 = 0, s10 = 0;
    for (int j = j0; j < j1; ++j) {
        const float* sp_ = sbuf + ((size_t)r * S_SAMPLES + j) * 12;
        const float a = sp_[0];
        const float w = a * pref;
        pref *= fmaxf(1.f - a, 1e-10f);
        s0 = fmaf(w, sp_[1], s0);
        s1 = fmaf(w, sp_[2], s1);
        s2 = fmaf(w, sp_[3], s2);
        s3 = fmaf(w, sp_[10], s3);
        s4 += w;
        s5 = fmaf(w, sp_[4], s5);
        s6 = fmaf(w, sp_[5], s6);
        s7 = fmaf(w, sp_[6], s7);
        s8 = fmaf(w, sp_[7], s8);
        s9 = fmaf(w, sp_[8], s9);
        s10 = fmaf(w, sp_[9], s10);
    }
#pragma unroll
    for (int m = 32; m >= 1; m >>= 1) {
        s0 += __shfl_xor(s0, m, 64);
        s1 += __shfl_xor(s1, m, 64);
        s2 += __shfl_xor(s2, m, 64);
        s3 += __shfl_xor(s3, m, 64);
        s4 += __shfl_xor(s4, m, 64);
        s5 += __shfl_xor(s5, m, 64);
        s6 += __shfl_xor(s6, m, 64);
        s7 += __shfl_xor(s7, m, 64);
        s8 += __shfl_xor(s8, m, 64);
        s9 += __shfl_xor(s9, m, 64);
        s10 += __shfl_xor(s10, m, 64);
    }
    if (lane == 0) {
        const float dm = s3 + total * 6.0f;        // + alphainv_last * FAR
        out[r * 12 + 0] = s0 + total;              // + alphainv_last * BG
        out[r * 12 + 1] = s1 + total;
        out[r * 12 + 2] = s2 + total;
        out[r * 12 + 3] = dm;
        out[r * 12 + 4] = 1.f / dm;
        out[r * 12 + 5] = s4;
        out[r * 12 + 6] = s5; out[r * 12 + 7] = s6; out[r * 12 + 8] = s7;
        out[r * 12 + 9] = s8; out[r * 12 + 10] = s9; out[r * 12 + 11] = s10;
    }
}

// ============================================================================
extern "C" void kernel_launch(void* const* d_in, const int* in_sizes, int n_in,
                              void* d_out, int out_size, void* d_ws, size_t ws_size,
                              hipStream_t stream)
{
    (void)n_in; (void)out_size; (void)ws_size;
    const float* rays_o   = (const float*)d_in[0];
    const float* rays_d   = (const float*)d_in[1];
    const float* viewdirs = (const float*)d_in[2];
    const float* grid     = (const float*)d_in[3];
    const float* c1_w  = (const float*)d_in[4];
    const float* c1_b  = (const float*)d_in[5];
    const float* bn1_g = (const float*)d_in[6];
    const float* bn1_b = (const float*)d_in[7];
    const float* pr1_a = (const float*)d_in[8];
    const float* c2_w  = (const float*)d_in[9];
    const float* c2_b  = (const float*)d_in[10];
    const float* bn2_g = (const float*)d_in[11];
    const float* bn2_b = (const float*)d_in[12];
    const float* pr2_a = (const float*)d_in[13];
    const float* c3_w  = (const float*)d_in[14];
    const float* c3_b  = (const float*)d_in[15];
    const float* mw0 = (const float*)d_in[16];
    const float* mb0 = (const float*)d_in[17];
    const float* mw1 = (const float*)d_in[18];
    const float* mb1 = (const float*)d_in[19];
    const float* mw2 = (const float*)d_in[20];
    const float* mb2 = (const float*)d_in[21];
    const float* mw3 = (const float*)d_in[22];
    const float* mb3 = (const float*)d_in[23];

    const int N = in_sizes[0] / 3;   // 1024 rays

    // ws layout (floats): feat 33,554,432 | dens 2,097,152 | normals 6,291,456 |
    // sbuf N*447*12  -> total ~181 MiB
    float* wsf     = (float*)d_ws;
    float* feat    = wsf;
    float* dens    = wsf + (size_t)33554432;
    float* normals = wsf + (size_t)35651584;
    float* sbuf    = wsf + (size_t)41943040;

    conv_kernel<<<1024, 256, 0, stream>>>(grid, c1_w, c1_b, bn1_g, bn1_b, pr1_a,
                                          c2_w, c2_b, bn2_g, bn2_b, pr2_a,
                                          c3_w, c3_b, feat, dens);
    sobel_kernel<<<8192, 256, 0, stream>>>(dens, normals);
    dim3 sg((S_SAMPLES + 255) / 256, N, 1);
    sample_kernel<<<sg, 256, 0, stream>>>(rays_o, rays_d, viewdirs, feat, normals,
                                          mw0, mb0, mw1, mb1, mw2, mb2, mw3, mb3, sbuf);
    reduce_kernel<<<N, 64, 0, stream>>>(sbuf, (float*)d_out);
}

// Round 2
// 1713.963 us; speedup vs baseline: 2.4333x; 2.4333x over previous
//
#include <hip/hip_runtime.h>
#include <math.h>

// ---- constants from the reference ----
#define S_SAMPLES 447                      // int(norm([129]*3)/0.5)+1
#define ACT_SHIFT -9.210240366971207f      // log(1/(1-1e-4) - 1)
#define BN_SCALE_C 0.9999950000374997f     // (1+1e-5)^-0.5
#define STEP_VOX 0.015625f                 // STEPSIZE * VOXEL = 0.5 * (2/64)

__device__ __forceinline__ unsigned short f2bf(float f) {
    unsigned u = __float_as_uint(f);
    unsigned r = (u + 0x7fffu + ((u >> 16) & 1u)) >> 16;   // RNE
    return (unsigned short)r;
}
__device__ __forceinline__ float bf2f(unsigned short u) {
    return __uint_as_float(((unsigned)u) << 16);
}

// ============================================================================
// Kernel 1a: conv1 (16->64) + conv2 (80->64) per voxel; BN+PReLU folded.
// Writes x2 (64 ch, channels-last fp32). x1 is recomputed in conv3 (cheap).
// Output-channel loop for conv2 is ROLLED with wave-uniform dynamic weight-row
// bases (s_load w/ SGPR offset) to keep code size I$-resident.
// ============================================================================
__global__ __launch_bounds__(256) void conv12_kernel(
    const float* __restrict__ grid,
    const float* __restrict__ w1, const float* __restrict__ b1,
    const float* __restrict__ g1, const float* __restrict__ bb1, const float* __restrict__ a1,
    const float* __restrict__ w2, const float* __restrict__ b2,
    const float* __restrict__ g2, const float* __restrict__ bb2, const float* __restrict__ a2,
    float* __restrict__ x2buf)
{
    const int v = blockIdx.x * 256 + threadIdx.x;     // 0..262143

    float g[16];
#pragma unroll
    for (int c = 0; c < 16; ++c) g[c] = grid[c * 262144 + v];

    float x1[64];
#pragma unroll
    for (int o = 0; o < 64; ++o) {                    // unrolled: x1[o] needs literal idx
        float acc = b1[o];
#pragma unroll
        for (int c = 0; c < 16; ++c) acc = fmaf(w1[o * 16 + c], g[c], acc);
        acc = acc * (BN_SCALE_C * g1[o]) + bb1[o];
        x1[o] = (acc >= 0.0f) ? acc : a1[o] * acc;
    }

    float* outp = x2buf + (size_t)v * 64;
#pragma unroll 1
    for (int og = 0; og < 16; ++og) {                 // rolled, o wave-uniform dynamic
        float a4[4];
#pragma unroll
        for (int i = 0; i < 4; ++i) {
            const int o = og * 4 + i;
            const float* wrow = w2 + o * 80;
            float acc = b2[o];
#pragma unroll
            for (int c = 0; c < 64; ++c) acc = fmaf(wrow[c], x1[c], acc);
#pragma unroll
            for (int c = 0; c < 16; ++c) acc = fmaf(wrow[64 + c], g[c], acc);
            acc = acc * (BN_SCALE_C * g2[o]) + bb2[o];
            a4[i] = (acc >= 0.0f) ? acc : a2[o] * acc;
        }
        ((float4*)outp)[og] = make_float4(a4[0], a4[1], a4[2], a4[3]);
    }
}

// ============================================================================
// Kernel 1b: conv3 (144->128) per voxel + pixel-shuffle scatter.
// x1 recomputed from g; x2 read back. Output loop rolled (uniform dyn bases).
// feat stored bf16 channels-last (128^3,16); density (l=0) kept fp32.
// ============================================================================
__global__ __launch_bounds__(256) void conv3_kernel(
    const float* __restrict__ grid,
    const float* __restrict__ w1, const float* __restrict__ b1,
    const float* __restrict__ g1, const float* __restrict__ bb1, const float* __restrict__ a1,
    const float* __restrict__ x2buf,
    const float* __restrict__ w3, const float* __restrict__ b3,
    unsigned short* __restrict__ featb, float* __restrict__ dens)
{
    const int v = blockIdx.x * 256 + threadIdx.x;
    const int Z = v & 63, Y = (v >> 6) & 63, X = v >> 12;

    float g[16];
#pragma unroll
    for (int c = 0; c < 16; ++c) g[c] = grid[c * 262144 + v];

    float x1[64];
#pragma unroll
    for (int o = 0; o < 64; ++o) {
        float acc = b1[o];
#pragma unroll
        for (int c = 0; c < 16; ++c) acc = fmaf(w1[o * 16 + c], g[c], acc);
        acc = acc * (BN_SCALE_C * g1[o]) + bb1[o];
        x1[o] = (acc >= 0.0f) ? acc : a1[o] * acc;
    }

    float x2[64];
    const float4* xp = (const float4*)(x2buf + (size_t)v * 64);
#pragma unroll
    for (int q = 0; q < 16; ++q) {
        const float4 t = xp[q];
        x2[q * 4 + 0] = t.x; x2[q * 4 + 1] = t.y; x2[q * 4 + 2] = t.z; x2[q * 4 + 3] = t.w;
    }

#pragma unroll 1
    for (int s = 0; s < 8; ++s) {
        const int d2 = (s >> 2) & 1, h2 = (s >> 1) & 1, w2i = s & 1;
        const int ubase = ((2 * X + d2) * 128 + (2 * Y + h2)) * 128 + (2 * Z + w2i);
        unsigned short* fp = featb + (size_t)ubase * 16;
#pragma unroll 1
        for (int lq = 0; lq < 4; ++lq) {
            float a4[4];
#pragma unroll
            for (int i = 0; i < 4; ++i) {
                const int o = (lq * 4 + i) * 8 + s;   // wave-uniform dynamic
                const float* wrow = w3 + o * 144;
                float acc = b3[o];
#pragma unroll
                for (int k = 0; k < 64; ++k) acc = fmaf(wrow[k], x1[k], acc);
#pragma unroll
                for (int k = 0; k < 64; ++k) acc = fmaf(wrow[64 + k], x2[k], acc);
#pragma unroll
                for (int k = 0; k < 16; ++k) acc = fmaf(wrow[128 + k], g[k], acc);
                a4[i] = acc;
            }
            uint2 st;
            st.x = (unsigned)f2bf(a4[0]) | ((unsigned)f2bf(a4[1]) << 16);
            st.y = (unsigned)f2bf(a4[2]) | ((unsigned)f2bf(a4[3]) << 16);
            *(uint2*)(fp + lq * 4) = st;
            if (lq == 0) dens[ubase] = a4[0];         // l=0 density, fp32 exact
        }
    }
}

// ============================================================================
// Kernel 2: 5x5x5 Sobel (zero pad) on fp32 density + normalize.
// ============================================================================
__global__ __launch_bounds__(256) void sobel_kernel(const float* __restrict__ dens,
                                                    float* __restrict__ normals)
{
    const int v = blockIdx.x * 256 + threadIdx.x;
    const int z = v & 127, y = (v >> 7) & 127, x = v >> 14;
    const float hw[5] = {1.f, 4.f, 6.f, 4.f, 1.f};
    const float hd[5] = {-1.f, -2.f, 0.f, 2.f, 1.f};
    float sx = 0.f, sy = 0.f, sz = 0.f;
#pragma unroll
    for (int i = 0; i < 5; ++i) {
        const int xx = x + i - 2;
        if (xx < 0 || xx > 127) continue;
#pragma unroll
        for (int j = 0; j < 5; ++j) {
            const int yy = y + j - 2;
            if (yy < 0 || yy > 127) continue;
            const float* row = dens + (xx * 128 + yy) * 128;
            float sh = 0.f, sd = 0.f;
#pragma unroll
            for (int k = 0; k < 5; ++k) {
                const int zz = z + k - 2;
                if (zz < 0 || zz > 127) continue;
                const float d = row[zz];
                sh = fmaf(hw[k], d, sh);
                sd = fmaf(hd[k], d, sd);
            }
            sx = fmaf(hd[i] * hw[j], sh, sx);
            sy = fmaf(hw[i] * hd[j], sh, sy);
            sz = fmaf(hw[i] * hw[j], sd, sz);
        }
    }
    sx *= (1.f / 72.f); sy *= (1.f / 72.f); sz *= (1.f / 72.f);
    const float n = sqrtf(sx * sx + sy * sy + sz * sz);
    const float inv = 1.f / fmaxf(n, 1e-12f);
    normals[v * 3 + 0] = -sx * inv;
    normals[v * 3 + 1] = -sy * inv;
    normals[v * 3 + 2] = -sz * inv;
}

// ============================================================================
// Kernel 3: per-sample shading. Density/gradient from fp32 dens, latent from
// bf16 feat, normals trilinear, reflection embedding (fast __sinf/__cosf),
// unrolled MLP 54->64->64->64->3. Record: [alpha,rgb3,nd3,ns3,depth,pad].
// ============================================================================
__global__ __launch_bounds__(256) void sample_kernel(
    const float* __restrict__ ro, const float* __restrict__ rd, const float* __restrict__ vd,
    const unsigned short* __restrict__ featb, const float* __restrict__ dens,
    const float* __restrict__ normals,
    const float* __restrict__ mw0, const float* __restrict__ mb0,
    const float* __restrict__ mw1, const float* __restrict__ mb1,
    const float* __restrict__ mw2, const float* __restrict__ mb2,
    const float* __restrict__ mw3, const float* __restrict__ mb3,
    float* __restrict__ sbuf)
{
    const int r = blockIdx.y;
    const int j = blockIdx.x * 256 + threadIdx.x;
    if (j >= S_SAMPLES) return;
    float* so = sbuf + ((size_t)r * S_SAMPLES + j) * 12;

    const float ox = ro[r * 3 + 0], oy = ro[r * 3 + 1], oz = ro[r * 3 + 2];
    const float dx = rd[r * 3 + 0], dy = rd[r * 3 + 1], dz = rd[r * 3 + 2];
    const float vx = vd[r * 3 + 0], vy = vd[r * 3 + 1], vz = vd[r * 3 + 2];

    const float vecx = (dx == 0.f) ? 1e-6f : dx;
    const float vecy = (dy == 0.f) ? 1e-6f : dy;
    const float vecz = (dz == 0.f) ? 1e-6f : dz;
    const float rax = (1.f - ox) / vecx, rbx = (-1.f - ox) / vecx;
    const float ray2 = (1.f - oy) / vecy, rby = (-1.f - oy) / vecy;
    const float raz = (1.f - oz) / vecz, rbz = (-1.f - oz) / vecz;
    float tmin = fmaxf(fmaxf(fminf(rax, rbx), fminf(ray2, rby)), fminf(raz, rbz));
    float tmax = fminf(fminf(fmaxf(rax, rbx), fmaxf(ray2, rby)), fmaxf(raz, rbz));
    tmin = fminf(fmaxf(tmin, 0.2f), 6.0f);
    tmax = fminf(fmaxf(tmax, 0.2f), 6.0f);
    const bool mask_ray = (tmax <= tmin);

    const float ndr = sqrtf(dx * dx + dy * dy + dz * dz);
    const float interpx = tmin + (STEP_VOX * (float)j) / ndr;
    const float px = ox + dx * interpx;
    const float py = oy + dy * interpx;
    const float pz = oz + dz * interpx;
    const bool outbox = mask_ray || (px < -1.f) || (px > 1.f) || (py < -1.f) ||
                        (py > 1.f) || (pz < -1.f) || (pz > 1.f);
    if (outbox) {
#pragma unroll
        for (int t = 0; t < 12; ++t) so[t] = 0.f;
        return;
    }

    const float ux = fminf(fmaxf((px + 1.f) * 63.5f, 0.f), 127.f);
    const float uy = fminf(fmaxf((py + 1.f) * 63.5f, 0.f), 127.f);
    const float uz = fminf(fmaxf((pz + 1.f) * 63.5f, 0.f), 127.f);
    const int ix = min(max((int)floorf(ux), 0), 126);
    const int iy = min(max((int)floorf(uy), 0), 126);
    const int iz = min(max((int)floorf(uz), 0), 126);
    const float fx = ux - (float)ix, fy = uy - (float)iy, fz = uz - (float)iz;

    float lat[15];
#pragma unroll
    for (int t = 0; t < 15; ++t) lat[t] = 0.f;
    float na0 = 0.f, na1 = 0.f, na2 = 0.f;
    float c0v[8];
#pragma unroll
    for (int cn = 0; cn < 8; ++cn) {
        const int adx = cn >> 2, ady = (cn >> 1) & 1, adz = cn & 1;
        const int vox = ((ix + adx) * 128 + (iy + ady)) * 128 + (iz + adz);
        const float w = (adx ? fx : 1.f - fx) * (ady ? fy : 1.f - fy) * (adz ? fz : 1.f - fz);
        c0v[cn] = dens[vox];
        const uint4* cp = (const uint4*)(featb + (size_t)vox * 16);
        const uint4 q0 = cp[0], q1 = cp[1];
        lat[0]  = fmaf(w, bf2f((unsigned short)(q0.x >> 16)), lat[0]);
        lat[1]  = fmaf(w, bf2f((unsigned short)(q0.y      )), lat[1]);
        lat[2]  = fmaf(w, bf2f((unsigned short)(q0.y >> 16)), lat[2]);
        lat[3]  = fmaf(w, bf2f((unsigned short)(q0.z      )), lat[3]);
        lat[4]  = fmaf(w, bf2f((unsigned short)(q0.z >> 16)), lat[4]);
        lat[5]  = fmaf(w, bf2f((unsigned short)(q0.w      )), lat[5]);
        lat[6]  = fmaf(w, bf2f((unsigned short)(q0.w >> 16)), lat[6]);
        lat[7]  = fmaf(w, bf2f((unsigned short)(q1.x      )), lat[7]);
        lat[8]  = fmaf(w, bf2f((unsigned short)(q1.x >> 16)), lat[8]);
        lat[9]  = fmaf(w, bf2f((unsigned short)(q1.y      )), lat[9]);
        lat[10] = fmaf(w, bf2f((unsigned short)(q1.y >> 16)), lat[10]);
        lat[11] = fmaf(w, bf2f((unsigned short)(q1.z      )), lat[11]);
        lat[12] = fmaf(w, bf2f((unsigned short)(q1.z >> 16)), lat[12]);
        lat[13] = fmaf(w, bf2f((unsigned short)(q1.w      )), lat[13]);
        lat[14] = fmaf(w, bf2f((unsigned short)(q1.w >> 16)), lat[14]);
        const float* np_ = normals + (size_t)vox * 3;
        na0 = fmaf(w, np_[0], na0);
        na1 = fmaf(w, np_[1], na1);
        na2 = fmaf(w, np_[2], na2);
    }

    // channel-0 trilinear (nested lerp, matches ref) + gradient wrt (fx,fy,fz)
    const float c00 = c0v[0] * (1.f - fz) + c0v[1] * fz;
    const float c01 = c0v[2] * (1.f - fz) + c0v[3] * fz;
    const float c10 = c0v[4] * (1.f - fz) + c0v[5] * fz;
    const float c11 = c0v[6] * (1.f - fz) + c0v[7] * fz;
    const float e0 = c00 * (1.f - fy) + c01 * fy;
    const float e1 = c10 * (1.f - fy) + c11 * fy;
    const float d0 = e0 * (1.f - fx) + e1 * fx;
    const float dfx = e1 - e0;
    const float dfy = (c01 - c00) * (1.f - fx) + (c11 - c10) * fx;
    const float dfz = ((c0v[1] - c0v[0]) * (1.f - fy) + (c0v[3] - c0v[2]) * fy) * (1.f - fx)
                    + ((c0v[5] - c0v[4]) * (1.f - fy) + (c0v[7] - c0v[6]) * fy) * fx;

    const float zin = d0 + ACT_SHIFT;
    const float splus = fmaxf(zin, 0.f) + log1pf(__expf(-fabsf(zin)));
    const float e = __expf(-splus * 0.5f);
    const float alpha = 1.f - e;
    const float sig = 1.f / (1.f + __expf(-zin));
    const float dad = e * 0.5f * sig;        // dalpha/dd0
    const float gx = dad * dfx * 63.5f;
    const float gy = dad * dfy * 63.5f;
    const float gz = dad * dfz * 63.5f;
    const float gn = sqrtf(gx * gx + gy * gy + gz * gz);
    const float gi = 1.f / fmaxf(gn, 1e-12f);
    const float ndx = -gx * gi, ndy = -gy * gi, ndz = -gz * gi;

    const float nn = sqrtf(na0 * na0 + na1 * na1 + na2 * na2);
    const float ni = 1.f / fmaxf(nn, 1e-12f);
    const float nsx = -na0 * ni, nsy = -na1 * ni, nsz = -na2 * ni;

    const float dotv = -(vx * ndx + vy * ndy + vz * ndz);
    const float rx = 2.f * dotv * ndx + vx;
    const float ry = 2.f * dotv * ndy + vy;
    const float rz = 2.f * dotv * ndz + vz;

    float hf[54];
#pragma unroll
    for (int t = 0; t < 15; ++t) hf[t] = lat[t];
    hf[15] = rx; hf[16] = ry; hf[17] = rz;
#pragma unroll
    for (int fi = 0; fi < 6; ++fi) {
        const float fr = (float)(1 << fi);
        hf[18 + fi * 6 + 0] = __sinf(rx * fr);
        hf[18 + fi * 6 + 1] = __sinf(ry * fr);
        hf[18 + fi * 6 + 2] = __sinf(rz * fr);
        hf[18 + fi * 6 + 3] = __cosf(rx * fr);
        hf[18 + fi * 6 + 4] = __cosf(ry * fr);
        hf[18 + fi * 6 + 5] = __cosf(rz * fr);
    }

    float h1[64];
#pragma unroll
    for (int o = 0; o < 64; ++o) {
        float a = mb0[o];
#pragma unroll
        for (int c = 0; c < 54; ++c) a = fmaf(hf[c], mw0[c * 64 + o], a);
        h1[o] = fmaxf(a, 0.f);
    }
    float h2[64];
#pragma unroll
    for (int o = 0; o < 64; ++o) {
        float a = mb1[o];
#pragma unroll
        for (int c = 0; c < 64; ++c) a = fmaf(h1[c], mw1[c * 64 + o], a);
        h2[o] = fmaxf(a, 0.f);
    }
    float h3[64];
#pragma unroll
    for (int o = 0; o < 64; ++o) {
        float a = mb2[o];
#pragma unroll
        for (int c = 0; c < 64; ++c) a = fmaf(h2[c], mw2[c * 64 + o], a);
        h3[o] = fmaxf(a, 0.f);
    }
    float rgb[3];
#pragma unroll
    for (int o = 0; o < 3; ++o) {
        float a = mb3[o];
#pragma unroll
        for (int c = 0; c < 64; ++c) a = fmaf(h3[c], mw3[c * 3 + o], a);
        rgb[o] = 1.f / (1.f + __expf(-a));
    }

    so[0] = alpha;
    so[1] = rgb[0]; so[2] = rgb[1]; so[3] = rgb[2];
    so[4] = ndx; so[5] = ndy; so[6] = ndz;
    so[7] = nsx; so[8] = nsy; so[9] = nsz;
    so[10] = interpx * ndr;
    so[11] = 0.f;
}

// ============================================================================
// Kernel 4: per-ray compositing (wave per ray; segmented product scan).
// ============================================================================
__global__ __launch_bounds__(64) void reduce_kernel(const float* __restrict__ sbuf,
                                                    float* __restrict__ out)
{
    const int r = blockIdx.x;
    const int lane = threadIdx.x;
    const int per = (S_SAMPLES + 63) / 64;   // 7
    const int j0 = lane * per;
    const int j1 = min(S_SAMPLES, j0 + per);

    float p = 1.f;
    for (int j = j0; j < j1; ++j) {
        const float a = sbuf[((size_t)r * S_SAMPLES + j) * 12];
        p *= fmaxf(1.f - a, 1e-10f);
    }
    float scan = p;
#pragma unroll
    for (int off = 1; off < 64; off <<= 1) {
        const float nv = __shfl_up(scan, (unsigned)off, 64);
        if (lane >= off) scan *= nv;
    }
    const float total = __shfl(scan, 63, 64);
    float pref = __shfl_up(scan, 1u, 64);
    if (lane == 0) pref = 1.f;

    float s0 = 0, s1 = 0, s2 = 0, s3 = 0, s4 = 0, s5 = 0, s6 = 0, s7 = 0, s8 = 0, s9 = 0, s10 = 0;
    for (int j = j0; j < j1; ++j) {
        const float* sp_ = sbuf + ((size_t)r * S_SAMPLES + j) * 12;
        const float a = sp_[0];
        const float w = a * pref;
        pref *= fmaxf(1.f - a, 1e-10f);
        s0 = fmaf(w, sp_[1], s0);
        s1 = fmaf(w, sp_[2], s1);
        s2 = fmaf(w, sp_[3], s2);
        s3 = fmaf(w, sp_[10], s3);
        s4 += w;
        s5 = fmaf(w, sp_[4], s5);
        s6 = fmaf(w, sp_[5], s6);
        s7 = fmaf(w, sp_[6], s7);
        s8 = fmaf(w, sp_[7], s8);
        s9 = fmaf(w, sp_[8], s9);
        s10 = fmaf(w, sp_[9], s10);
    }
#pragma unroll
    for (int m = 32; m >= 1; m >>= 1) {
        s0 += __shfl_xor(s0, m, 64);
        s1 += __shfl_xor(s1, m, 64);
        s2 += __shfl_xor(s2, m, 64);
        s3 += __shfl_xor(s3, m, 64);
        s4 += __shfl_xor(s4, m, 64);
        s5 += __shfl_xor(s5, m, 64);
        s6 += __shfl_xor(s6, m, 64);
        s7 += __shfl_xor(s7, m, 64);
        s8 += __shfl_xor(s8, m, 64);
        s9 += __shfl_xor(s9, m, 64);
        s10 += __shfl_xor(s10, m, 64);
    }
    if (lane == 0) {
        const float dm = s3 + total * 6.0f;
        out[r * 12 + 0] = s0 + total;
        out[r * 12 + 1] = s1 + total;
        out[r * 12 + 2] = s2 + total;
        out[r * 12 + 3] = dm;
        out[r * 12 + 4] = 1.f / dm;
        out[r * 12 + 5] = s4;
        out[r * 12 + 6] = s5; out[r * 12 + 7] = s6; out[r * 12 + 8] = s7;
        out[r * 12 + 9] = s8; out[r * 12 + 10] = s9; out[r * 12 + 11] = s10;
    }
}

// ============================================================================
extern "C" void kernel_launch(void* const* d_in, const int* in_sizes, int n_in,
                              void* d_out, int out_size, void* d_ws, size_t ws_size,
                              hipStream_t stream)
{
    (void)n_in; (void)out_size; (void)ws_size;
    const float* rays_o   = (const float*)d_in[0];
    const float* rays_d   = (const float*)d_in[1];
    const float* viewdirs = (const float*)d_in[2];
    const float* grid     = (const float*)d_in[3];
    const float* c1_w  = (const float*)d_in[4];
    const float* c1_b  = (const float*)d_in[5];
    const float* bn1_g = (const float*)d_in[6];
    const float* bn1_b = (const float*)d_in[7];
    const float* pr1_a = (const float*)d_in[8];
    const float* c2_w  = (const float*)d_in[9];
    const float* c2_b  = (const float*)d_in[10];
    const float* bn2_g = (const float*)d_in[11];
    const float* bn2_b = (const float*)d_in[12];
    const float* pr2_a = (const float*)d_in[13];
    const float* c3_w  = (const float*)d_in[14];
    const float* c3_b  = (const float*)d_in[15];
    const float* mw0 = (const float*)d_in[16];
    const float* mb0 = (const float*)d_in[17];
    const float* mw1 = (const float*)d_in[18];
    const float* mb1 = (const float*)d_in[19];
    const float* mw2 = (const float*)d_in[20];
    const float* mb2 = (const float*)d_in[21];
    const float* mw3 = (const float*)d_in[22];
    const float* mb3 = (const float*)d_in[23];

    const int N = in_sizes[0] / 3;   // 1024 rays

    // ws layout (float units). featb is bf16 (2 B) but sized in float slots.
    // featb [0, 16777216) | dens [16777216, 18874368) | x2buf [18874368, 35651584)
    // normals + sbuf alias the (dead-after-conv3) x2buf region.
    float* wsf = (float*)d_ws;
    unsigned short* featb = (unsigned short*)wsf;                   // 128^3*16 bf16
    float* dens    = wsf + (size_t)16777216;                        // 128^3 fp32
    float* x2buf   = wsf + (size_t)18874368;                        // 64^3*64 fp32
    float* normals = wsf + (size_t)18874368;                        // alias (x2 dead)
    float* sbuf    = wsf + (size_t)25165824;                        // N*447*12

    conv12_kernel<<<1024, 256, 0, stream>>>(grid, c1_w, c1_b, bn1_g, bn1_b, pr1_a,
                                            c2_w, c2_b, bn2_g, bn2_b, pr2_a, x2buf);
    conv3_kernel<<<1024, 256, 0, stream>>>(grid, c1_w, c1_b, bn1_g, bn1_b, pr1_a,
                                           x2buf, c3_w, c3_b, featb, dens);
    sobel_kernel<<<8192, 256, 0, stream>>>(dens, normals);
    dim3 sg((S_SAMPLES + 255) / 256, N, 1);
    sample_kernel<<<sg, 256, 0, stream>>>(rays_o, rays_d, viewdirs, featb, dens, normals,
                                          mw0, mb0, mw1, mb1, mw2, mb2, mw3, mb3, sbuf);
    reduce_kernel<<<N, 64, 0, stream>>>(sbuf, (float*)d_out);
}

// Round 3
// 1568.096 us; speedup vs baseline: 2.6597x; 1.0930x over previous
//
#include <hip/hip_runtime.h>
#include <math.h>

// ---- constants from the reference ----
#define S_SAMPLES 447                      // int(norm([129]*3)/0.5)+1
#define ACT_SHIFT -9.210240366971207f      // log(1/(1-1e-4) - 1)
#define BN_SCALE_C 0.9999950000374997f     // (1+1e-5)^-0.5
#define STEP_VOX 0.015625f                 // STEPSIZE * VOXEL = 0.5 * (2/64)

__device__ __forceinline__ unsigned short f2bf(float f) {
    unsigned u = __float_as_uint(f);
    unsigned r = (u + 0x7fffu + ((u >> 16) & 1u)) >> 16;   // RNE
    return (unsigned short)r;
}
__device__ __forceinline__ float bf2f(unsigned short u) {
    return __uint_as_float(((unsigned)u) << 16);
}

// ============================================================================
// Kernel 1a: conv1 (16->64) + conv2 (80->64), BN+PReLU folded. Weights staged
// in LDS; inner reads are wave-uniform ds_read_b128 broadcasts (conflict-free).
// ============================================================================
__global__ __launch_bounds__(256) void conv12_kernel(
    const float* __restrict__ grid,
    const float* __restrict__ w1, const float* __restrict__ b1,
    const float* __restrict__ g1, const float* __restrict__ bb1, const float* __restrict__ a1,
    const float* __restrict__ w2, const float* __restrict__ b2,
    const float* __restrict__ g2, const float* __restrict__ bb2, const float* __restrict__ a2,
    float* __restrict__ x2buf)
{
    __shared__ float lw1[1024];            // 64x16
    __shared__ float lp1[256];             // b1,g1,bb1,a1
    __shared__ float lw2[5120];            // 64x80
    __shared__ float lp2[256];             // b2,g2,bb2,a2
    const int tid = threadIdx.x;
    for (int i = tid; i < 1024; i += 256) lw1[i] = w1[i];
    for (int i = tid; i < 5120; i += 256) lw2[i] = w2[i];
    if (tid < 64) {
        lp1[tid] = b1[tid]; lp1[64 + tid] = g1[tid]; lp1[128 + tid] = bb1[tid]; lp1[192 + tid] = a1[tid];
        lp2[tid] = b2[tid]; lp2[64 + tid] = g2[tid]; lp2[128 + tid] = bb2[tid]; lp2[192 + tid] = a2[tid];
    }
    __syncthreads();

    const int v = blockIdx.x * 256 + tid;     // 0..262143
    float g[16];
#pragma unroll
    for (int c = 0; c < 16; ++c) g[c] = grid[c * 262144 + v];

    float x1[64];
#pragma unroll
    for (int o = 0; o < 64; ++o) {
        const float4* wr = (const float4*)&lw1[o * 16];
        float acc = lp1[o];
#pragma unroll
        for (int k = 0; k < 4; ++k) {
            const float4 wv = wr[k];
            acc = fmaf(wv.x, g[4 * k + 0], acc);
            acc = fmaf(wv.y, g[4 * k + 1], acc);
            acc = fmaf(wv.z, g[4 * k + 2], acc);
            acc = fmaf(wv.w, g[4 * k + 3], acc);
        }
        acc = acc * (BN_SCALE_C * lp1[64 + o]) + lp1[128 + o];
        x1[o] = (acc >= 0.0f) ? acc : lp1[192 + o] * acc;
    }

    float* outp = x2buf + (size_t)v * 64;
#pragma unroll 1
    for (int og = 0; og < 16; ++og) {
        float a4[4];
#pragma unroll
        for (int i = 0; i < 4; ++i) {
            const int o = og * 4 + i;
            const float4* wr = (const float4*)&lw2[o * 80];
            float acc = lp2[o];
#pragma unroll
            for (int k = 0; k < 16; ++k) {
                const float4 wv = wr[k];
                acc = fmaf(wv.x, x1[4 * k + 0], acc);
                acc = fmaf(wv.y, x1[4 * k + 1], acc);
                acc = fmaf(wv.z, x1[4 * k + 2], acc);
                acc = fmaf(wv.w, x1[4 * k + 3], acc);
            }
#pragma unroll
            for (int k = 0; k < 4; ++k) {
                const float4 wv = wr[16 + k];
                acc = fmaf(wv.x, g[4 * k + 0], acc);
                acc = fmaf(wv.y, g[4 * k + 1], acc);
                acc = fmaf(wv.z, g[4 * k + 2], acc);
                acc = fmaf(wv.w, g[4 * k + 3], acc);
            }
            acc = acc * (BN_SCALE_C * lp2[64 + o]) + lp2[128 + o];
            a4[i] = (acc >= 0.0f) ? acc : lp2[192 + o] * acc;
        }
        ((float4*)outp)[og] = make_float4(a4[0], a4[1], a4[2], a4[3]);
    }
}

// ============================================================================
// Kernel 1b: conv3 (144->128) + pixel shuffle. blockIdx.y selects s in
// [4y, 4y+4): each block stages its 64 weight rows (36 KB) in LDS.
// feat bf16 channels-last; density (l=0) fp32.
// ============================================================================
__global__ __launch_bounds__(256) void conv3_kernel(
    const float* __restrict__ grid,
    const float* __restrict__ w1, const float* __restrict__ b1,
    const float* __restrict__ g1, const float* __restrict__ bb1, const float* __restrict__ a1,
    const float* __restrict__ x2buf,
    const float* __restrict__ w3, const float* __restrict__ b3,
    unsigned short* __restrict__ featb, float* __restrict__ dens)
{
    __shared__ float lw3[9216];            // 64 rows x 144 (this half's channels)
    __shared__ float lb3[64];
    __shared__ float lw1[1024];
    __shared__ float lp1[256];
    const int tid = threadIdx.x;
    const int s0 = 4 * blockIdx.y;

    // stage half of w3: LDS row r = l*4 + si  <->  global row o = l*8 + s0 + si
    {
        const float4* w3_4 = (const float4*)w3;
        float4* lw3_4 = (float4*)lw3;
        for (int idx = tid; idx < 2304; idx += 256) {      // 64 rows * 36 f4
            const int r = idx / 36, kq = idx % 36;
            const int l = r >> 2, si = r & 3;
            lw3_4[idx] = w3_4[(l * 8 + s0 + si) * 36 + kq];
        }
        if (tid < 64) {
            const int l = tid >> 2, si = tid & 3;
            lb3[tid] = b3[l * 8 + s0 + si];
        }
        for (int i = tid; i < 1024; i += 256) lw1[i] = w1[i];
        if (tid < 64) {
            lp1[tid] = b1[tid]; lp1[64 + tid] = g1[tid];
            lp1[128 + tid] = bb1[tid]; lp1[192 + tid] = a1[tid];
        }
    }
    __syncthreads();

    const int v = blockIdx.x * 256 + tid;
    const int Z = v & 63, Y = (v >> 6) & 63, X = v >> 12;

    float g[16];
#pragma unroll
    for (int c = 0; c < 16; ++c) g[c] = grid[c * 262144 + v];

    float x1[64];
#pragma unroll
    for (int o = 0; o < 64; ++o) {
        const float4* wr = (const float4*)&lw1[o * 16];
        float acc = lp1[o];
#pragma unroll
        for (int k = 0; k < 4; ++k) {
            const float4 wv = wr[k];
            acc = fmaf(wv.x, g[4 * k + 0], acc);
            acc = fmaf(wv.y, g[4 * k + 1], acc);
            acc = fmaf(wv.z, g[4 * k + 2], acc);
            acc = fmaf(wv.w, g[4 * k + 3], acc);
        }
        acc = acc * (BN_SCALE_C * lp1[64 + o]) + lp1[128 + o];
        x1[o] = (acc >= 0.0f) ? acc : lp1[192 + o] * acc;
    }

    float x2[64];
    const float4* xp = (const float4*)(x2buf + (size_t)v * 64);
#pragma unroll
    for (int q = 0; q < 16; ++q) {
        const float4 t = xp[q];
        x2[q * 4 + 0] = t.x; x2[q * 4 + 1] = t.y; x2[q * 4 + 2] = t.z; x2[q * 4 + 3] = t.w;
    }

#pragma unroll 1
    for (int si = 0; si < 4; ++si) {
        const int s = s0 + si;
        const int d2 = (s >> 2) & 1, h2 = (s >> 1) & 1, w2i = s & 1;
        const int ubase = ((2 * X + d2) * 128 + (2 * Y + h2)) * 128 + (2 * Z + w2i);
        unsigned short* fp = featb + (size_t)ubase * 16;
#pragma unroll 1
        for (int lq = 0; lq < 4; ++lq) {
            float a4[4];
#pragma unroll
            for (int i = 0; i < 4; ++i) {
                const int l = lq * 4 + i;
                const int r = l * 4 + si;                 // LDS row
                const float4* wr = (const float4*)&lw3[r * 144];
                float acc = lb3[r];
#pragma unroll
                for (int k = 0; k < 16; ++k) {
                    const float4 wv = wr[k];
                    acc = fmaf(wv.x, x1[4 * k + 0], acc);
                    acc = fmaf(wv.y, x1[4 * k + 1], acc);
                    acc = fmaf(wv.z, x1[4 * k + 2], acc);
                    acc = fmaf(wv.w, x1[4 * k + 3], acc);
                }
#pragma unroll
                for (int k = 0; k < 16; ++k) {
                    const float4 wv = wr[16 + k];
                    acc = fmaf(wv.x, x2[4 * k + 0], acc);
                    acc = fmaf(wv.y, x2[4 * k + 1], acc);
                    acc = fmaf(wv.z, x2[4 * k + 2], acc);
                    acc = fmaf(wv.w, x2[4 * k + 3], acc);
                }
#pragma unroll
                for (int k = 0; k < 4; ++k) {
                    const float4 wv = wr[32 + k];
                    acc = fmaf(wv.x, g[4 * k + 0], acc);
                    acc = fmaf(wv.y, g[4 * k + 1], acc);
                    acc = fmaf(wv.z, g[4 * k + 2], acc);
                    acc = fmaf(wv.w, g[4 * k + 3], acc);
                }
                a4[i] = acc;
            }
            uint2 st;
            st.x = (unsigned)f2bf(a4[0]) | ((unsigned)f2bf(a4[1]) << 16);
            st.y = (unsigned)f2bf(a4[2]) | ((unsigned)f2bf(a4[3]) << 16);
            *(uint2*)(fp + lq * 4) = st;
            if (lq == 0) dens[ubase] = a4[0];             // l==0 density, fp32
        }
    }
}

// ============================================================================
// Kernel 2: 5x5x5 Sobel (zero pad) on fp32 density + normalize.
// ============================================================================
__global__ __launch_bounds__(256) void sobel_kernel(const float* __restrict__ dens,
                                                    float* __restrict__ normals)
{
    const int v = blockIdx.x * 256 + threadIdx.x;
    const int z = v & 127, y = (v >> 7) & 127, x = v >> 14;
    const float hw[5] = {1.f, 4.f, 6.f, 4.f, 1.f};
    const float hd[5] = {-1.f, -2.f, 0.f, 2.f, 1.f};
    float sx = 0.f, sy = 0.f, sz = 0.f;
#pragma unroll
    for (int i = 0; i < 5; ++i) {
        const int xx = x + i - 2;
        if (xx < 0 || xx > 127) continue;
#pragma unroll
        for (int j = 0; j < 5; ++j) {
            const int yy = y + j - 2;
            if (yy < 0 || yy > 127) continue;
            const float* row = dens + (xx * 128 + yy) * 128;
            float sh = 0.f, sd = 0.f;
#pragma unroll
            for (int k = 0; k < 5; ++k) {
                const int zz = z + k - 2;
                if (zz < 0 || zz > 127) continue;
                const float d = row[zz];
                sh = fmaf(hw[k], d, sh);
                sd = fmaf(hd[k], d, sd);
            }
            sx = fmaf(hd[i] * hw[j], sh, sx);
            sy = fmaf(hw[i] * hd[j], sh, sy);
            sz = fmaf(hw[i] * hw[j], sd, sz);
        }
    }
    sx *= (1.f / 72.f); sy *= (1.f / 72.f); sz *= (1.f / 72.f);
    const float n = sqrtf(sx * sx + sy * sy + sz * sz);
    const float inv = 1.f / fmaxf(n, 1e-12f);
    normals[v * 3 + 0] = -sx * inv;
    normals[v * 3 + 1] = -sy * inv;
    normals[v * 3 + 2] = -sz * inv;
}

// ============================================================================
// Kernel 3: per-sample shading (unchanged from round 2).
// ============================================================================
__global__ __launch_bounds__(256) void sample_kernel(
    const float* __restrict__ ro, const float* __restrict__ rd, const float* __restrict__ vd,
    const unsigned short* __restrict__ featb, const float* __restrict__ dens,
    const float* __restrict__ normals,
    const float* __restrict__ mw0, const float* __restrict__ mb0,
    const float* __restrict__ mw1, const float* __restrict__ mb1,
    const float* __restrict__ mw2, const float* __restrict__ mb2,
    const float* __restrict__ mw3, const float* __restrict__ mb3,
    float* __restrict__ sbuf)
{
    const int r = blockIdx.y;
    const int j = blockIdx.x * 256 + threadIdx.x;
    if (j >= S_SAMPLES) return;
    float* so = sbuf + ((size_t)r * S_SAMPLES + j) * 12;

    const float ox = ro[r * 3 + 0], oy = ro[r * 3 + 1], oz = ro[r * 3 + 2];
    const float dx = rd[r * 3 + 0], dy = rd[r * 3 + 1], dz = rd[r * 3 + 2];
    const float vx = vd[r * 3 + 0], vy = vd[r * 3 + 1], vz = vd[r * 3 + 2];

    const float vecx = (dx == 0.f) ? 1e-6f : dx;
    const float vecy = (dy == 0.f) ? 1e-6f : dy;
    const float vecz = (dz == 0.f) ? 1e-6f : dz;
    const float rax = (1.f - ox) / vecx, rbx = (-1.f - ox) / vecx;
    const float ray2 = (1.f - oy) / vecy, rby = (-1.f - oy) / vecy;
    const float raz = (1.f - oz) / vecz, rbz = (-1.f - oz) / vecz;
    float tmin = fmaxf(fmaxf(fminf(rax, rbx), fminf(ray2, rby)), fminf(raz, rbz));
    float tmax = fminf(fminf(fmaxf(rax, rbx), fmaxf(ray2, rby)), fmaxf(raz, rbz));
    tmin = fminf(fmaxf(tmin, 0.2f), 6.0f);
    tmax = fminf(fmaxf(tmax, 0.2f), 6.0f);
    const bool mask_ray = (tmax <= tmin);

    const float ndr = sqrtf(dx * dx + dy * dy + dz * dz);
    const float interpx = tmin + (STEP_VOX * (float)j) / ndr;
    const float px = ox + dx * interpx;
    const float py = oy + dy * interpx;
    const float pz = oz + dz * interpx;
    const bool outbox = mask_ray || (px < -1.f) || (px > 1.f) || (py < -1.f) ||
                        (py > 1.f) || (pz < -1.f) || (pz > 1.f);
    if (outbox) {
#pragma unroll
        for (int t = 0; t < 12; ++t) so[t] = 0.f;
        return;
    }

    const float ux = fminf(fmaxf((px + 1.f) * 63.5f, 0.f), 127.f);
    const float uy = fminf(fmaxf((py + 1.f) * 63.5f, 0.f), 127.f);
    const float uz = fminf(fmaxf((pz + 1.f) * 63.5f, 0.f), 127.f);
    const int ix = min(max((int)floorf(ux), 0), 126);
    const int iy = min(max((int)floorf(uy), 0), 126);
    const int iz = min(max((int)floorf(uz), 0), 126);
    const float fx = ux - (float)ix, fy = uy - (float)iy, fz = uz - (float)iz;

    float lat[15];
#pragma unroll
    for (int t = 0; t < 15; ++t) lat[t] = 0.f;
    float na0 = 0.f, na1 = 0.f, na2 = 0.f;
    float c0v[8];
#pragma unroll
    for (int cn = 0; cn < 8; ++cn) {
        const int adx = cn >> 2, ady = (cn >> 1) & 1, adz = cn & 1;
        const int vox = ((ix + adx) * 128 + (iy + ady)) * 128 + (iz + adz);
        const float w = (adx ? fx : 1.f - fx) * (ady ? fy : 1.f - fy) * (adz ? fz : 1.f - fz);
        c0v[cn] = dens[vox];
        const uint4* cp = (const uint4*)(featb + (size_t)vox * 16);
        const uint4 q0 = cp[0], q1 = cp[1];
        lat[0]  = fmaf(w, bf2f((unsigned short)(q0.x >> 16)), lat[0]);
        lat[1]  = fmaf(w, bf2f((unsigned short)(q0.y      )), lat[1]);
        lat[2]  = fmaf(w, bf2f((unsigned short)(q0.y >> 16)), lat[2]);
        lat[3]  = fmaf(w, bf2f((unsigned short)(q0.z      )), lat[3]);
        lat[4]  = fmaf(w, bf2f((unsigned short)(q0.z >> 16)), lat[4]);
        lat[5]  = fmaf(w, bf2f((unsigned short)(q0.w      )), lat[5]);
        lat[6]  = fmaf(w, bf2f((unsigned short)(q0.w >> 16)), lat[6]);
        lat[7]  = fmaf(w, bf2f((unsigned short)(q1.x      )), lat[7]);
        lat[8]  = fmaf(w, bf2f((unsigned short)(q1.x >> 16)), lat[8]);
        lat[9]  = fmaf(w, bf2f((unsigned short)(q1.y      )), lat[9]);
        lat[10] = fmaf(w, bf2f((unsigned short)(q1.y >> 16)), lat[10]);
        lat[11] = fmaf(w, bf2f((unsigned short)(q1.z      )), lat[11]);
        lat[12] = fmaf(w, bf2f((unsigned short)(q1.z >> 16)), lat[12]);
        lat[13] = fmaf(w, bf2f((unsigned short)(q1.w      )), lat[13]);
        lat[14] = fmaf(w, bf2f((unsigned short)(q1.w >> 16)), lat[14]);
        const float* np_ = normals + (size_t)vox * 3;
        na0 = fmaf(w, np_[0], na0);
        na1 = fmaf(w, np_[1], na1);
        na2 = fmaf(w, np_[2], na2);
    }

    const float c00 = c0v[0] * (1.f - fz) + c0v[1] * fz;
    const float c01 = c0v[2] * (1.f - fz) + c0v[3] * fz;
    const float c10 = c0v[4] * (1.f - fz) + c0v[5] * fz;
    const float c11 = c0v[6] * (1.f - fz) + c0v[7] * fz;
    const float e0 = c00 * (1.f - fy) + c01 * fy;
    const float e1 = c10 * (1.f - fy) + c11 * fy;
    const float d0 = e0 * (1.f - fx) + e1 * fx;
    const float dfx = e1 - e0;
    const float dfy = (c01 - c00) * (1.f - fx) + (c11 - c10) * fx;
    const float dfz = ((c0v[1] - c0v[0]) * (1.f - fy) + (c0v[3] - c0v[2]) * fy) * (1.f - fx)
                    + ((c0v[5] - c0v[4]) * (1.f - fy) + (c0v[7] - c0v[6]) * fy) * fx;

    const float zin = d0 + ACT_SHIFT;
    const float splus = fmaxf(zin, 0.f) + log1pf(__expf(-fabsf(zin)));
    const float e = __expf(-splus * 0.5f);
    const float alpha = 1.f - e;
    const float sig = 1.f / (1.f + __expf(-zin));
    const float dad = e * 0.5f * sig;
    const float gx = dad * dfx * 63.5f;
    const float gy = dad * dfy * 63.5f;
    const float gz = dad * dfz * 63.5f;
    const float gn = sqrtf(gx * gx + gy * gy + gz * gz);
    const float gi = 1.f / fmaxf(gn, 1e-12f);
    const float ndx = -gx * gi, ndy = -gy * gi, ndz = -gz * gi;

    const float nn = sqrtf(na0 * na0 + na1 * na1 + na2 * na2);
    const float ni = 1.f / fmaxf(nn, 1e-12f);
    const float nsx = -na0 * ni, nsy = -na1 * ni, nsz = -na2 * ni;

    const float dotv = -(vx * ndx + vy * ndy + vz * ndz);
    const float rx = 2.f * dotv * ndx + vx;
    const float ry = 2.f * dotv * ndy + vy;
    const float rz = 2.f * dotv * ndz + vz;

    float hf[54];
#pragma unroll
    for (int t = 0; t < 15; ++t) hf[t] = lat[t];
    hf[15] = rx; hf[16] = ry; hf[17] = rz;
#pragma unroll
    for (int fi = 0; fi < 6; ++fi) {
        const float fr = (float)(1 << fi);
        hf[18 + fi * 6 + 0] = __sinf(rx * fr);
        hf[18 + fi * 6 + 1] = __sinf(ry * fr);
        hf[18 + fi * 6 + 2] = __sinf(rz * fr);
        hf[18 + fi * 6 + 3] = __cosf(rx * fr);
        hf[18 + fi * 6 + 4] = __cosf(ry * fr);
        hf[18 + fi * 6 + 5] = __cosf(rz * fr);
    }

    float h1[64];
#pragma unroll
    for (int o = 0; o < 64; ++o) {
        float a = mb0[o];
#pragma unroll
        for (int c = 0; c < 54; ++c) a = fmaf(hf[c], mw0[c * 64 + o], a);
        h1[o] = fmaxf(a, 0.f);
    }
    float h2[64];
#pragma unroll
    for (int o = 0; o < 64; ++o) {
        float a = mb1[o];
#pragma unroll
        for (int c = 0; c < 64; ++c) a = fmaf(h1[c], mw1[c * 64 + o], a);
        h2[o] = fmaxf(a, 0.f);
    }
    float h3[64];
#pragma unroll
    for (int o = 0; o < 64; ++o) {
        float a = mb2[o];
#pragma unroll
        for (int c = 0; c < 64; ++c) a = fmaf(h2[c], mw2[c * 64 + o], a);
        h3[o] = fmaxf(a, 0.f);
    }
    float rgb[3];
#pragma unroll
    for (int o = 0; o < 3; ++o) {
        float a = mb3[o];
#pragma unroll
        for (int c = 0; c < 64; ++c) a = fmaf(h3[c], mw3[c * 3 + o], a);
        rgb[o] = 1.f / (1.f + __expf(-a));
    }

    so[0] = alpha;
    so[1] = rgb[0]; so[2] = rgb[1]; so[3] = rgb[2];
    so[4] = ndx; so[5] = ndy; so[6] = ndz;
    so[7] = nsx; so[8] = nsy; so[9] = nsz;
    so[10] = interpx * ndr;
    so[11] = 0.f;
}

// ============================================================================
// Kernel 4: per-ray compositing (wave per ray; segmented product scan).
// ============================================================================
__global__ __launch_bounds__(64) void reduce_kernel(const float* __restrict__ sbuf,
                                                    float* __restrict__ out)
{
    const int r = blockIdx.x;
    const int lane = threadIdx.x;
    const int per = (S_SAMPLES + 63) / 64;   // 7
    const int j0 = lane * per;
    const int j1 = min(S_SAMPLES, j0 + per);

    float p = 1.f;
    for (int j = j0; j < j1; ++j) {
        const float a = sbuf[((size_t)r * S_SAMPLES + j) * 12];
        p *= fmaxf(1.f - a, 1e-10f);
    }
    float scan = p;
#pragma unroll
    for (int off = 1; off < 64; off <<= 1) {
        const float nv = __shfl_up(scan, (unsigned)off, 64);
        if (lane >= off) scan *= nv;
    }
    const float total = __shfl(scan, 63, 64);
    float pref = __shfl_up(scan, 1u, 64);
    if (lane == 0) pref = 1.f;

    float s0 = 0, s1 = 0, s2 = 0, s3 = 0, s4 = 0, s5 = 0, s6 = 0, s7 = 0, s8 = 0, s9 = 0, s10 = 0;
    for (int j = j0; j < j1; ++j) {
        const float* sp_ = sbuf + ((size_t)r * S_SAMPLES + j) * 12;
        const float a = sp_[0];
        const float w = a * pref;
        pref *= fmaxf(1.f - a, 1e-10f);
        s0 = fmaf(w, sp_[1], s0);
        s1 = fmaf(w, sp_[2], s1);
        s2 = fmaf(w, sp_[3], s2);
        s3 = fmaf(w, sp_[10], s3);
        s4 += w;
        s5 = fmaf(w, sp_[4], s5);
        s6 = fmaf(w, sp_[5], s6);
        s7 = fmaf(w, sp_[6], s7);
        s8 = fmaf(w, sp_[7], s8);
        s9 = fmaf(w, sp_[8], s9);
        s10 = fmaf(w, sp_[9], s10);
    }
#pragma unroll
    for (int m = 32; m >= 1; m >>= 1) {
        s0 += __shfl_xor(s0, m, 64);
        s1 += __shfl_xor(s1, m, 64);
        s2 += __shfl_xor(s2, m, 64);
        s3 += __shfl_xor(s3, m, 64);
        s4 += __shfl_xor(s4, m, 64);
        s5 += __shfl_xor(s5, m, 64);
        s6 += __shfl_xor(s6, m, 64);
        s7 += __shfl_xor(s7, m, 64);
        s8 += __shfl_xor(s8, m, 64);
        s9 += __shfl_xor(s9, m, 64);
        s10 += __shfl_xor(s10, m, 64);
    }
    if (lane == 0) {
        const float dm = s3 + total * 6.0f;
        out[r * 12 + 0] = s0 + total;
        out[r * 12 + 1] = s1 + total;
        out[r * 12 + 2] = s2 + total;
        out[r * 12 + 3] = dm;
        out[r * 12 + 4] = 1.f / dm;
        out[r * 12 + 5] = s4;
        out[r * 12 + 6] = s5; out[r * 12 + 7] = s6; out[r * 12 + 8] = s7;
        out[r * 12 + 9] = s8; out[r * 12 + 10] = s9; out[r * 12 + 11] = s10;
    }
}

// ============================================================================
extern "C" void kernel_launch(void* const* d_in, const int* in_sizes, int n_in,
                              void* d_out, int out_size, void* d_ws, size_t ws_size,
                              hipStream_t stream)
{
    (void)n_in; (void)out_size; (void)ws_size;
    const float* rays_o   = (const float*)d_in[0];
    const float* rays_d   = (const float*)d_in[1];
    const float* viewdirs = (const float*)d_in[2];
    const float* grid     = (const float*)d_in[3];
    const float* c1_w  = (const float*)d_in[4];
    const float* c1_b  = (const float*)d_in[5];
    const float* bn1_g = (const float*)d_in[6];
    const float* bn1_b = (const float*)d_in[7];
    const float* pr1_a = (const float*)d_in[8];
    const float* c2_w  = (const float*)d_in[9];
    const float* c2_b  = (const float*)d_in[10];
    const float* bn2_g = (const float*)d_in[11];
    const float* bn2_b = (const float*)d_in[12];
    const float* pr2_a = (const float*)d_in[13];
    const float* c3_w  = (const float*)d_in[14];
    const float* c3_b  = (const float*)d_in[15];
    const float* mw0 = (const float*)d_in[16];
    const float* mb0 = (const float*)d_in[17];
    const float* mw1 = (const float*)d_in[18];
    const float* mb1 = (const float*)d_in[19];
    const float* mw2 = (const float*)d_in[20];
    const float* mb2 = (const float*)d_in[21];
    const float* mw3 = (const float*)d_in[22];
    const float* mb3 = (const float*)d_in[23];

    const int N = in_sizes[0] / 3;   // 1024 rays

    // ws layout (float units). featb is bf16 (2 B) but sized in float slots.
    float* wsf = (float*)d_ws;
    unsigned short* featb = (unsigned short*)wsf;                   // 128^3*16 bf16
    float* dens    = wsf + (size_t)16777216;                        // 128^3 fp32
    float* x2buf   = wsf + (size_t)18874368;                        // 64^3*64 fp32
    float* normals = wsf + (size_t)18874368;                        // alias (x2 dead)
    float* sbuf    = wsf + (size_t)25165824;                        // N*447*12

    conv12_kernel<<<1024, 256, 0, stream>>>(grid, c1_w, c1_b, bn1_g, bn1_b, pr1_a,
                                            c2_w, c2_b, bn2_g, bn2_b, pr2_a, x2buf);
    dim3 c3g(1024, 2, 1);
    conv3_kernel<<<c3g, 256, 0, stream>>>(grid, c1_w, c1_b, bn1_g, bn1_b, pr1_a,
                                          x2buf, c3_w, c3_b, featb, dens);
    sobel_kernel<<<8192, 256, 0, stream>>>(dens, normals);
    dim3 sg((S_SAMPLES + 255) / 256, N, 1);
    sample_kernel<<<sg, 256, 0, stream>>>(rays_o, rays_d, viewdirs, featb, dens, normals,
                                          mw0, mb0, mw1, mb1, mw2, mb2, mw3, mb3, sbuf);
    reduce_kernel<<<N, 64, 0, stream>>>(sbuf, (float*)d_out);
}

// Round 4
// 671.734 us; speedup vs baseline: 6.2087x; 2.3344x over previous
//
#include <hip/hip_runtime.h>
#include <math.h>

// ---- constants from the reference ----
#define S_SAMPLES 447                      // int(norm([129]*3)/0.5)+1
#define ACT_SHIFT -9.210240366971207f      // log(1/(1-1e-4) - 1)
#define BN_SCALE_C 0.9999950000374997f     // (1+1e-5)^-0.5
#define STEP_VOX 0.015625f                 // STEPSIZE * VOXEL = 0.5 * (2/64)

__device__ __forceinline__ unsigned f2bf_u(float f) {
    unsigned u = __float_as_uint(f);
    return (u + 0x7fffu + ((u >> 16) & 1u)) >> 16;   // RNE, as low 16 bits
}
__device__ __forceinline__ float bf2f(unsigned short u) {
    return __uint_as_float(((unsigned)u) << 16);
}

// ============================================================================
// Kernel 0: prep — transpose weights to [k][channel] layouts for GEMM B-reads.
// w3 gets the pixel-shuffle channel permutation baked in: n = (o&7)*16 + (o>>3)
// so that a thread's 8 consecutive n are {s fixed, l0..l0+7} (contiguous featb).
// ============================================================================
__global__ __launch_bounds__(256) void prep_kernel(
    const float* __restrict__ w1, const float* __restrict__ w2,
    const float* __restrict__ w3, const float* __restrict__ b3,
    float* __restrict__ w1t, float* __restrict__ w2t,
    float* __restrict__ w3t, float* __restrict__ b3p)
{
    const int t = threadIdx.x;
    for (int idx = t; idx < 1024; idx += 256) {          // w1 [64][16] -> w1t [16][64]
        const int o = idx >> 4, k = idx & 15;
        w1t[k * 64 + o] = w1[idx];
    }
    for (int idx = t; idx < 5120; idx += 256) {          // w2 [64][80] -> w2t [80][64]
        const int o = idx / 80, k = idx % 80;
        w2t[k * 64 + o] = w2[idx];
    }
    for (int idx = t; idx < 18432; idx += 256) {         // w3 [128][144] -> w3t [144][128] permuted
        const int o = idx / 144, k = idx % 144;
        const int n = (o & 7) * 16 + (o >> 3);
        w3t[k * 128 + n] = w3[idx];
    }
    if (t < 128) {
        const int o = t;
        b3p[(o & 7) * 16 + (o >> 3)] = b3[o];
    }
}

// ============================================================================
// Kernel 1a: conv1 (16->64) + conv2 (80->64) as tiled GEMMs over 64-voxel
// tiles. Thread = 8 voxels x 4 channels. BN+PReLU in epilogues. Writes
// A_g bf16 [128 rows][262144]: rows 0-63 = x1, 64-127 = x2.
// ============================================================================
__global__ __launch_bounds__(128, 2) void conv12_kernel(
    const float* __restrict__ grid,
    const float* __restrict__ w1t, const float* __restrict__ b1,
    const float* __restrict__ g1, const float* __restrict__ bb1, const float* __restrict__ a1,
    const float* __restrict__ w2t, const float* __restrict__ b2,
    const float* __restrict__ g2, const float* __restrict__ bb2, const float* __restrict__ a2,
    unsigned short* __restrict__ A_g)
{
    __shared__ float Gt[16 * 64];        // [c][v]  4KB
    __shared__ float X1t[64 * 64];       // [c][v] 16KB
    const int t = threadIdx.x;
    const int v0 = blockIdx.x * 64;
    const int vv = t & 63;

    // stage grid tile (coalesced; k = 2*i + (t>>6))
#pragma unroll
    for (int i = 0; i < 8; ++i) {
        const int c = 2 * i + (t >> 6);
        Gt[c * 64 + vv] = grid[(size_t)c * 262144 + v0 + vv];
    }
    __syncthreads();

    const int tx = t & 7, ty = t >> 3;       // vq = 8*tx (64 v), cq = 4*ty (64 c)
    const int vq = 8 * tx, cq = 4 * ty;
    const float4* w1t4 = (const float4*)w1t;
    const float4* w2t4 = (const float4*)w2t;

    // ---- GEMM1: x1 = act(bn(G @ W1^T)) ----
    float acc1[8][4];
#pragma unroll
    for (int j = 0; j < 4; ++j) {
        const float bj = b1[cq + j];
#pragma unroll
        for (int i = 0; i < 8; ++i) acc1[i][j] = bj;
    }
#pragma unroll 8
    for (int k = 0; k < 16; ++k) {
        const float4 av0 = *(const float4*)&Gt[k * 64 + vq];
        const float4 av1 = *(const float4*)&Gt[k * 64 + vq + 4];
        const float4 wv = w1t4[k * 16 + ty];
        const float a[8] = {av0.x, av0.y, av0.z, av0.w, av1.x, av1.y, av1.z, av1.w};
        const float w[4] = {wv.x, wv.y, wv.z, wv.w};
#pragma unroll
        for (int i = 0; i < 8; ++i)
#pragma unroll
            for (int j = 0; j < 4; ++j) acc1[i][j] = fmaf(a[i], w[j], acc1[i][j]);
    }
    // epilogue 1: BN + PReLU, write X1t and A_g rows cq..cq+3
#pragma unroll
    for (int j = 0; j < 4; ++j) {
        const int c = cq + j;
        const float gs = BN_SCALE_C * g1[c], bb = bb1[c], al = a1[c];
        float vals[8];
#pragma unroll
        for (int i = 0; i < 8; ++i) {
            float x = acc1[i][j] * gs + bb;
            vals[i] = (x >= 0.f) ? x : al * x;
        }
        *(float4*)&X1t[c * 64 + vq]     = make_float4(vals[0], vals[1], vals[2], vals[3]);
        *(float4*)&X1t[c * 64 + vq + 4] = make_float4(vals[4], vals[5], vals[6], vals[7]);
        uint4 st;
        st.x = f2bf_u(vals[0]) | (f2bf_u(vals[1]) << 16);
        st.y = f2bf_u(vals[2]) | (f2bf_u(vals[3]) << 16);
        st.z = f2bf_u(vals[4]) | (f2bf_u(vals[5]) << 16);
        st.w = f2bf_u(vals[6]) | (f2bf_u(vals[7]) << 16);
        *(uint4*)(A_g + (size_t)c * 262144 + v0 + vq) = st;
    }
    __syncthreads();

    // ---- GEMM2: x2 = act(bn([x1|g] @ W2^T)) ----
    float acc2[8][4];
#pragma unroll
    for (int j = 0; j < 4; ++j) {
        const float bj = b2[cq + j];
#pragma unroll
        for (int i = 0; i < 8; ++i) acc2[i][j] = bj;
    }
#pragma unroll 4
    for (int k = 0; k < 80; ++k) {
        const float* arow = (k < 64) ? &X1t[k * 64] : &Gt[(k - 64) * 64];
        const float4 av0 = *(const float4*)&arow[vq];
        const float4 av1 = *(const float4*)&arow[vq + 4];
        const float4 wv = w2t4[k * 16 + ty];
        const float a[8] = {av0.x, av0.y, av0.z, av0.w, av1.x, av1.y, av1.z, av1.w};
        const float w[4] = {wv.x, wv.y, wv.z, wv.w};
#pragma unroll
        for (int i = 0; i < 8; ++i)
#pragma unroll
            for (int j = 0; j < 4; ++j) acc2[i][j] = fmaf(a[i], w[j], acc2[i][j]);
    }
#pragma unroll
    for (int j = 0; j < 4; ++j) {
        const int c = cq + j;
        const float gs = BN_SCALE_C * g2[c], bb = bb2[c], al = a2[c];
        float vals[8];
#pragma unroll
        for (int i = 0; i < 8; ++i) {
            float x = acc2[i][j] * gs + bb;
            vals[i] = (x >= 0.f) ? x : al * x;
        }
        uint4 st;
        st.x = f2bf_u(vals[0]) | (f2bf_u(vals[1]) << 16);
        st.y = f2bf_u(vals[2]) | (f2bf_u(vals[3]) << 16);
        st.z = f2bf_u(vals[4]) | (f2bf_u(vals[5]) << 16);
        st.w = f2bf_u(vals[6]) | (f2bf_u(vals[7]) << 16);
        *(uint4*)(A_g + (size_t)(64 + c) * 262144 + v0 + vq) = st;
    }
}

// ============================================================================
// Kernel 1b: conv3 (144->128) as tiled GEMM + pixel-shuffle epilogue.
// Thread = 8 voxels x 8 channels. A-tile (x1|x2 bf16 from A_g, g fp32 from
// grid) staged fp32 in LDS; B (w3t) streamed from global (L2-resident).
// featb bf16 (16B store per voxel-half), dens fp32.
// ============================================================================
__global__ __launch_bounds__(128, 2) void conv3_kernel(
    const unsigned short* __restrict__ A_g, const float* __restrict__ grid,
    const float* __restrict__ w3t, const float* __restrict__ b3p,
    unsigned short* __restrict__ featb, float* __restrict__ dens)
{
    __shared__ float At[144 * 64];       // [k][v] 36.9KB
    const int t = threadIdx.x;
    const int v0 = blockIdx.x * 64;
    const int vv = t & 63;

#pragma unroll
    for (int i = 0; i < 72; ++i) {
        const int k = 2 * i + (t >> 6);
        float val;
        if (k < 128) val = bf2f(A_g[(size_t)k * 262144 + v0 + vv]);
        else         val = grid[(size_t)(k - 128) * 262144 + v0 + vv];
        At[k * 64 + vv] = val;
    }
    __syncthreads();

    const int tx = t & 7, ty = t >> 3;       // vq = 8*tx, n-block = 8*ty
    const int vq = 8 * tx, cq = 8 * ty;
    const float4* w3t4 = (const float4*)w3t;

    float acc[8][8];
    {
        const float4 b0 = *(const float4*)&b3p[cq];
        const float4 b1v = *(const float4*)&b3p[cq + 4];
        const float bj[8] = {b0.x, b0.y, b0.z, b0.w, b1v.x, b1v.y, b1v.z, b1v.w};
#pragma unroll
        for (int i = 0; i < 8; ++i)
#pragma unroll
            for (int j = 0; j < 8; ++j) acc[i][j] = bj[j];
    }

#pragma unroll 4
    for (int k = 0; k < 144; ++k) {
        const float4 av0 = *(const float4*)&At[k * 64 + vq];
        const float4 av1 = *(const float4*)&At[k * 64 + vq + 4];
        const float4 wv0 = w3t4[k * 32 + 2 * ty];
        const float4 wv1 = w3t4[k * 32 + 2 * ty + 1];
        const float a[8] = {av0.x, av0.y, av0.z, av0.w, av1.x, av1.y, av1.z, av1.w};
        const float w[8] = {wv0.x, wv0.y, wv0.z, wv0.w, wv1.x, wv1.y, wv1.z, wv1.w};
#pragma unroll
        for (int i = 0; i < 8; ++i)
#pragma unroll
            for (int j = 0; j < 8; ++j) acc[i][j] = fmaf(a[i], w[j], acc[i][j]);
    }

    // epilogue: n = cq + j -> s = ty>>1, l = 8*(ty&1) + j
    const int s = ty >> 1;
    const int l0 = 8 * (ty & 1);
    const int d2 = (s >> 2) & 1, h2 = (s >> 1) & 1, w2i = s & 1;
#pragma unroll
    for (int i = 0; i < 8; ++i) {
        const int v = v0 + vq + i;
        const int Z = v & 63, Y = (v >> 6) & 63, X = v >> 12;
        const int ubase = ((2 * X + d2) * 128 + (2 * Y + h2)) * 128 + (2 * Z + w2i);
        if (l0 == 0) dens[ubase] = acc[i][0];
        uint4 st;
        st.x = f2bf_u(acc[i][0]) | (f2bf_u(acc[i][1]) << 16);
        st.y = f2bf_u(acc[i][2]) | (f2bf_u(acc[i][3]) << 16);
        st.z = f2bf_u(acc[i][4]) | (f2bf_u(acc[i][5]) << 16);
        st.w = f2bf_u(acc[i][6]) | (f2bf_u(acc[i][7]) << 16);
        *(uint4*)(featb + (size_t)ubase * 16 + l0) = st;
    }
}

// ============================================================================
// Kernel 2: 5x5x5 Sobel (zero pad) on fp32 density + normalize.
// ============================================================================
__global__ __launch_bounds__(256) void sobel_kernel(const float* __restrict__ dens,
                                                    float* __restrict__ normals)
{
    const int v = blockIdx.x * 256 + threadIdx.x;
    const int z = v & 127, y = (v >> 7) & 127, x = v >> 14;
    const float hw[5] = {1.f, 4.f, 6.f, 4.f, 1.f};
    const float hd[5] = {-1.f, -2.f, 0.f, 2.f, 1.f};
    float sx = 0.f, sy = 0.f, sz = 0.f;
#pragma unroll
    for (int i = 0; i < 5; ++i) {
        const int xx = x + i - 2;
        if (xx < 0 || xx > 127) continue;
#pragma unroll
        for (int j = 0; j < 5; ++j) {
            const int yy = y + j - 2;
            if (yy < 0 || yy > 127) continue;
            const float* row = dens + (xx * 128 + yy) * 128;
            float sh = 0.f, sd = 0.f;
#pragma unroll
            for (int k = 0; k < 5; ++k) {
                const int zz = z + k - 2;
                if (zz < 0 || zz > 127) continue;
                const float d = row[zz];
                sh = fmaf(hw[k], d, sh);
                sd = fmaf(hd[k], d, sd);
            }
            sx = fmaf(hd[i] * hw[j], sh, sx);
            sy = fmaf(hw[i] * hd[j], sh, sy);
            sz = fmaf(hw[i] * hw[j], sd, sz);
        }
    }
    sx *= (1.f / 72.f); sy *= (1.f / 72.f); sz *= (1.f / 72.f);
    const float n = sqrtf(sx * sx + sy * sy + sz * sz);
    const float inv = 1.f / fmaxf(n, 1e-12f);
    normals[v * 3 + 0] = -sx * inv;
    normals[v * 3 + 1] = -sy * inv;
    normals[v * 3 + 2] = -sz * inv;
}

// ============================================================================
// Kernel 3: per-sample shading (unchanged from round 3).
// ============================================================================
__global__ __launch_bounds__(256) void sample_kernel(
    const float* __restrict__ ro, const float* __restrict__ rd, const float* __restrict__ vd,
    const unsigned short* __restrict__ featb, const float* __restrict__ dens,
    const float* __restrict__ normals,
    const float* __restrict__ mw0, const float* __restrict__ mb0,
    const float* __restrict__ mw1, const float* __restrict__ mb1,
    const float* __restrict__ mw2, const float* __restrict__ mb2,
    const float* __restrict__ mw3, const float* __restrict__ mb3,
    float* __restrict__ sbuf)
{
    const int r = blockIdx.y;
    const int j = blockIdx.x * 256 + threadIdx.x;
    if (j >= S_SAMPLES) return;
    float* so = sbuf + ((size_t)r * S_SAMPLES + j) * 12;

    const float ox = ro[r * 3 + 0], oy = ro[r * 3 + 1], oz = ro[r * 3 + 2];
    const float dx = rd[r * 3 + 0], dy = rd[r * 3 + 1], dz = rd[r * 3 + 2];
    const float vx = vd[r * 3 + 0], vy = vd[r * 3 + 1], vz = vd[r * 3 + 2];

    const float vecx = (dx == 0.f) ? 1e-6f : dx;
    const float vecy = (dy == 0.f) ? 1e-6f : dy;
    const float vecz = (dz == 0.f) ? 1e-6f : dz;
    const float rax = (1.f - ox) / vecx, rbx = (-1.f - ox) / vecx;
    const float ray2 = (1.f - oy) / vecy, rby = (-1.f - oy) / vecy;
    const float raz = (1.f - oz) / vecz, rbz = (-1.f - oz) / vecz;
    float tmin = fmaxf(fmaxf(fminf(rax, rbx), fminf(ray2, rby)), fminf(raz, rbz));
    float tmax = fminf(fminf(fmaxf(rax, rbx), fmaxf(ray2, rby)), fmaxf(raz, rbz));
    tmin = fminf(fmaxf(tmin, 0.2f), 6.0f);
    tmax = fminf(fmaxf(tmax, 0.2f), 6.0f);
    const bool mask_ray = (tmax <= tmin);

    const float ndr = sqrtf(dx * dx + dy * dy + dz * dz);
    const float interpx = tmin + (STEP_VOX * (float)j) / ndr;
    const float px = ox + dx * interpx;
    const float py = oy + dy * interpx;
    const float pz = oz + dz * interpx;
    const bool outbox = mask_ray || (px < -1.f) || (px > 1.f) || (py < -1.f) ||
                        (py > 1.f) || (pz < -1.f) || (pz > 1.f);
    if (outbox) {
#pragma unroll
        for (int t = 0; t < 12; ++t) so[t] = 0.f;
        return;
    }

    const float ux = fminf(fmaxf((px + 1.f) * 63.5f, 0.f), 127.f);
    const float uy = fminf(fmaxf((py + 1.f) * 63.5f, 0.f), 127.f);
    const float uz = fminf(fmaxf((pz + 1.f) * 63.5f, 0.f), 127.f);
    const int ix = min(max((int)floorf(ux), 0), 126);
    const int iy = min(max((int)floorf(uy), 0), 126);
    const int iz = min(max((int)floorf(uz), 0), 126);
    const float fx = ux - (float)ix, fy = uy - (float)iy, fz = uz - (float)iz;

    float lat[15];
#pragma unroll
    for (int t = 0; t < 15; ++t) lat[t] = 0.f;
    float na0 = 0.f, na1 = 0.f, na2 = 0.f;
    float c0v[8];
#pragma unroll
    for (int cn = 0; cn < 8; ++cn) {
        const int adx = cn >> 2, ady = (cn >> 1) & 1, adz = cn & 1;
        const int vox = ((ix + adx) * 128 + (iy + ady)) * 128 + (iz + adz);
        const float w = (adx ? fx : 1.f - fx) * (ady ? fy : 1.f - fy) * (adz ? fz : 1.f - fz);
        c0v[cn] = dens[vox];
        const uint4* cp = (const uint4*)(featb + (size_t)vox * 16);
        const uint4 q0 = cp[0], q1 = cp[1];
        lat[0]  = fmaf(w, bf2f((unsigned short)(q0.x >> 16)), lat[0]);
        lat[1]  = fmaf(w, bf2f((unsigned short)(q0.y      )), lat[1]);
        lat[2]  = fmaf(w, bf2f((unsigned short)(q0.y >> 16)), lat[2]);
        lat[3]  = fmaf(w, bf2f((unsigned short)(q0.z      )), lat[3]);
        lat[4]  = fmaf(w, bf2f((unsigned short)(q0.z >> 16)), lat[4]);
        lat[5]  = fmaf(w, bf2f((unsigned short)(q0.w      )), lat[5]);
        lat[6]  = fmaf(w, bf2f((unsigned short)(q0.w >> 16)), lat[6]);
        lat[7]  = fmaf(w, bf2f((unsigned short)(q1.x      )), lat[7]);
        lat[8]  = fmaf(w, bf2f((unsigned short)(q1.x >> 16)), lat[8]);
        lat[9]  = fmaf(w, bf2f((unsigned short)(q1.y      )), lat[9]);
        lat[10] = fmaf(w, bf2f((unsigned short)(q1.y >> 16)), lat[10]);
        lat[11] = fmaf(w, bf2f((unsigned short)(q1.z      )), lat[11]);
        lat[12] = fmaf(w, bf2f((unsigned short)(q1.z >> 16)), lat[12]);
        lat[13] = fmaf(w, bf2f((unsigned short)(q1.w      )), lat[13]);
        lat[14] = fmaf(w, bf2f((unsigned short)(q1.w >> 16)), lat[14]);
        const float* np_ = normals + (size_t)vox * 3;
        na0 = fmaf(w, np_[0], na0);
        na1 = fmaf(w, np_[1], na1);
        na2 = fmaf(w, np_[2], na2);
    }

    const float c00 = c0v[0] * (1.f - fz) + c0v[1] * fz;
    const float c01 = c0v[2] * (1.f - fz) + c0v[3] * fz;
    const float c10 = c0v[4] * (1.f - fz) + c0v[5] * fz;
    const float c11 = c0v[6] * (1.f - fz) + c0v[7] * fz;
    const float e0 = c00 * (1.f - fy) + c01 * fy;
    const float e1 = c10 * (1.f - fy) + c11 * fy;
    const float d0 = e0 * (1.f - fx) + e1 * fx;
    const float dfx = e1 - e0;
    const float dfy = (c01 - c00) * (1.f - fx) + (c11 - c10) * fx;
    const float dfz = ((c0v[1] - c0v[0]) * (1.f - fy) + (c0v[3] - c0v[2]) * fy) * (1.f - fx)
                    + ((c0v[5] - c0v[4]) * (1.f - fy) + (c0v[7] - c0v[6]) * fy) * fx;

    const float zin = d0 + ACT_SHIFT;
    const float splus = fmaxf(zin, 0.f) + log1pf(__expf(-fabsf(zin)));
    const float e = __expf(-splus * 0.5f);
    const float alpha = 1.f - e;
    const float sig = 1.f / (1.f + __expf(-zin));
    const float dad = e * 0.5f * sig;
    const float gx = dad * dfx * 63.5f;
    const float gy = dad * dfy * 63.5f;
    const float gz = dad * dfz * 63.5f;
    const float gn = sqrtf(gx * gx + gy * gy + gz * gz);
    const float gi = 1.f / fmaxf(gn, 1e-12f);
    const float ndx = -gx * gi, ndy = -gy * gi, ndz = -gz * gi;

    const float nn = sqrtf(na0 * na0 + na1 * na1 + na2 * na2);
    const float ni = 1.f / fmaxf(nn, 1e-12f);
    const float nsx = -na0 * ni, nsy = -na1 * ni, nsz = -na2 * ni;

    const float dotv = -(vx * ndx + vy * ndy + vz * ndz);
    const float rx = 2.f * dotv * ndx + vx;
    const float ry = 2.f * dotv * ndy + vy;
    const float rz = 2.f * dotv * ndz + vz;

    float hf[54];
#pragma unroll
    for (int t = 0; t < 15; ++t) hf[t] = lat[t];
    hf[15] = rx; hf[16] = ry; hf[17] = rz;
#pragma unroll
    for (int fi = 0; fi < 6; ++fi) {
        const float fr = (float)(1 << fi);
        hf[18 + fi * 6 + 0] = __sinf(rx * fr);
        hf[18 + fi * 6 + 1] = __sinf(ry * fr);
        hf[18 + fi * 6 + 2] = __sinf(rz * fr);
        hf[18 + fi * 6 + 3] = __cosf(rx * fr);
        hf[18 + fi * 6 + 4] = __cosf(ry * fr);
        hf[18 + fi * 6 + 5] = __cosf(rz * fr);
    }

    float h1[64];
#pragma unroll
    for (int o = 0; o < 64; ++o) {
        float a = mb0[o];
#pragma unroll
        for (int c = 0; c < 54; ++c) a = fmaf(hf[c], mw0[c * 64 + o], a);
        h1[o] = fmaxf(a, 0.f);
    }
    float h2[64];
#pragma unroll
    for (int o = 0; o < 64; ++o) {
        float a = mb1[o];
#pragma unroll
        for (int c = 0; c < 64; ++c) a = fmaf(h1[c], mw1[c * 64 + o], a);
        h2[o] = fmaxf(a, 0.f);
    }
    float h3[64];
#pragma unroll
    for (int o = 0; o < 64; ++o) {
        float a = mb2[o];
#pragma unroll
        for (int c = 0; c < 64; ++c) a = fmaf(h2[c], mw2[c * 64 + o], a);
        h3[o] = fmaxf(a, 0.f);
    }
    float rgb[3];
#pragma unroll
    for (int o = 0; o < 3; ++o) {
        float a = mb3[o];
#pragma unroll
        for (int c = 0; c < 64; ++c) a = fmaf(h3[c], mw3[c * 3 + o], a);
        rgb[o] = 1.f / (1.f + __expf(-a));
    }

    so[0] = alpha;
    so[1] = rgb[0]; so[2] = rgb[1]; so[3] = rgb[2];
    so[4] = ndx; so[5] = ndy; so[6] = ndz;
    so[7] = nsx; so[8] = nsy; so[9] = nsz;
    so[10] = interpx * ndr;
    so[11] = 0.f;
}

// ============================================================================
// Kernel 4: per-ray compositing (wave per ray; segmented product scan).
// ============================================================================
__global__ __launch_bounds__(64) void reduce_kernel(const float* __restrict__ sbuf,
                                                    float* __restrict__ out)
{
    const int r = blockIdx.x;
    const int lane = threadIdx.x;
    const int per = (S_SAMPLES + 63) / 64;   // 7
    const int j0 = lane * per;
    const int j1 = min(S_SAMPLES, j0 + per);

    float p = 1.f;
    for (int j = j0; j < j1; ++j) {
        const float a = sbuf[((size_t)r * S_SAMPLES + j) * 12];
        p *= fmaxf(1.f - a, 1e-10f);
    }
    float scan = p;
#pragma unroll
    for (int off = 1; off < 64; off <<= 1) {
        const float nv = __shfl_up(scan, (unsigned)off, 64);
        if (lane >= off) scan *= nv;
    }
    const float total = __shfl(scan, 63, 64);
    float pref = __shfl_up(scan, 1u, 64);
    if (lane == 0) pref = 1.f;

    float s0 = 0, s1 = 0, s2 = 0, s3 = 0, s4 = 0, s5 = 0, s6 = 0, s7 = 0, s8 = 0, s9 = 0, s10 = 0;
    for (int j = j0; j < j1; ++j) {
        const float* sp_ = sbuf + ((size_t)r * S_SAMPLES + j) * 12;
        const float a = sp_[0];
        const float w = a * pref;
        pref *= fmaxf(1.f - a, 1e-10f);
        s0 = fmaf(w, sp_[1], s0);
        s1 = fmaf(w, sp_[2], s1);
        s2 = fmaf(w, sp_[3], s2);
        s3 = fmaf(w, sp_[10], s3);
        s4 += w;
        s5 = fmaf(w, sp_[4], s5);
        s6 = fmaf(w, sp_[5], s6);
        s7 = fmaf(w, sp_[6], s7);
        s8 = fmaf(w, sp_[7], s8);
        s9 = fmaf(w, sp_[8], s9);
        s10 = fmaf(w, sp_[9], s10);
    }
#pragma unroll
    for (int m = 32; m >= 1; m >>= 1) {
        s0 += __shfl_xor(s0, m, 64);
        s1 += __shfl_xor(s1, m, 64);
        s2 += __shfl_xor(s2, m, 64);
        s3 += __shfl_xor(s3, m, 64);
        s4 += __shfl_xor(s4, m, 64);
        s5 += __shfl_xor(s5, m, 64);
        s6 += __shfl_xor(s6, m, 64);
        s7 += __shfl_xor(s7, m, 64);
        s8 += __shfl_xor(s8, m, 64);
        s9 += __shfl_xor(s9, m, 64);
        s10 += __shfl_xor(s10, m, 64);
    }
    if (lane == 0) {
        const float dm = s3 + total * 6.0f;
        out[r * 12 + 0] = s0 + total;
        out[r * 12 + 1] = s1 + total;
        out[r * 12 + 2] = s2 + total;
        out[r * 12 + 3] = dm;
        out[r * 12 + 4] = 1.f / dm;
        out[r * 12 + 5] = s4;
        out[r * 12 + 6] = s5; out[r * 12 + 7] = s6; out[r * 12 + 8] = s7;
        out[r * 12 + 9] = s8; out[r * 12 + 10] = s9; out[r * 12 + 11] = s10;
    }
}

// ============================================================================
extern "C" void kernel_launch(void* const* d_in, const int* in_sizes, int n_in,
                              void* d_out, int out_size, void* d_ws, size_t ws_size,
                              hipStream_t stream)
{
    (void)n_in; (void)out_size; (void)ws_size;
    const float* rays_o   = (const float*)d_in[0];
    const float* rays_d   = (const float*)d_in[1];
    const float* viewdirs = (const float*)d_in[2];
    const float* grid     = (const float*)d_in[3];
    const float* c1_w  = (const float*)d_in[4];
    const float* c1_b  = (const float*)d_in[5];
    const float* bn1_g = (const float*)d_in[6];
    const float* bn1_b = (const float*)d_in[7];
    const float* pr1_a = (const float*)d_in[8];
    const float* c2_w  = (const float*)d_in[9];
    const float* c2_b  = (const float*)d_in[10];
    const float* bn2_g = (const float*)d_in[11];
    const float* bn2_b = (const float*)d_in[12];
    const float* pr2_a = (const float*)d_in[13];
    const float* c3_w  = (const float*)d_in[14];
    const float* c3_b  = (const float*)d_in[15];
    const float* mw0 = (const float*)d_in[16];
    const float* mb0 = (const float*)d_in[17];
    const float* mw1 = (const float*)d_in[18];
    const float* mb1 = (const float*)d_in[19];
    const float* mw2 = (const float*)d_in[20];
    const float* mb2 = (const float*)d_in[21];
    const float* mw3 = (const float*)d_in[22];
    const float* mb3 = (const float*)d_in[23];

    const int N = in_sizes[0] / 3;   // 1024 rays

    // ws layout (float units), total 142.7 MB:
    // featb  [0, 16777216)            bf16 128^3 x 16
    // dens   [16777216, 18874368)     fp32 128^3
    // A_g    [18874368, 35651584)     bf16 128 x 262144 (x1|x2)
    //   normals aliases [18874368, 25165824)  (written after A_g is dead)
    //   sbuf    aliases [25165824, 30660608)
    // wts    [35651584, 35676288)     w1t|w2t|w3t|b3p
    float* wsf = (float*)d_ws;
    unsigned short* featb = (unsigned short*)wsf;
    float* dens    = wsf + (size_t)16777216;
    unsigned short* A_g = (unsigned short*)(wsf + (size_t)18874368);
    float* normals = wsf + (size_t)18874368;
    float* sbuf    = wsf + (size_t)25165824;
    float* w1t = wsf + (size_t)35651584;
    float* w2t = w1t + 1024;
    float* w3t = w2t + 5120;
    float* b3p = w3t + 18432;

    prep_kernel<<<1, 256, 0, stream>>>(c1_w, c2_w, c3_w, c3_b, w1t, w2t, w3t, b3p);
    conv12_kernel<<<4096, 128, 0, stream>>>(grid, w1t, c1_b, bn1_g, bn1_b, pr1_a,
                                            w2t, c2_b, bn2_g, bn2_b, pr2_a, A_g);
    conv3_kernel<<<4096, 128, 0, stream>>>(A_g, grid, w3t, b3p, featb, dens);
    sobel_kernel<<<8192, 256, 0, stream>>>(dens, normals);
    dim3 sg((S_SAMPLES + 255) / 256, N, 1);
    sample_kernel<<<sg, 256, 0, stream>>>(rays_o, rays_d, viewdirs, featb, dens, normals,
                                          mw0, mb0, mw1, mb1, mw2, mb2, mw3, mb3, sbuf);
    reduce_kernel<<<N, 64, 0, stream>>>(sbuf, (float*)d_out);
}

// Round 5
// 612.551 us; speedup vs baseline: 6.8086x; 1.0966x over previous
//
#include <hip/hip_runtime.h>
#include <math.h>

// ---- constants from the reference ----
#define S_SAMPLES 447                      // int(norm([129]*3)/0.5)+1
#define ACT_SHIFT -9.210240366971207f      // log(1/(1-1e-4) - 1)
#define BN_SCALE_C 0.9999950000374997f     // (1+1e-5)^-0.5
#define STEP_VOX 0.015625f                 // STEPSIZE * VOXEL = 0.5 * (2/64)

__device__ __forceinline__ unsigned f2bf_u(float f) {
    unsigned u = __float_as_uint(f);
    return (u + 0x7fffu + ((u >> 16) & 1u)) >> 16;   // RNE, low 16 bits
}
__device__ __forceinline__ float bf2f(unsigned short u) {
    return __uint_as_float(((unsigned)u) << 16);
}
__device__ __forceinline__ float bf_lo(unsigned u) { return __uint_as_float(u << 16); }
__device__ __forceinline__ float bf_hi(unsigned u) { return __uint_as_float(u & 0xffff0000u); }

// ============================================================================
// Kernel 0: prep — transpose weights to [k][channel] layouts for GEMM B-reads.
// w3 gets the pixel-shuffle channel permutation baked in: n = (o&7)*16 + (o>>3).
// ============================================================================
__global__ __launch_bounds__(256) void prep_kernel(
    const float* __restrict__ w1, const float* __restrict__ w2,
    const float* __restrict__ w3, const float* __restrict__ b3,
    float* __restrict__ w1t, float* __restrict__ w2t,
    float* __restrict__ w3t, float* __restrict__ b3p)
{
    const int t = threadIdx.x;
    for (int idx = t; idx < 1024; idx += 256) {          // w1 [64][16] -> w1t [16][64]
        const int o = idx >> 4, k = idx & 15;
        w1t[k * 64 + o] = w1[idx];
    }
    for (int idx = t; idx < 5120; idx += 256) {          // w2 [64][80] -> w2t [80][64]
        const int o = idx / 80, k = idx % 80;
        w2t[k * 64 + o] = w2[idx];
    }
    for (int idx = t; idx < 18432; idx += 256) {         // w3 [128][144] -> w3t [144][128] permuted
        const int o = idx / 144, k = idx % 144;
        const int n = (o & 7) * 16 + (o >> 3);
        w3t[k * 128 + n] = w3[idx];
    }
    if (t < 128) {
        const int o = t;
        b3p[(o & 7) * 16 + (o >> 3)] = b3[o];
    }
}

// ============================================================================
// Kernel 1a: conv1+conv2 tiled GEMMs (thread = 8 voxels x 4 channels).
// Writes A_g bf16 [128 rows][262144]: rows 0-63 = x1, 64-127 = x2.
// ============================================================================
__global__ __launch_bounds__(128, 2) void conv12_kernel(
    const float* __restrict__ grid,
    const float* __restrict__ w1t, const float* __restrict__ b1,
    const float* __restrict__ g1, const float* __restrict__ bb1, const float* __restrict__ a1,
    const float* __restrict__ w2t, const float* __restrict__ b2,
    const float* __restrict__ g2, const float* __restrict__ bb2, const float* __restrict__ a2,
    unsigned short* __restrict__ A_g)
{
    __shared__ float Gt[16 * 64];
    __shared__ float X1t[64 * 64];
    const int t = threadIdx.x;
    const int v0 = blockIdx.x * 64;
    const int vv = t & 63;

#pragma unroll
    for (int i = 0; i < 8; ++i) {
        const int c = 2 * i + (t >> 6);
        Gt[c * 64 + vv] = grid[(size_t)c * 262144 + v0 + vv];
    }
    __syncthreads();

    const int tx = t & 7, ty = t >> 3;
    const int vq = 8 * tx, cq = 4 * ty;
    const float4* w1t4 = (const float4*)w1t;
    const float4* w2t4 = (const float4*)w2t;

    float acc1[8][4];
#pragma unroll
    for (int j = 0; j < 4; ++j) {
        const float bj = b1[cq + j];
#pragma unroll
        for (int i = 0; i < 8; ++i) acc1[i][j] = bj;
    }
#pragma unroll 8
    for (int k = 0; k < 16; ++k) {
        const float4 av0 = *(const float4*)&Gt[k * 64 + vq];
        const float4 av1 = *(const float4*)&Gt[k * 64 + vq + 4];
        const float4 wv = w1t4[k * 16 + ty];
        const float a[8] = {av0.x, av0.y, av0.z, av0.w, av1.x, av1.y, av1.z, av1.w};
        const float w[4] = {wv.x, wv.y, wv.z, wv.w};
#pragma unroll
        for (int i = 0; i < 8; ++i)
#pragma unroll
            for (int j = 0; j < 4; ++j) acc1[i][j] = fmaf(a[i], w[j], acc1[i][j]);
    }
#pragma unroll
    for (int j = 0; j < 4; ++j) {
        const int c = cq + j;
        const float gs = BN_SCALE_C * g1[c], bb = bb1[c], al = a1[c];
        float vals[8];
#pragma unroll
        for (int i = 0; i < 8; ++i) {
            float x = acc1[i][j] * gs + bb;
            vals[i] = (x >= 0.f) ? x : al * x;
        }
        *(float4*)&X1t[c * 64 + vq]     = make_float4(vals[0], vals[1], vals[2], vals[3]);
        *(float4*)&X1t[c * 64 + vq + 4] = make_float4(vals[4], vals[5], vals[6], vals[7]);
        uint4 st;
        st.x = f2bf_u(vals[0]) | (f2bf_u(vals[1]) << 16);
        st.y = f2bf_u(vals[2]) | (f2bf_u(vals[3]) << 16);
        st.z = f2bf_u(vals[4]) | (f2bf_u(vals[5]) << 16);
        st.w = f2bf_u(vals[6]) | (f2bf_u(vals[7]) << 16);
        *(uint4*)(A_g + (size_t)c * 262144 + v0 + vq) = st;
    }
    __syncthreads();

    float acc2[8][4];
#pragma unroll
    for (int j = 0; j < 4; ++j) {
        const float bj = b2[cq + j];
#pragma unroll
        for (int i = 0; i < 8; ++i) acc2[i][j] = bj;
    }
#pragma unroll 4
    for (int k = 0; k < 80; ++k) {
        const float* arow = (k < 64) ? &X1t[k * 64] : &Gt[(k - 64) * 64];
        const float4 av0 = *(const float4*)&arow[vq];
        const float4 av1 = *(const float4*)&arow[vq + 4];
        const float4 wv = w2t4[k * 16 + ty];
        const float a[8] = {av0.x, av0.y, av0.z, av0.w, av1.x, av1.y, av1.z, av1.w};
        const float w[4] = {wv.x, wv.y, wv.z, wv.w};
#pragma unroll
        for (int i = 0; i < 8; ++i)
#pragma unroll
            for (int j = 0; j < 4; ++j) acc2[i][j] = fmaf(a[i], w[j], acc2[i][j]);
    }
#pragma unroll
    for (int j = 0; j < 4; ++j) {
        const int c = cq + j;
        const float gs = BN_SCALE_C * g2[c], bb = bb2[c], al = a2[c];
        float vals[8];
#pragma unroll
        for (int i = 0; i < 8; ++i) {
            float x = acc2[i][j] * gs + bb;
            vals[i] = (x >= 0.f) ? x : al * x;
        }
        uint4 st;
        st.x = f2bf_u(vals[0]) | (f2bf_u(vals[1]) << 16);
        st.y = f2bf_u(vals[2]) | (f2bf_u(vals[3]) << 16);
        st.z = f2bf_u(vals[4]) | (f2bf_u(vals[5]) << 16);
        st.w = f2bf_u(vals[6]) | (f2bf_u(vals[7]) << 16);
        *(uint4*)(A_g + (size_t)(64 + c) * 262144 + v0 + vq) = st;
    }
}

// ============================================================================
// Kernel 1b: conv3 tiled GEMM + pixel-shuffle epilogue (thread = 8v x 8ch).
// ============================================================================
__global__ __launch_bounds__(128, 2) void conv3_kernel(
    const unsigned short* __restrict__ A_g, const float* __restrict__ grid,
    const float* __restrict__ w3t, const float* __restrict__ b3p,
    unsigned short* __restrict__ featb, float* __restrict__ dens)
{
    __shared__ float At[144 * 64];
    const int t = threadIdx.x;
    const int v0 = blockIdx.x * 64;
    const int vv = t & 63;

#pragma unroll
    for (int i = 0; i < 72; ++i) {
        const int k = 2 * i + (t >> 6);
        float val;
        if (k < 128) val = bf2f(A_g[(size_t)k * 262144 + v0 + vv]);
        else         val = grid[(size_t)(k - 128) * 262144 + v0 + vv];
        At[k * 64 + vv] = val;
    }
    __syncthreads();

    const int tx = t & 7, ty = t >> 3;
    const int vq = 8 * tx, cq = 8 * ty;
    const float4* w3t4 = (const float4*)w3t;

    float acc[8][8];
    {
        const float4 b0 = *(const float4*)&b3p[cq];
        const float4 b1v = *(const float4*)&b3p[cq + 4];
        const float bj[8] = {b0.x, b0.y, b0.z, b0.w, b1v.x, b1v.y, b1v.z, b1v.w};
#pragma unroll
        for (int i = 0; i < 8; ++i)
#pragma unroll
            for (int j = 0; j < 8; ++j) acc[i][j] = bj[j];
    }

#pragma unroll 4
    for (int k = 0; k < 144; ++k) {
        const float4 av0 = *(const float4*)&At[k * 64 + vq];
        const float4 av1 = *(const float4*)&At[k * 64 + vq + 4];
        const float4 wv0 = w3t4[k * 32 + 2 * ty];
        const float4 wv1 = w3t4[k * 32 + 2 * ty + 1];
        const float a[8] = {av0.x, av0.y, av0.z, av0.w, av1.x, av1.y, av1.z, av1.w};
        const float w[8] = {wv0.x, wv0.y, wv0.z, wv0.w, wv1.x, wv1.y, wv1.z, wv1.w};
#pragma unroll
        for (int i = 0; i < 8; ++i)
#pragma unroll
            for (int j = 0; j < 8; ++j) acc[i][j] = fmaf(a[i], w[j], acc[i][j]);
    }

    const int s = ty >> 1;
    const int l0 = 8 * (ty & 1);
    const int d2 = (s >> 2) & 1, h2 = (s >> 1) & 1, w2i = s & 1;
#pragma unroll
    for (int i = 0; i < 8; ++i) {
        const int v = v0 + vq + i;
        const int Z = v & 63, Y = (v >> 6) & 63, X = v >> 12;
        const int ubase = ((2 * X + d2) * 128 + (2 * Y + h2)) * 128 + (2 * Z + w2i);
        if (l0 == 0) dens[ubase] = acc[i][0];
        uint4 st;
        st.x = f2bf_u(acc[i][0]) | (f2bf_u(acc[i][1]) << 16);
        st.y = f2bf_u(acc[i][2]) | (f2bf_u(acc[i][3]) << 16);
        st.z = f2bf_u(acc[i][4]) | (f2bf_u(acc[i][5]) << 16);
        st.w = f2bf_u(acc[i][6]) | (f2bf_u(acc[i][7]) << 16);
        *(uint4*)(featb + (size_t)ubase * 16 + l0) = st;
    }
}

// ============================================================================
// Kernel 2: 5x5x5 Sobel (zero pad) on fp32 density + normalize.
// ============================================================================
__global__ __launch_bounds__(256) void sobel_kernel(const float* __restrict__ dens,
                                                    float* __restrict__ normals)
{
    const int v = blockIdx.x * 256 + threadIdx.x;
    const int z = v & 127, y = (v >> 7) & 127, x = v >> 14;
    const float hw[5] = {1.f, 4.f, 6.f, 4.f, 1.f};
    const float hd[5] = {-1.f, -2.f, 0.f, 2.f, 1.f};
    float sx = 0.f, sy = 0.f, sz = 0.f;
#pragma unroll
    for (int i = 0; i < 5; ++i) {
        const int xx = x + i - 2;
        if (xx < 0 || xx > 127) continue;
#pragma unroll
        for (int j = 0; j < 5; ++j) {
            const int yy = y + j - 2;
            if (yy < 0 || yy > 127) continue;
            const float* row = dens + (xx * 128 + yy) * 128;
            float sh = 0.f, sd = 0.f;
#pragma unroll
            for (int k = 0; k < 5; ++k) {
                const int zz = z + k - 2;
                if (zz < 0 || zz > 127) continue;
                const float d = row[zz];
                sh = fmaf(hw[k], d, sh);
                sd = fmaf(hd[k], d, sd);
            }
            sx = fmaf(hd[i] * hw[j], sh, sx);
            sy = fmaf(hw[i] * hd[j], sh, sy);
            sz = fmaf(hw[i] * hw[j], sd, sz);
        }
    }
    sx *= (1.f / 72.f); sy *= (1.f / 72.f); sz *= (1.f / 72.f);
    const float n = sqrtf(sx * sx + sy * sy + sz * sz);
    const float inv = 1.f / fmaxf(n, 1e-12f);
    normals[v * 3 + 0] = -sx * inv;
    normals[v * 3 + 1] = -sy * inv;
    normals[v * 3 + 2] = -sz * inv;
}

// ============================================================================
// Kernel 3: per-sample shading, GEMM-ified MLP.
// Block = 256 threads = 128 samples. Phase A: threads 0-127 do fp32 per-sample
// setup, write hf[54] bf16 to LDS; all threads stage bf16 weights. Phase B:
// 3 GEMM layers (thread = 8 samples x 4 ch, rolled k-loop, I$-resident) with
// ping/pong bf16 LDS activations. Final 64->3 + sigmoid per-sample.
// ============================================================================
__device__ __forceinline__ void stage_bf(unsigned short* dst, const float* src, int n2, int t) {
    for (int i = t; i < n2; i += 256) {
        const float2 v = ((const float2*)src)[i];
        ((unsigned*)dst)[i] = f2bf_u(v.x) | (f2bf_u(v.y) << 16);
    }
}

__device__ __forceinline__ void gemm_layer(const unsigned short* A, unsigned short* D,
                                           const unsigned short* W, const float* bias,
                                           const int K, const int sx, const int ty)
{
    float acc[8][4];
    {
        const float b0 = bias[4 * ty], b1 = bias[4 * ty + 1];
        const float b2 = bias[4 * ty + 2], b3 = bias[4 * ty + 3];
#pragma unroll
        for (int i = 0; i < 8; ++i) {
            acc[i][0] = b0; acc[i][1] = b1; acc[i][2] = b2; acc[i][3] = b3;
        }
    }
#pragma unroll 2
    for (int k = 0; k < K; ++k) {
        const uint4 au = *(const uint4*)(A + k * 128 + 8 * sx);
        const uint2 wu = *(const uint2*)(W + k * 64 + 4 * ty);
        const float a[8] = {bf_lo(au.x), bf_hi(au.x), bf_lo(au.y), bf_hi(au.y),
                            bf_lo(au.z), bf_hi(au.z), bf_lo(au.w), bf_hi(au.w)};
        const float w[4] = {bf_lo(wu.x), bf_hi(wu.x), bf_lo(wu.y), bf_hi(wu.y)};
#pragma unroll
        for (int i = 0; i < 8; ++i)
#pragma unroll
            for (int j = 0; j < 4; ++j) acc[i][j] = fmaf(a[i], w[j], acc[i][j]);
    }
#pragma unroll
    for (int j = 0; j < 4; ++j) {
        float v[8];
#pragma unroll
        for (int i = 0; i < 8; ++i) v[i] = fmaxf(acc[i][j], 0.f);
        uint4 st;
        st.x = f2bf_u(v[0]) | (f2bf_u(v[1]) << 16);
        st.y = f2bf_u(v[2]) | (f2bf_u(v[3]) << 16);
        st.z = f2bf_u(v[4]) | (f2bf_u(v[5]) << 16);
        st.w = f2bf_u(v[6]) | (f2bf_u(v[7]) << 16);
        *(uint4*)(D + (4 * ty + j) * 128 + 8 * sx) = st;
    }
}

__global__ __launch_bounds__(256) void sample_kernel(
    const float* __restrict__ ro, const float* __restrict__ rd, const float* __restrict__ vd,
    const unsigned short* __restrict__ featb, const float* __restrict__ dens,
    const float* __restrict__ normals,
    const float* __restrict__ mw0, const float* __restrict__ mb0,
    const float* __restrict__ mw1, const float* __restrict__ mb1,
    const float* __restrict__ mw2, const float* __restrict__ mb2,
    const float* __restrict__ mw3, const float* __restrict__ mb3,
    float* __restrict__ sbuf, const int total)
{
    __shared__ __align__(16) unsigned short actA[64 * 128];   // ping 16KB
    __shared__ __align__(16) unsigned short actB[64 * 128];   // pong 16KB
    __shared__ __align__(16) unsigned short lw0s[54 * 64];
    __shared__ __align__(16) unsigned short lw1s[64 * 64];
    __shared__ __align__(16) unsigned short lw2s[64 * 64];
    __shared__ __align__(16) unsigned short lw3s[64 * 4];
    __shared__ float lbs[200];

    const int t = threadIdx.x;

    // ---- stage weights (all threads) ----
    stage_bf(lw0s, mw0, 1728, t);
    stage_bf(lw1s, mw1, 2048, t);
    stage_bf(lw2s, mw2, 2048, t);
    for (int i = t; i < 256; i += 256) {
        const int c = i >> 2, o = i & 3;
        lw3s[i] = (o < 3) ? (unsigned short)f2bf_u(mw3[c * 3 + o]) : 0;
    }
    if (t < 64) { lbs[t] = mb0[t]; lbs[64 + t] = mb1[t]; lbs[128 + t] = mb2[t]; }
    if (t < 4)  { lbs[192 + t] = (t < 3) ? mb3[t] : 0.f; }

    // ---- phase A: per-sample setup (threads 0-127) ----
    bool live = false, act = false;
    float alpha = 0.f, ndx = 0.f, ndy = 0.f, ndz = 0.f;
    float nsx = 0.f, nsy = 0.f, nsz = 0.f, depth = 0.f;
    if (t < 128) {
        const int s = blockIdx.x * 128 + t;
        live = (s < total);
        float hf[54];
        if (live) {
            const int r = s / S_SAMPLES;
            const int j = s - r * S_SAMPLES;

            const float ox = ro[r * 3 + 0], oy = ro[r * 3 + 1], oz = ro[r * 3 + 2];
            const float dx = rd[r * 3 + 0], dy = rd[r * 3 + 1], dz = rd[r * 3 + 2];
            const float vx = vd[r * 3 + 0], vy = vd[r * 3 + 1], vz = vd[r * 3 + 2];

            const float vecx = (dx == 0.f) ? 1e-6f : dx;
            const float vecy = (dy == 0.f) ? 1e-6f : dy;
            const float vecz = (dz == 0.f) ? 1e-6f : dz;
            const float rax = (1.f - ox) / vecx, rbx = (-1.f - ox) / vecx;
            const float ray2 = (1.f - oy) / vecy, rby = (-1.f - oy) / vecy;
            const float raz = (1.f - oz) / vecz, rbz = (-1.f - oz) / vecz;
            float tmin = fmaxf(fmaxf(fminf(rax, rbx), fminf(ray2, rby)), fminf(raz, rbz));
            float tmax = fminf(fminf(fmaxf(rax, rbx), fmaxf(ray2, rby)), fmaxf(raz, rbz));
            tmin = fminf(fmaxf(tmin, 0.2f), 6.0f);
            tmax = fminf(fmaxf(tmax, 0.2f), 6.0f);
            const bool mask_ray = (tmax <= tmin);

            const float ndr = sqrtf(dx * dx + dy * dy + dz * dz);
            const float interpx = tmin + (STEP_VOX * (float)j) / ndr;
            const float px = ox + dx * interpx;
            const float py = oy + dy * interpx;
            const float pz = oz + dz * interpx;
            const bool outbox = mask_ray || (px < -1.f) || (px > 1.f) || (py < -1.f) ||
                                (py > 1.f) || (pz < -1.f) || (pz > 1.f);
            act = !outbox;
            if (act) {
                const float ux = fminf(fmaxf((px + 1.f) * 63.5f, 0.f), 127.f);
                const float uy = fminf(fmaxf((py + 1.f) * 63.5f, 0.f), 127.f);
                const float uz = fminf(fmaxf((pz + 1.f) * 63.5f, 0.f), 127.f);
                const int ix = min(max((int)floorf(ux), 0), 126);
                const int iy = min(max((int)floorf(uy), 0), 126);
                const int iz = min(max((int)floorf(uz), 0), 126);
                const float fx = ux - (float)ix, fy = uy - (float)iy, fz = uz - (float)iz;

                float lat[15];
#pragma unroll
                for (int q = 0; q < 15; ++q) lat[q] = 0.f;
                float na0 = 0.f, na1 = 0.f, na2 = 0.f;
                float c0v[8];
#pragma unroll
                for (int cn = 0; cn < 8; ++cn) {
                    const int adx = cn >> 2, ady = (cn >> 1) & 1, adz = cn & 1;
                    const int vox = ((ix + adx) * 128 + (iy + ady)) * 128 + (iz + adz);
                    const float w = (adx ? fx : 1.f - fx) * (ady ? fy : 1.f - fy) * (adz ? fz : 1.f - fz);
                    c0v[cn] = dens[vox];
                    const uint4* cp = (const uint4*)(featb + (size_t)vox * 16);
                    const uint4 q0 = cp[0], q1 = cp[1];
                    lat[0]  = fmaf(w, bf_hi(q0.x), lat[0]);
                    lat[1]  = fmaf(w, bf_lo(q0.y), lat[1]);
                    lat[2]  = fmaf(w, bf_hi(q0.y), lat[2]);
                    lat[3]  = fmaf(w, bf_lo(q0.z), lat[3]);
                    lat[4]  = fmaf(w, bf_hi(q0.z), lat[4]);
                    lat[5]  = fmaf(w, bf_lo(q0.w), lat[5]);
                    lat[6]  = fmaf(w, bf_hi(q0.w), lat[6]);
                    lat[7]  = fmaf(w, bf_lo(q1.x), lat[7]);
                    lat[8]  = fmaf(w, bf_hi(q1.x), lat[8]);
                    lat[9]  = fmaf(w, bf_lo(q1.y), lat[9]);
                    lat[10] = fmaf(w, bf_hi(q1.y), lat[10]);
                    lat[11] = fmaf(w, bf_lo(q1.z), lat[11]);
                    lat[12] = fmaf(w, bf_hi(q1.z), lat[12]);
                    lat[13] = fmaf(w, bf_lo(q1.w), lat[13]);
                    lat[14] = fmaf(w, bf_hi(q1.w), lat[14]);
                    const float* np_ = normals + (size_t)vox * 3;
                    na0 = fmaf(w, np_[0], na0);
                    na1 = fmaf(w, np_[1], na1);
                    na2 = fmaf(w, np_[2], na2);
                }

                const float c00 = c0v[0] * (1.f - fz) + c0v[1] * fz;
                const float c01 = c0v[2] * (1.f - fz) + c0v[3] * fz;
                const float c10 = c0v[4] * (1.f - fz) + c0v[5] * fz;
                const float c11 = c0v[6] * (1.f - fz) + c0v[7] * fz;
                const float e0 = c00 * (1.f - fy) + c01 * fy;
                const float e1 = c10 * (1.f - fy) + c11 * fy;
                const float d0 = e0 * (1.f - fx) + e1 * fx;
                const float dfx = e1 - e0;
                const float dfy = (c01 - c00) * (1.f - fx) + (c11 - c10) * fx;
                const float dfz = ((c0v[1] - c0v[0]) * (1.f - fy) + (c0v[3] - c0v[2]) * fy) * (1.f - fx)
                                + ((c0v[5] - c0v[4]) * (1.f - fy) + (c0v[7] - c0v[6]) * fy) * fx;

                const float zin = d0 + ACT_SHIFT;
                const float splus = fmaxf(zin, 0.f) + log1pf(__expf(-fabsf(zin)));
                const float e = __expf(-splus * 0.5f);
                alpha = 1.f - e;
                const float sig = 1.f / (1.f + __expf(-zin));
                const float dad = e * 0.5f * sig;
                const float gx = dad * dfx * 63.5f;
                const float gy = dad * dfy * 63.5f;
                const float gz = dad * dfz * 63.5f;
                const float gn = sqrtf(gx * gx + gy * gy + gz * gz);
                const float gi = 1.f / fmaxf(gn, 1e-12f);
                ndx = -gx * gi; ndy = -gy * gi; ndz = -gz * gi;

                const float nn = sqrtf(na0 * na0 + na1 * na1 + na2 * na2);
                const float ni = 1.f / fmaxf(nn, 1e-12f);
                nsx = -na0 * ni; nsy = -na1 * ni; nsz = -na2 * ni;

                const float dotv = -(vx * ndx + vy * ndy + vz * ndz);
                const float rx = 2.f * dotv * ndx + vx;
                const float ry = 2.f * dotv * ndy + vy;
                const float rz = 2.f * dotv * ndz + vz;

#pragma unroll
                for (int q = 0; q < 15; ++q) hf[q] = lat[q];
                hf[15] = rx; hf[16] = ry; hf[17] = rz;
#pragma unroll
                for (int fi = 0; fi < 6; ++fi) {
                    const float fr = (float)(1 << fi);
                    hf[18 + fi * 6 + 0] = __sinf(rx * fr);
                    hf[18 + fi * 6 + 1] = __sinf(ry * fr);
                    hf[18 + fi * 6 + 2] = __sinf(rz * fr);
                    hf[18 + fi * 6 + 3] = __cosf(rx * fr);
                    hf[18 + fi * 6 + 4] = __cosf(ry * fr);
                    hf[18 + fi * 6 + 5] = __cosf(rz * fr);
                }
                depth = interpx * ndr;
            }
        }
        if (act) {
#pragma unroll
            for (int k = 0; k < 54; ++k) actA[k * 128 + t] = (unsigned short)f2bf_u(hf[k]);
        } else {
#pragma unroll
            for (int k = 0; k < 54; ++k) actA[k * 128 + t] = 0;
        }
    }
    __syncthreads();

    // ---- phase B: GEMM layers ----
    const int sx = t & 15, ty = t >> 4;
    gemm_layer(actA, actB, lw0s, lbs,       54, sx, ty);
    __syncthreads();
    gemm_layer(actB, actA, lw1s, lbs + 64,  64, sx, ty);
    __syncthreads();
    gemm_layer(actA, actB, lw2s, lbs + 128, 64, sx, ty);
    __syncthreads();

    // ---- final layer (64->3) + sigmoid + record write ----
    if (t < 128 && live) {
        const int s = blockIdx.x * 128 + t;
        float* so = sbuf + (size_t)s * 12;
        if (act) {
            float r0 = lbs[192], r1 = lbs[193], r2 = lbs[194];
#pragma unroll 8
            for (int c = 0; c < 64; ++c) {
                const float h = bf2f(actB[c * 128 + t]);
                const uint2 wu = *(const uint2*)(lw3s + c * 4);
                r0 = fmaf(h, bf_lo(wu.x), r0);
                r1 = fmaf(h, bf_hi(wu.x), r1);
                r2 = fmaf(h, bf_lo(wu.y), r2);
            }
            so[0] = alpha;
            so[1] = 1.f / (1.f + __expf(-r0));
            so[2] = 1.f / (1.f + __expf(-r1));
            so[3] = 1.f / (1.f + __expf(-r2));
            so[4] = ndx; so[5] = ndy; so[6] = ndz;
            so[7] = nsx; so[8] = nsy; so[9] = nsz;
            so[10] = depth;
            so[11] = 0.f;
        } else {
#pragma unroll
            for (int q = 0; q < 12; ++q) so[q] = 0.f;
        }
    }
}

// ============================================================================
// Kernel 4: per-ray compositing (wave per ray; segmented product scan).
// ============================================================================
__global__ __launch_bounds__(64) void reduce_kernel(const float* __restrict__ sbuf,
                                                    float* __restrict__ out)
{
    const int r = blockIdx.x;
    const int lane = threadIdx.x;
    const int per = (S_SAMPLES + 63) / 64;   // 7
    const int j0 = lane * per;
    const int j1 = min(S_SAMPLES, j0 + per);

    float p = 1.f;
    for (int j = j0; j < j1; ++j) {
        const float a = sbuf[((size_t)r * S_SAMPLES + j) * 12];
        p *= fmaxf(1.f - a, 1e-10f);
    }
    float scan = p;
#pragma unroll
    for (int off = 1; off < 64; off <<= 1) {
        const float nv = __shfl_up(scan, (unsigned)off, 64);
        if (lane >= off) scan *= nv;
    }
    const float total = __shfl(scan, 63, 64);
    float pref = __shfl_up(scan, 1u, 64);
    if (lane == 0) pref = 1.f;

    float s0 = 0, s1 = 0, s2 = 0, s3 = 0, s4 = 0, s5 = 0, s6 = 0, s7 = 0, s8 = 0, s9 = 0, s10 = 0;
    for (int j = j0; j < j1; ++j) {
        const float* sp_ = sbuf + ((size_t)r * S_SAMPLES + j) * 12;
        const float a = sp_[0];
        const float w = a * pref;
        pref *= fmaxf(1.f - a, 1e-10f);
        s0 = fmaf(w, sp_[1], s0);
        s1 = fmaf(w, sp_[2], s1);
        s2 = fmaf(w, sp_[3], s2);
        s3 = fmaf(w, sp_[10], s3);
        s4 += w;
        s5 = fmaf(w, sp_[4], s5);
        s6 = fmaf(w, sp_[5], s6);
        s7 = fmaf(w, sp_[6], s7);
        s8 = fmaf(w, sp_[7], s8);
        s9 = fmaf(w, sp_[8], s9);
        s10 = fmaf(w, sp_[9], s10);
    }
#pragma unroll
    for (int m = 32; m >= 1; m >>= 1) {
        s0 += __shfl_xor(s0, m, 64);
        s1 += __shfl_xor(s1, m, 64);
        s2 += __shfl_xor(s2, m, 64);
        s3 += __shfl_xor(s3, m, 64);
        s4 += __shfl_xor(s4, m, 64);
        s5 += __shfl_xor(s5, m, 64);
        s6 += __shfl_xor(s6, m, 64);
        s7 += __shfl_xor(s7, m, 64);
        s8 += __shfl_xor(s8, m, 64);
        s9 += __shfl_xor(s9, m, 64);
        s10 += __shfl_xor(s10, m, 64);
    }
    if (lane == 0) {
        const float dm = s3 + total * 6.0f;
        out[r * 12 + 0] = s0 + total;
        out[r * 12 + 1] = s1 + total;
        out[r * 12 + 2] = s2 + total;
        out[r * 12 + 3] = dm;
        out[r * 12 + 4] = 1.f / dm;
        out[r * 12 + 5] = s4;
        out[r * 12 + 6] = s5; out[r * 12 + 7] = s6; out[r * 12 + 8] = s7;
        out[r * 12 + 9] = s8; out[r * 12 + 10] = s9; out[r * 12 + 11] = s10;
    }
}

// ============================================================================
extern "C" void kernel_launch(void* const* d_in, const int* in_sizes, int n_in,
                              void* d_out, int out_size, void* d_ws, size_t ws_size,
                              hipStream_t stream)
{
    (void)n_in; (void)out_size; (void)ws_size;
    const float* rays_o   = (const float*)d_in[0];
    const float* rays_d   = (const float*)d_in[1];
    const float* viewdirs = (const float*)d_in[2];
    const float* grid     = (const float*)d_in[3];
    const float* c1_w  = (const float*)d_in[4];
    const float* c1_b  = (const float*)d_in[5];
    const float* bn1_g = (const float*)d_in[6];
    const float* bn1_b = (const float*)d_in[7];
    const float* pr1_a = (const float*)d_in[8];
    const float* c2_w  = (const float*)d_in[9];
    const float* c2_b  = (const float*)d_in[10];
    const float* bn2_g = (const float*)d_in[11];
    const float* bn2_b = (const float*)d_in[12];
    const float* pr2_a = (const float*)d_in[13];
    const float* c3_w  = (const float*)d_in[14];
    const float* c3_b  = (const float*)d_in[15];
    const float* mw0 = (const float*)d_in[16];
    const float* mb0 = (const float*)d_in[17];
    const float* mw1 = (const float*)d_in[18];
    const float* mb1 = (const float*)d_in[19];
    const float* mw2 = (const float*)d_in[20];
    const float* mb2 = (const float*)d_in[21];
    const float* mw3 = (const float*)d_in[22];
    const float* mb3 = (const float*)d_in[23];

    const int N = in_sizes[0] / 3;   // 1024 rays
    const int total = N * S_SAMPLES;

    float* wsf = (float*)d_ws;
    unsigned short* featb = (unsigned short*)wsf;                   // 128^3*16 bf16
    float* dens    = wsf + (size_t)16777216;                        // 128^3 fp32
    unsigned short* A_g = (unsigned short*)(wsf + (size_t)18874368);
    float* normals = wsf + (size_t)18874368;                        // alias (A_g dead)
    float* sbuf    = wsf + (size_t)25165824;                        // N*447*12
    float* w1t = wsf + (size_t)35651584;
    float* w2t = w1t + 1024;
    float* w3t = w2t + 5120;
    float* b3p = w3t + 18432;

    prep_kernel<<<1, 256, 0, stream>>>(c1_w, c2_w, c3_w, c3_b, w1t, w2t, w3t, b3p);
    conv12_kernel<<<4096, 128, 0, stream>>>(grid, w1t, c1_b, bn1_g, bn1_b, pr1_a,
                                            w2t, c2_b, bn2_g, bn2_b, pr2_a, A_g);
    conv3_kernel<<<4096, 128, 0, stream>>>(A_g, grid, w3t, b3p, featb, dens);
    sobel_kernel<<<8192, 256, 0, stream>>>(dens, normals);
    const int sblocks = (total + 127) / 128;
    sample_kernel<<<sblocks, 256, 0, stream>>>(rays_o, rays_d, viewdirs, featb, dens, normals,
                                               mw0, mb0, mw1, mb1, mw2, mb2, mw3, mb3,
                                               sbuf, total);
    reduce_kernel<<<N, 64, 0, stream>>>(sbuf, (float*)d_out);
}

// Round 6
// 468.299 us; speedup vs baseline: 8.9059x; 1.3080x over previous
//
#include <hip/hip_runtime.h>
#include <math.h>

// ---- constants from the reference ----
#define S_SAMPLES 447                      // int(norm([129]*3)/0.5)+1
#define ACT_SHIFT -9.210240366971207f      // log(1/(1-1e-4) - 1)
#define BN_SCALE_C 0.9999950000374997f     // (1+1e-5)^-0.5
#define STEP_VOX 0.015625f                 // STEPSIZE * VOXEL = 0.5 * (2/64)

__device__ __forceinline__ unsigned f2bf_u(float f) {
    unsigned u = __float_as_uint(f);
    return (u + 0x7fffu + ((u >> 16) & 1u)) >> 16;   // RNE, low 16 bits
}
__device__ __forceinline__ float bf2f(unsigned short u) {
    return __uint_as_float(((unsigned)u) << 16);
}
__device__ __forceinline__ float bf_lo(unsigned u) { return __uint_as_float(u << 16); }
__device__ __forceinline__ float bf_hi(unsigned u) { return __uint_as_float(u & 0xffff0000u); }

typedef __attribute__((ext_vector_type(8))) short bf16x8;   // MFMA A/B frag (4 VGPRs)
typedef __attribute__((ext_vector_type(4))) float f32x4;    // MFMA C/D frag

// ============================================================================
// Kernel 0: prep — weight transposes.
// conv: w1t[16][64], w2t[80][64], w3t[144][128] (pixel-shuffle perm baked in).
// MLP (bf16, for MFMA B-frags): mXt[o][k] k-contiguous, K zero-padded to 64.
// ============================================================================
__global__ __launch_bounds__(256) void prep_kernel(
    const float* __restrict__ w1, const float* __restrict__ w2,
    const float* __restrict__ w3, const float* __restrict__ b3,
    const float* __restrict__ mw0, const float* __restrict__ mw1,
    const float* __restrict__ mw2,
    float* __restrict__ w1t, float* __restrict__ w2t,
    float* __restrict__ w3t, float* __restrict__ b3p,
    unsigned short* __restrict__ m0t, unsigned short* __restrict__ m1t,
    unsigned short* __restrict__ m2t)
{
    const int t = threadIdx.x;
    for (int idx = t; idx < 1024; idx += 256) {          // w1 [64][16] -> w1t [16][64]
        const int o = idx >> 4, k = idx & 15;
        w1t[k * 64 + o] = w1[idx];
    }
    for (int idx = t; idx < 5120; idx += 256) {          // w2 [64][80] -> w2t [80][64]
        const int o = idx / 80, k = idx % 80;
        w2t[k * 64 + o] = w2[idx];
    }
    for (int idx = t; idx < 18432; idx += 256) {         // w3 [128][144] -> w3t [144][128] permuted
        const int o = idx / 144, k = idx % 144;
        const int n = (o & 7) * 16 + (o >> 3);
        w3t[k * 128 + n] = w3[idx];
    }
    if (t < 128) {
        const int o = t;
        b3p[(o & 7) * 16 + (o >> 3)] = b3[o];
    }
    for (int idx = t; idx < 4096; idx += 256) {          // mw0 [54][64] -> m0t [64 o][64 k]
        const int o = idx >> 6, k = idx & 63;
        m0t[o * 64 + k] = (k < 54) ? (unsigned short)f2bf_u(mw0[k * 64 + o]) : 0;
    }
    for (int idx = t; idx < 4096; idx += 256) {          // mw1 [64][64] -> m1t [o][k]
        const int o = idx >> 6, k = idx & 63;
        m1t[o * 64 + k] = (unsigned short)f2bf_u(mw1[k * 64 + o]);
    }
    for (int idx = t; idx < 4096; idx += 256) {          // mw2 [64][64] -> m2t [o][k]
        const int o = idx >> 6, k = idx & 63;
        m2t[o * 64 + k] = (unsigned short)f2bf_u(mw2[k * 64 + o]);
    }
}

// ============================================================================
// Kernel 1a: conv1+conv2 tiled GEMMs (thread = 8 voxels x 4 channels).
// Writes A_g bf16 [128 rows][262144]: rows 0-63 = x1, 64-127 = x2.
// ============================================================================
__global__ __launch_bounds__(128, 2) void conv12_kernel(
    const float* __restrict__ grid,
    const float* __restrict__ w1t, const float* __restrict__ b1,
    const float* __restrict__ g1, const float* __restrict__ bb1, const float* __restrict__ a1,
    const float* __restrict__ w2t, const float* __restrict__ b2,
    const float* __restrict__ g2, const float* __restrict__ bb2, const float* __restrict__ a2,
    unsigned short* __restrict__ A_g)
{
    __shared__ float Gt[16 * 64];
    __shared__ float X1t[64 * 64];
    const int t = threadIdx.x;
    const int v0 = blockIdx.x * 64;
    const int vv = t & 63;

#pragma unroll
    for (int i = 0; i < 8; ++i) {
        const int c = 2 * i + (t >> 6);
        Gt[c * 64 + vv] = grid[(size_t)c * 262144 + v0 + vv];
    }
    __syncthreads();

    const int tx = t & 7, ty = t >> 3;
    const int vq = 8 * tx, cq = 4 * ty;
    const float4* w1t4 = (const float4*)w1t;
    const float4* w2t4 = (const float4*)w2t;

    float acc1[8][4];
#pragma unroll
    for (int j = 0; j < 4; ++j) {
        const float bj = b1[cq + j];
#pragma unroll
        for (int i = 0; i < 8; ++i) acc1[i][j] = bj;
    }
#pragma unroll 8
    for (int k = 0; k < 16; ++k) {
        const float4 av0 = *(const float4*)&Gt[k * 64 + vq];
        const float4 av1 = *(const float4*)&Gt[k * 64 + vq + 4];
        const float4 wv = w1t4[k * 16 + ty];
        const float a[8] = {av0.x, av0.y, av0.z, av0.w, av1.x, av1.y, av1.z, av1.w};
        const float w[4] = {wv.x, wv.y, wv.z, wv.w};
#pragma unroll
        for (int i = 0; i < 8; ++i)
#pragma unroll
            for (int j = 0; j < 4; ++j) acc1[i][j] = fmaf(a[i], w[j], acc1[i][j]);
    }
#pragma unroll
    for (int j = 0; j < 4; ++j) {
        const int c = cq + j;
        const float gs = BN_SCALE_C * g1[c], bb = bb1[c], al = a1[c];
        float vals[8];
#pragma unroll
        for (int i = 0; i < 8; ++i) {
            float x = acc1[i][j] * gs + bb;
            vals[i] = (x >= 0.f) ? x : al * x;
        }
        *(float4*)&X1t[c * 64 + vq]     = make_float4(vals[0], vals[1], vals[2], vals[3]);
        *(float4*)&X1t[c * 64 + vq + 4] = make_float4(vals[4], vals[5], vals[6], vals[7]);
        uint4 st;
        st.x = f2bf_u(vals[0]) | (f2bf_u(vals[1]) << 16);
        st.y = f2bf_u(vals[2]) | (f2bf_u(vals[3]) << 16);
        st.z = f2bf_u(vals[4]) | (f2bf_u(vals[5]) << 16);
        st.w = f2bf_u(vals[6]) | (f2bf_u(vals[7]) << 16);
        *(uint4*)(A_g + (size_t)c * 262144 + v0 + vq) = st;
    }
    __syncthreads();

    float acc2[8][4];
#pragma unroll
    for (int j = 0; j < 4; ++j) {
        const float bj = b2[cq + j];
#pragma unroll
        for (int i = 0; i < 8; ++i) acc2[i][j] = bj;
    }
#pragma unroll 4
    for (int k = 0; k < 80; ++k) {
        const float* arow = (k < 64) ? &X1t[k * 64] : &Gt[(k - 64) * 64];
        const float4 av0 = *(const float4*)&arow[vq];
        const float4 av1 = *(const float4*)&arow[vq + 4];
        const float4 wv = w2t4[k * 16 + ty];
        const float a[8] = {av0.x, av0.y, av0.z, av0.w, av1.x, av1.y, av1.z, av1.w};
        const float w[4] = {wv.x, wv.y, wv.z, wv.w};
#pragma unroll
        for (int i = 0; i < 8; ++i)
#pragma unroll
            for (int j = 0; j < 4; ++j) acc2[i][j] = fmaf(a[i], w[j], acc2[i][j]);
    }
#pragma unroll
    for (int j = 0; j < 4; ++j) {
        const int c = cq + j;
        const float gs = BN_SCALE_C * g2[c], bb = bb2[c], al = a2[c];
        float vals[8];
#pragma unroll
        for (int i = 0; i < 8; ++i) {
            float x = acc2[i][j] * gs + bb;
            vals[i] = (x >= 0.f) ? x : al * x;
        }
        uint4 st;
        st.x = f2bf_u(vals[0]) | (f2bf_u(vals[1]) << 16);
        st.y = f2bf_u(vals[2]) | (f2bf_u(vals[3]) << 16);
        st.z = f2bf_u(vals[4]) | (f2bf_u(vals[5]) << 16);
        st.w = f2bf_u(vals[6]) | (f2bf_u(vals[7]) << 16);
        *(uint4*)(A_g + (size_t)(64 + c) * 262144 + v0 + vq) = st;
    }
}

// ============================================================================
// Kernel 1b: conv3 tiled GEMM + pixel-shuffle epilogue (thread = 8v x 8ch).
// ============================================================================
__global__ __launch_bounds__(128, 2) void conv3_kernel(
    const unsigned short* __restrict__ A_g, const float* __restrict__ grid,
    const float* __restrict__ w3t, const float* __restrict__ b3p,
    unsigned short* __restrict__ featb, float* __restrict__ dens)
{
    __shared__ float At[144 * 64];
    const int t = threadIdx.x;
    const int v0 = blockIdx.x * 64;
    const int vv = t & 63;

#pragma unroll
    for (int i = 0; i < 72; ++i) {
        const int k = 2 * i + (t >> 6);
        float val;
        if (k < 128) val = bf2f(A_g[(size_t)k * 262144 + v0 + vv]);
        else         val = grid[(size_t)(k - 128) * 262144 + v0 + vv];
        At[k * 64 + vv] = val;
    }
    __syncthreads();

    const int tx = t & 7, ty = t >> 3;
    const int vq = 8 * tx, cq = 8 * ty;
    const float4* w3t4 = (const float4*)w3t;

    float acc[8][8];
    {
        const float4 b0 = *(const float4*)&b3p[cq];
        const float4 b1v = *(const float4*)&b3p[cq + 4];
        const float bj[8] = {b0.x, b0.y, b0.z, b0.w, b1v.x, b1v.y, b1v.z, b1v.w};
#pragma unroll
        for (int i = 0; i < 8; ++i)
#pragma unroll
            for (int j = 0; j < 8; ++j) acc[i][j] = bj[j];
    }

#pragma unroll 4
    for (int k = 0; k < 144; ++k) {
        const float4 av0 = *(const float4*)&At[k * 64 + vq];
        const float4 av1 = *(const float4*)&At[k * 64 + vq + 4];
        const float4 wv0 = w3t4[k * 32 + 2 * ty];
        const float4 wv1 = w3t4[k * 32 + 2 * ty + 1];
        const float a[8] = {av0.x, av0.y, av0.z, av0.w, av1.x, av1.y, av1.z, av1.w};
        const float w[8] = {wv0.x, wv0.y, wv0.z, wv0.w, wv1.x, wv1.y, wv1.z, wv1.w};
#pragma unroll
        for (int i = 0; i < 8; ++i)
#pragma unroll
            for (int j = 0; j < 8; ++j) acc[i][j] = fmaf(a[i], w[j], acc[i][j]);
    }

    const int s = ty >> 1;
    const int l0 = 8 * (ty & 1);
    const int d2 = (s >> 2) & 1, h2 = (s >> 1) & 1, w2i = s & 1;
#pragma unroll
    for (int i = 0; i < 8; ++i) {
        const int v = v0 + vq + i;
        const int Z = v & 63, Y = (v >> 6) & 63, X = v >> 12;
        const int ubase = ((2 * X + d2) * 128 + (2 * Y + h2)) * 128 + (2 * Z + w2i);
        if (l0 == 0) dens[ubase] = acc[i][0];
        uint4 st;
        st.x = f2bf_u(acc[i][0]) | (f2bf_u(acc[i][1]) << 16);
        st.y = f2bf_u(acc[i][2]) | (f2bf_u(acc[i][3]) << 16);
        st.z = f2bf_u(acc[i][4]) | (f2bf_u(acc[i][5]) << 16);
        st.w = f2bf_u(acc[i][6]) | (f2bf_u(acc[i][7]) << 16);
        *(uint4*)(featb + (size_t)ubase * 16 + l0) = st;
    }
}

// ============================================================================
// Kernel 2: 5x5x5 Sobel (zero pad) on fp32 density + normalize.
// ============================================================================
__global__ __launch_bounds__(256) void sobel_kernel(const float* __restrict__ dens,
                                                    float* __restrict__ normals)
{
    const int v = blockIdx.x * 256 + threadIdx.x;
    const int z = v & 127, y = (v >> 7) & 127, x = v >> 14;
    const float hw[5] = {1.f, 4.f, 6.f, 4.f, 1.f};
    const float hd[5] = {-1.f, -2.f, 0.f, 2.f, 1.f};
    float sx = 0.f, sy = 0.f, sz = 0.f;
#pragma unroll
    for (int i = 0; i < 5; ++i) {
        const int xx = x + i - 2;
        if (xx < 0 || xx > 127) continue;
#pragma unroll
        for (int j = 0; j < 5; ++j) {
            const int yy = y + j - 2;
            if (yy < 0 || yy > 127) continue;
            const float* row = dens + (xx * 128 + yy) * 128;
            float sh = 0.f, sd = 0.f;
#pragma unroll
            for (int k = 0; k < 5; ++k) {
                const int zz = z + k - 2;
                if (zz < 0 || zz > 127) continue;
                const float d = row[zz];
                sh = fmaf(hw[k], d, sh);
                sd = fmaf(hd[k], d, sd);
            }
            sx = fmaf(hd[i] * hw[j], sh, sx);
            sy = fmaf(hw[i] * hd[j], sh, sy);
            sz = fmaf(hw[i] * hw[j], sd, sz);
        }
    }
    sx *= (1.f / 72.f); sy *= (1.f / 72.f); sz *= (1.f / 72.f);
    const float n = sqrtf(sx * sx + sy * sy + sz * sz);
    const float inv = 1.f / fmaxf(n, 1e-12f);
    normals[v * 3 + 0] = -sx * inv;
    normals[v * 3 + 1] = -sy * inv;
    normals[v * 3 + 2] = -sz * inv;
}

// ============================================================================
// Kernel 3: per-sample shading with MFMA MLP.
// Block = 128 threads = 128 samples (2 waves). Phase A: every thread does the
// fp32 per-sample setup and writes its hf row (bf16, K padded 54->64) into LDS
// act[s][k] (stride 72 -> conflict-free b128 frags). Phase B: 3 layers on the
// matrix pipe; per wave 4x4 tiles of mfma_f32_16x16x32_bf16 (A from LDS,
// B = pre-transposed weights from global, L1/L2-resident). Final 64->3 VALU.
// ============================================================================
__device__ __forceinline__ void mfma_layer(const unsigned short* A,
                                           unsigned short* D,
                                           const unsigned short* __restrict__ Wg,
                                           const float* __restrict__ bias,
                                           const int wv, const int lane)
{
    const int quad = lane >> 4, l16 = lane & 15;
    f32x4 acc[4][4];
#pragma unroll
    for (int nt = 0; nt < 4; ++nt) {
        const float bv = bias[16 * nt + l16];
#pragma unroll
        for (int mt = 0; mt < 4; ++mt) {
            acc[mt][nt][0] = bv; acc[mt][nt][1] = bv;
            acc[mt][nt][2] = bv; acc[mt][nt][3] = bv;
        }
    }
#pragma unroll
    for (int kq = 0; kq < 2; ++kq) {
        const int k0 = 32 * kq + 8 * quad;
        bf16x8 a[4], b[4];
#pragma unroll
        for (int mt = 0; mt < 4; ++mt) {
            const uint4 u = *(const uint4*)(A + (64 * wv + 16 * mt + l16) * 72 + k0);
            a[mt] = __builtin_bit_cast(bf16x8, u);
        }
#pragma unroll
        for (int nt = 0; nt < 4; ++nt) {
            const uint4 u = *(const uint4*)(Wg + (16 * nt + l16) * 64 + k0);
            b[nt] = __builtin_bit_cast(bf16x8, u);
        }
#pragma unroll
        for (int mt = 0; mt < 4; ++mt)
#pragma unroll
            for (int nt = 0; nt < 4; ++nt)
                acc[mt][nt] = __builtin_amdgcn_mfma_f32_16x16x32_bf16(
                    a[mt], b[nt], acc[mt][nt], 0, 0, 0);
    }
    // ReLU + store in D-layout: row = quad*4+reg (sample), col = l16 (channel)
#pragma unroll
    for (int mt = 0; mt < 4; ++mt)
#pragma unroll
        for (int nt = 0; nt < 4; ++nt)
#pragma unroll
            for (int reg = 0; reg < 4; ++reg) {
                const float v = fmaxf(acc[mt][nt][reg], 0.f);
                D[(64 * wv + 16 * mt + 4 * quad + reg) * 72 + 16 * nt + l16] =
                    (unsigned short)f2bf_u(v);
            }
}

__global__ __launch_bounds__(128) void sample_kernel(
    const float* __restrict__ ro, const float* __restrict__ rd, const float* __restrict__ vd,
    const unsigned short* __restrict__ featb, const float* __restrict__ dens,
    const float* __restrict__ normals,
    const unsigned short* __restrict__ m0t, const float* __restrict__ mb0,
    const unsigned short* __restrict__ m1t, const float* __restrict__ mb1,
    const unsigned short* __restrict__ m2t, const float* __restrict__ mb2,
    const float* __restrict__ mw3, const float* __restrict__ mb3,
    float* __restrict__ sbuf, const int total)
{
    __shared__ __align__(16) unsigned short actA[128 * 72];   // 18.4 KB
    __shared__ __align__(16) unsigned short actB[128 * 72];   // 18.4 KB

    const int t = threadIdx.x;
    const int s = blockIdx.x * 128 + t;
    const bool live = (s < total);
    bool act = false;
    float alpha = 0.f, ndx = 0.f, ndy = 0.f, ndz = 0.f;
    float nsx = 0.f, nsy = 0.f, nsz = 0.f, depth = 0.f;
    float hf[64];
#pragma unroll
    for (int q = 0; q < 64; ++q) hf[q] = 0.f;

    if (live) {
        const int r = s / S_SAMPLES;
        const int j = s - r * S_SAMPLES;

        const float ox = ro[r * 3 + 0], oy = ro[r * 3 + 1], oz = ro[r * 3 + 2];
        const float dx = rd[r * 3 + 0], dy = rd[r * 3 + 1], dz = rd[r * 3 + 2];
        const float vx = vd[r * 3 + 0], vy = vd[r * 3 + 1], vz = vd[r * 3 + 2];

        const float vecx = (dx == 0.f) ? 1e-6f : dx;
        const float vecy = (dy == 0.f) ? 1e-6f : dy;
        const float vecz = (dz == 0.f) ? 1e-6f : dz;
        const float rax = (1.f - ox) / vecx, rbx = (-1.f - ox) / vecx;
        const float ray2 = (1.f - oy) / vecy, rby = (-1.f - oy) / vecy;
        const float raz = (1.f - oz) / vecz, rbz = (-1.f - oz) / vecz;
        float tmin = fmaxf(fmaxf(fminf(rax, rbx), fminf(ray2, rby)), fminf(raz, rbz));
        float tmax = fminf(fminf(fmaxf(rax, rbx), fmaxf(ray2, rby)), fmaxf(raz, rbz));
        tmin = fminf(fmaxf(tmin, 0.2f), 6.0f);
        tmax = fminf(fmaxf(tmax, 0.2f), 6.0f);
        const bool mask_ray = (tmax <= tmin);

        const float ndr = sqrtf(dx * dx + dy * dy + dz * dz);
        const float interpx = tmin + (STEP_VOX * (float)j) / ndr;
        const float px = ox + dx * interpx;
        const float py = oy + dy * interpx;
        const float pz = oz + dz * interpx;
        const bool outbox = mask_ray || (px < -1.f) || (px > 1.f) || (py < -1.f) ||
                            (py > 1.f) || (pz < -1.f) || (pz > 1.f);
        act = !outbox;
        if (act) {
            const float ux = fminf(fmaxf((px + 1.f) * 63.5f, 0.f), 127.f);
            const float uy = fminf(fmaxf((py + 1.f) * 63.5f, 0.f), 127.f);
            const float uz = fminf(fmaxf((pz + 1.f) * 63.5f, 0.f), 127.f);
            const int ix = min(max((int)floorf(ux), 0), 126);
            const int iy = min(max((int)floorf(uy), 0), 126);
            const int iz = min(max((int)floorf(uz), 0), 126);
            const float fx = ux - (float)ix, fy = uy - (float)iy, fz = uz - (float)iz;

            float lat[15];
#pragma unroll
            for (int q = 0; q < 15; ++q) lat[q] = 0.f;
            float na0 = 0.f, na1 = 0.f, na2 = 0.f;
            float c0v[8];
#pragma unroll
            for (int cn = 0; cn < 8; ++cn) {
                const int adx = cn >> 2, ady = (cn >> 1) & 1, adz = cn & 1;
                const int vox = ((ix + adx) * 128 + (iy + ady)) * 128 + (iz + adz);
                const float w = (adx ? fx : 1.f - fx) * (ady ? fy : 1.f - fy) * (adz ? fz : 1.f - fz);
                c0v[cn] = dens[vox];
                const uint4* cp = (const uint4*)(featb + (size_t)vox * 16);
                const uint4 q0 = cp[0], q1 = cp[1];
                lat[0]  = fmaf(w, bf_hi(q0.x), lat[0]);
                lat[1]  = fmaf(w, bf_lo(q0.y), lat[1]);
                lat[2]  = fmaf(w, bf_hi(q0.y), lat[2]);
                lat[3]  = fmaf(w, bf_lo(q0.z), lat[3]);
                lat[4]  = fmaf(w, bf_hi(q0.z), lat[4]);
                lat[5]  = fmaf(w, bf_lo(q0.w), lat[5]);
                lat[6]  = fmaf(w, bf_hi(q0.w), lat[6]);
                lat[7]  = fmaf(w, bf_lo(q1.x), lat[7]);
                lat[8]  = fmaf(w, bf_hi(q1.x), lat[8]);
                lat[9]  = fmaf(w, bf_lo(q1.y), lat[9]);
                lat[10] = fmaf(w, bf_hi(q1.y), lat[10]);
                lat[11] = fmaf(w, bf_lo(q1.z), lat[11]);
                lat[12] = fmaf(w, bf_hi(q1.z), lat[12]);
                lat[13] = fmaf(w, bf_lo(q1.w), lat[13]);
                lat[14] = fmaf(w, bf_hi(q1.w), lat[14]);
                const float* np_ = normals + (size_t)vox * 3;
                na0 = fmaf(w, np_[0], na0);
                na1 = fmaf(w, np_[1], na1);
                na2 = fmaf(w, np_[2], na2);
            }

            const float c00 = c0v[0] * (1.f - fz) + c0v[1] * fz;
            const float c01 = c0v[2] * (1.f - fz) + c0v[3] * fz;
            const float c10 = c0v[4] * (1.f - fz) + c0v[5] * fz;
            const float c11 = c0v[6] * (1.f - fz) + c0v[7] * fz;
            const float e0 = c00 * (1.f - fy) + c01 * fy;
            const float e1 = c10 * (1.f - fy) + c11 * fy;
            const float d0 = e0 * (1.f - fx) + e1 * fx;
            const float dfx = e1 - e0;
            const float dfy = (c01 - c00) * (1.f - fx) + (c11 - c10) * fx;
            const float dfz = ((c0v[1] - c0v[0]) * (1.f - fy) + (c0v[3] - c0v[2]) * fy) * (1.f - fx)
                            + ((c0v[5] - c0v[4]) * (1.f - fy) + (c0v[7] - c0v[6]) * fy) * fx;

            const float zin = d0 + ACT_SHIFT;
            const float splus = fmaxf(zin, 0.f) + log1pf(__expf(-fabsf(zin)));
            const float e = __expf(-splus * 0.5f);
            alpha = 1.f - e;
            const float sig = 1.f / (1.f + __expf(-zin));
            const float dad = e * 0.5f * sig;
            const float gx = dad * dfx * 63.5f;
            const float gy = dad * dfy * 63.5f;
            const float gz = dad * dfz * 63.5f;
            const float gn = sqrtf(gx * gx + gy * gy + gz * gz);
            const float gi = 1.f / fmaxf(gn, 1e-12f);
            ndx = -gx * gi; ndy = -gy * gi; ndz = -gz * gi;

            const float nn = sqrtf(na0 * na0 + na1 * na1 + na2 * na2);
            const float ni = 1.f / fmaxf(nn, 1e-12f);
            nsx = -na0 * ni; nsy = -na1 * ni; nsz = -na2 * ni;

            const float dotv = -(vx * ndx + vy * ndy + vz * ndz);
            const float rx = 2.f * dotv * ndx + vx;
            const float ry = 2.f * dotv * ndy + vy;
            const float rz = 2.f * dotv * ndz + vz;

#pragma unroll
            for (int q = 0; q < 15; ++q) hf[q] = lat[q];
            hf[15] = rx; hf[16] = ry; hf[17] = rz;
#pragma unroll
            for (int fi = 0; fi < 6; ++fi) {
                const float fr = (float)(1 << fi);
                hf[18 + fi * 6 + 0] = __sinf(rx * fr);
                hf[18 + fi * 6 + 1] = __sinf(ry * fr);
                hf[18 + fi * 6 + 2] = __sinf(rz * fr);
                hf[18 + fi * 6 + 3] = __cosf(rx * fr);
                hf[18 + fi * 6 + 4] = __cosf(ry * fr);
                hf[18 + fi * 6 + 5] = __cosf(rz * fr);
            }
            depth = interpx * ndr;
        }
    }

    // write bf16 row (zeros where inactive / k>=54)
#pragma unroll
    for (int q = 0; q < 8; ++q) {
        uint4 st;
        st.x = f2bf_u(hf[8 * q + 0]) | (f2bf_u(hf[8 * q + 1]) << 16);
        st.y = f2bf_u(hf[8 * q + 2]) | (f2bf_u(hf[8 * q + 3]) << 16);
        st.z = f2bf_u(hf[8 * q + 4]) | (f2bf_u(hf[8 * q + 5]) << 16);
        st.w = f2bf_u(hf[8 * q + 6]) | (f2bf_u(hf[8 * q + 7]) << 16);
        *(uint4*)(actA + t * 72 + 8 * q) = st;
    }
    __syncthreads();

    const int wv = t >> 6, lane = t & 63;
    mfma_layer(actA, actB, m0t, mb0, wv, lane);
    __syncthreads();
    mfma_layer(actB, actA, m1t, mb1, wv, lane);
    __syncthreads();
    mfma_layer(actA, actB, m2t, mb2, wv, lane);
    __syncthreads();

    // final layer 64->3 + sigmoid + record
    if (live) {
        float* so = sbuf + (size_t)s * 12;
        if (act) {
            float r0 = mb3[0], r1 = mb3[1], r2 = mb3[2];
            const unsigned short* hr = actB + t * 72;
#pragma unroll
            for (int c8 = 0; c8 < 8; ++c8) {
                const uint4 hu = *(const uint4*)(hr + 8 * c8);
                const float h[8] = {bf_lo(hu.x), bf_hi(hu.x), bf_lo(hu.y), bf_hi(hu.y),
                                    bf_lo(hu.z), bf_hi(hu.z), bf_lo(hu.w), bf_hi(hu.w)};
#pragma unroll
                for (int u = 0; u < 8; ++u) {
                    const int c = 8 * c8 + u;
                    r0 = fmaf(h[u], mw3[c * 3 + 0], r0);
                    r1 = fmaf(h[u], mw3[c * 3 + 1], r1);
                    r2 = fmaf(h[u], mw3[c * 3 + 2], r2);
                }
            }
            so[0] = alpha;
            so[1] = 1.f / (1.f + __expf(-r0));
            so[2] = 1.f / (1.f + __expf(-r1));
            so[3] = 1.f / (1.f + __expf(-r2));
            so[4] = ndx; so[5] = ndy; so[6] = ndz;
            so[7] = nsx; so[8] = nsy; so[9] = nsz;
            so[10] = depth;
            so[11] = 0.f;
        } else {
#pragma unroll
            for (int q = 0; q < 12; ++q) so[q] = 0.f;
        }
    }
}

// ============================================================================
// Kernel 4: per-ray compositing (wave per ray; segmented product scan).
// ============================================================================
__global__ __launch_bounds__(64) void reduce_kernel(const float* __restrict__ sbuf,
                                                    float* __restrict__ out)
{
    const int r = blockIdx.x;
    const int lane = threadIdx.x;
    const int per = (S_SAMPLES + 63) / 64;   // 7
    const int j0 = lane * per;
    const int j1 = min(S_SAMPLES, j0 + per);

    float p = 1.f;
    for (int j = j0; j < j1; ++j) {
        const float a = sbuf[((size_t)r * S_SAMPLES + j) * 12];
        p *= fmaxf(1.f - a, 1e-10f);
    }
    float scan = p;
#pragma unroll
    for (int off = 1; off < 64; off <<= 1) {
        const float nv = __shfl_up(scan, (unsigned)off, 64);
        if (lane >= off) scan *= nv;
    }
    const float total = __shfl(scan, 63, 64);
    float pref = __shfl_up(scan, 1u, 64);
    if (lane == 0) pref = 1.f;

    float s0 = 0, s1 = 0, s2 = 0, s3 = 0, s4 = 0, s5 = 0, s6 = 0, s7 = 0, s8 = 0, s9 = 0, s10 = 0;
    for (int j = j0; j < j1; ++j) {
        const float* sp_ = sbuf + ((size_t)r * S_SAMPLES + j) * 12;
        const float a = sp_[0];
        const float w = a * pref;
        pref *= fmaxf(1.f - a, 1e-10f);
        s0 = fmaf(w, sp_[1], s0);
        s1 = fmaf(w, sp_[2], s1);
        s2 = fmaf(w, sp_[3], s2);
        s3 = fmaf(w, sp_[10], s3);
        s4 += w;
        s5 = fmaf(w, sp_[4], s5);
        s6 = fmaf(w, sp_[5], s6);
        s7 = fmaf(w, sp_[6], s7);
        s8 = fmaf(w, sp_[7], s8);
        s9 = fmaf(w, sp_[8], s9);
        s10 = fmaf(w, sp_[9], s10);
    }
#pragma unroll
    for (int m = 32; m >= 1; m >>= 1) {
        s0 += __shfl_xor(s0, m, 64);
        s1 += __shfl_xor(s1, m, 64);
        s2 += __shfl_xor(s2, m, 64);
        s3 += __shfl_xor(s3, m, 64);
        s4 += __shfl_xor(s4, m, 64);
        s5 += __shfl_xor(s5, m, 64);
        s6 += __shfl_xor(s6, m, 64);
        s7 += __shfl_xor(s7, m, 64);
        s8 += __shfl_xor(s8, m, 64);
        s9 += __shfl_xor(s9, m, 64);
        s10 += __shfl_xor(s10, m, 64);
    }
    if (lane == 0) {
        const float dm = s3 + total * 6.0f;
        out[r * 12 + 0] = s0 + total;
        out[r * 12 + 1] = s1 + total;
        out[r * 12 + 2] = s2 + total;
        out[r * 12 + 3] = dm;
        out[r * 12 + 4] = 1.f / dm;
        out[r * 12 + 5] = s4;
        out[r * 12 + 6] = s5; out[r * 12 + 7] = s6; out[r * 12 + 8] = s7;
        out[r * 12 + 9] = s8; out[r * 12 + 10] = s9; out[r * 12 + 11] = s10;
    }
}

// ============================================================================
extern "C" void kernel_launch(void* const* d_in, const int* in_sizes, int n_in,
                              void* d_out, int out_size, void* d_ws, size_t ws_size,
                              hipStream_t stream)
{
    (void)n_in; (void)out_size; (void)ws_size;
    const float* rays_o   = (const float*)d_in[0];
    const float* rays_d   = (const float*)d_in[1];
    const float* viewdirs = (const float*)d_in[2];
    const float* grid     = (const float*)d_in[3];
    const float* c1_w  = (const float*)d_in[4];
    const float* c1_b  = (const float*)d_in[5];
    const float* bn1_g = (const float*)d_in[6];
    const float* bn1_b = (const float*)d_in[7];
    const float* pr1_a = (const float*)d_in[8];
    const float* c2_w  = (const float*)d_in[9];
    const float* c2_b  = (const float*)d_in[10];
    const float* bn2_g = (const float*)d_in[11];
    const float* bn2_b = (const float*)d_in[12];
    const float* pr2_a = (const float*)d_in[13];
    const float* c3_w  = (const float*)d_in[14];
    const float* c3_b  = (const float*)d_in[15];
    const float* mw0 = (const float*)d_in[16];
    const float* mb0 = (const float*)d_in[17];
    const float* mw1 = (const float*)d_in[18];
    const float* mb1 = (const float*)d_in[19];
    const float* mw2 = (const float*)d_in[20];
    const float* mb2 = (const float*)d_in[21];
    const float* mw3 = (const float*)d_in[22];
    const float* mb3 = (const float*)d_in[23];

    const int N = in_sizes[0] / 3;   // 1024 rays
    const int total = N * S_SAMPLES;

    float* wsf = (float*)d_ws;
    unsigned short* featb = (unsigned short*)wsf;                   // 128^3*16 bf16
    float* dens    = wsf + (size_t)16777216;                        // 128^3 fp32
    unsigned short* A_g = (unsigned short*)(wsf + (size_t)18874368);
    float* normals = wsf + (size_t)18874368;                        // alias (A_g dead)
    float* sbuf    = wsf + (size_t)25165824;                        // N*447*12
    float* w1t = wsf + (size_t)35651584;
    float* w2t = w1t + 1024;
    float* w3t = w2t + 5120;
    float* b3p = w3t + 18432;
    unsigned short* m0t = (unsigned short*)(wsf + (size_t)35676288);   // 4096 bf16
    unsigned short* m1t = (unsigned short*)(wsf + (size_t)35678336);
    unsigned short* m2t = (unsigned short*)(wsf + (size_t)35680384);

    prep_kernel<<<1, 256, 0, stream>>>(c1_w, c2_w, c3_w, c3_b, mw0, mw1, mw2,
                                       w1t, w2t, w3t, b3p, m0t, m1t, m2t);
    conv12_kernel<<<4096, 128, 0, stream>>>(grid, w1t, c1_b, bn1_g, bn1_b, pr1_a,
                                            w2t, c2_b, bn2_g, bn2_b, pr2_a, A_g);
    conv3_kernel<<<4096, 128, 0, stream>>>(A_g, grid, w3t, b3p, featb, dens);
    sobel_kernel<<<8192, 256, 0, stream>>>(dens, normals);
    const int sblocks = (total + 127) / 128;
    sample_kernel<<<sblocks, 128, 0, stream>>>(rays_o, rays_d, viewdirs, featb, dens, normals,
                                               m0t, mb0, m1t, mb1, m2t, mb2, mw3, mb3,
                                               sbuf, total);
    reduce_kernel<<<N, 64, 0, stream>>>(sbuf, (float*)d_out);
}

// Round 7
// 400.908 us; speedup vs baseline: 10.4029x; 1.1681x over previous
//
#include <hip/hip_runtime.h>
#include <math.h>

// ---- constants from the reference ----
#define S_SAMPLES 447                      // int(norm([129]*3)/0.5)+1
#define ACT_SHIFT -9.210240366971207f      // log(1/(1-1e-4) - 1)
#define BN_SCALE_C 0.9999950000374997f     // (1+1e-5)^-0.5
#define STEP_VOX 0.015625f                 // STEPSIZE * VOXEL = 0.5 * (2/64)

__device__ __forceinline__ unsigned f2bf_u(float f) {
    unsigned u = __float_as_uint(f);
    return (u + 0x7fffu + ((u >> 16) & 1u)) >> 16;   // RNE, low 16 bits
}
__device__ __forceinline__ float bf2f(unsigned short u) {
    return __uint_as_float(((unsigned)u) << 16);
}
__device__ __forceinline__ float bf_lo(unsigned u) { return __uint_as_float(u << 16); }
__device__ __forceinline__ float bf_hi(unsigned u) { return __uint_as_float(u & 0xffff0000u); }

typedef __attribute__((ext_vector_type(8))) short bf16x8;   // MFMA A/B frag (4 VGPRs)
typedef __attribute__((ext_vector_type(4))) float f32x4;    // MFMA C/D frag

// ============================================================================
// Kernel 0: prep — weight transposes.
// conv: w1t[16][64], w2t[80][64] fp32.
// conv3 B: w3b[n=128][k=160] bf16, n = pixel-shuffle perm (n = s*16+l, o=l*8+s),
//          k<144 from w3, else 0. b3p[n] fp32.
// MLP: mXt[o][k] bf16, K zero-padded to 64.
// ============================================================================
__global__ __launch_bounds__(256) void prep_kernel(
    const float* __restrict__ w1, const float* __restrict__ w2,
    const float* __restrict__ w3, const float* __restrict__ b3,
    const float* __restrict__ mw0, const float* __restrict__ mw1,
    const float* __restrict__ mw2,
    float* __restrict__ w1t, float* __restrict__ w2t,
    unsigned short* __restrict__ w3b, float* __restrict__ b3p,
    unsigned short* __restrict__ m0t, unsigned short* __restrict__ m1t,
    unsigned short* __restrict__ m2t)
{
    const int t = threadIdx.x;
    for (int idx = t; idx < 1024; idx += 256) {          // w1 [64][16] -> w1t [16][64]
        const int o = idx >> 4, k = idx & 15;
        w1t[k * 64 + o] = w1[idx];
    }
    for (int idx = t; idx < 5120; idx += 256) {          // w2 [64][80] -> w2t [80][64]
        const int o = idx / 80, k = idx % 80;
        w2t[k * 64 + o] = w2[idx];
    }
    for (int idx = t; idx < 20480; idx += 256) {         // w3 -> w3b [128 n][160 k] bf16
        const int n = idx / 160, k = idx % 160;
        const int s = n >> 4, l = n & 15;
        const int o = l * 8 + s;
        w3b[idx] = (k < 144) ? (unsigned short)f2bf_u(w3[o * 144 + k]) : 0;
    }
    if (t < 128) {
        const int o = t;
        b3p[(o & 7) * 16 + (o >> 3)] = b3[o];
    }
    for (int idx = t; idx < 4096; idx += 256) {          // mw0 [54][64] -> m0t [64 o][64 k]
        const int o = idx >> 6, k = idx & 63;
        m0t[o * 64 + k] = (k < 54) ? (unsigned short)f2bf_u(mw0[k * 64 + o]) : 0;
    }
    for (int idx = t; idx < 4096; idx += 256) {          // mw1 [64][64] -> m1t [o][k]
        const int o = idx >> 6, k = idx & 63;
        m1t[o * 64 + k] = (unsigned short)f2bf_u(mw1[k * 64 + o]);
    }
    for (int idx = t; idx < 4096; idx += 256) {          // mw2 [64][64] -> m2t [o][k]
        const int o = idx >> 6, k = idx & 63;
        m2t[o * 64 + k] = (unsigned short)f2bf_u(mw2[k * 64 + o]);
    }
}

// ============================================================================
// Kernel 1a: conv1+conv2 tiled fp32 GEMMs (thread = 8 voxels x 4 channels).
// Writes A_g bf16 [262144 v][160 k] row-major: k 0-63 = x1, 64-127 = x2,
// 128-143 = grid (bf16), 144-159 = 0 — ready for conv3's MFMA A-frags.
// ============================================================================
__global__ __launch_bounds__(128, 2) void conv12_kernel(
    const float* __restrict__ grid,
    const float* __restrict__ w1t, const float* __restrict__ b1,
    const float* __restrict__ g1, const float* __restrict__ bb1, const float* __restrict__ a1,
    const float* __restrict__ w2t, const float* __restrict__ b2,
    const float* __restrict__ g2, const float* __restrict__ bb2, const float* __restrict__ a2,
    unsigned short* __restrict__ A_g)
{
    __shared__ float Gt[16 * 64];
    __shared__ float X1t[64 * 64];
    const int t = threadIdx.x;
    const int v0 = blockIdx.x * 64;
    const int vv = t & 63;

#pragma unroll
    for (int i = 0; i < 8; ++i) {
        const int c = 2 * i + (t >> 6);
        Gt[c * 64 + vv] = grid[(size_t)c * 262144 + v0 + vv];
    }
    __syncthreads();

    // grid channels (bf16) into A_g cols 128-143, zeros 144-159
    for (int idx = t; idx < 256; idx += 128) {
        const int v = idx >> 2, ch = idx & 3;
        uint4 st = make_uint4(0, 0, 0, 0);
        if (ch < 2) {
            float g8[8];
#pragma unroll
            for (int q = 0; q < 8; ++q) g8[q] = Gt[(8 * ch + q) * 64 + v];
            st.x = f2bf_u(g8[0]) | (f2bf_u(g8[1]) << 16);
            st.y = f2bf_u(g8[2]) | (f2bf_u(g8[3]) << 16);
            st.z = f2bf_u(g8[4]) | (f2bf_u(g8[5]) << 16);
            st.w = f2bf_u(g8[6]) | (f2bf_u(g8[7]) << 16);
        }
        *(uint4*)(A_g + (size_t)(v0 + v) * 160 + 128 + ch * 8) = st;
    }

    const int tx = t & 7, ty = t >> 3;
    const int vq = 8 * tx, cq = 4 * ty;
    const float4* w1t4 = (const float4*)w1t;
    const float4* w2t4 = (const float4*)w2t;

    // ---- GEMM1 ----
    float acc1[8][4];
#pragma unroll
    for (int j = 0; j < 4; ++j) {
        const float bj = b1[cq + j];
#pragma unroll
        for (int i = 0; i < 8; ++i) acc1[i][j] = bj;
    }
#pragma unroll 8
    for (int k = 0; k < 16; ++k) {
        const float4 av0 = *(const float4*)&Gt[k * 64 + vq];
        const float4 av1 = *(const float4*)&Gt[k * 64 + vq + 4];
        const float4 wv = w1t4[k * 16 + ty];
        const float a[8] = {av0.x, av0.y, av0.z, av0.w, av1.x, av1.y, av1.z, av1.w};
        const float w[4] = {wv.x, wv.y, wv.z, wv.w};
#pragma unroll
        for (int i = 0; i < 8; ++i)
#pragma unroll
            for (int j = 0; j < 4; ++j) acc1[i][j] = fmaf(a[i], w[j], acc1[i][j]);
    }
    float av1a[8][4];
#pragma unroll
    for (int j = 0; j < 4; ++j) {
        const int c = cq + j;
        const float gs = BN_SCALE_C * g1[c], bb = bb1[c], al = a1[c];
        float vals[8];
#pragma unroll
        for (int i = 0; i < 8; ++i) {
            float x = acc1[i][j] * gs + bb;
            vals[i] = (x >= 0.f) ? x : al * x;
            av1a[i][j] = vals[i];
        }
        *(float4*)&X1t[c * 64 + vq]     = make_float4(vals[0], vals[1], vals[2], vals[3]);
        *(float4*)&X1t[c * 64 + vq + 4] = make_float4(vals[4], vals[5], vals[6], vals[7]);
    }
#pragma unroll
    for (int i = 0; i < 8; ++i) {
        uint2 p;
        p.x = f2bf_u(av1a[i][0]) | (f2bf_u(av1a[i][1]) << 16);
        p.y = f2bf_u(av1a[i][2]) | (f2bf_u(av1a[i][3]) << 16);
        *(uint2*)(A_g + (size_t)(v0 + vq + i) * 160 + cq) = p;
    }
    __syncthreads();

    // ---- GEMM2 ----
    float acc2[8][4];
#pragma unroll
    for (int j = 0; j < 4; ++j) {
        const float bj = b2[cq + j];
#pragma unroll
        for (int i = 0; i < 8; ++i) acc2[i][j] = bj;
    }
#pragma unroll 4
    for (int k = 0; k < 80; ++k) {
        const float* arow = (k < 64) ? &X1t[k * 64] : &Gt[(k - 64) * 64];
        const float4 av0 = *(const float4*)&arow[vq];
        const float4 av1 = *(const float4*)&arow[vq + 4];
        const float4 wv = w2t4[k * 16 + ty];
        const float a[8] = {av0.x, av0.y, av0.z, av0.w, av1.x, av1.y, av1.z, av1.w};
        const float w[4] = {wv.x, wv.y, wv.z, wv.w};
#pragma unroll
        for (int i = 0; i < 8; ++i)
#pragma unroll
            for (int j = 0; j < 4; ++j) acc2[i][j] = fmaf(a[i], w[j], acc2[i][j]);
    }
    float av2a[8][4];
#pragma unroll
    for (int j = 0; j < 4; ++j) {
        const int c = cq + j;
        const float gs = BN_SCALE_C * g2[c], bb = bb2[c], al = a2[c];
#pragma unroll
        for (int i = 0; i < 8; ++i) {
            float x = acc2[i][j] * gs + bb;
            av2a[i][j] = (x >= 0.f) ? x : al * x;
        }
    }
#pragma unroll
    for (int i = 0; i < 8; ++i) {
        uint2 p;
        p.x = f2bf_u(av2a[i][0]) | (f2bf_u(av2a[i][1]) << 16);
        p.y = f2bf_u(av2a[i][2]) | (f2bf_u(av2a[i][3]) << 16);
        *(uint2*)(A_g + (size_t)(v0 + vq + i) * 160 + 64 + cq) = p;
    }
}

// ============================================================================
// Kernel 1b: conv3 on the matrix pipe. Block = 128 thr (2 waves) = 64-voxel x
// 128-channel tile. A (bf16 [v][160]) staged contiguously in LDS (stride 168,
// bank-spread); B = w3b from global (40 KB, L1/L2-resident). Per wave:
// 4 m-tiles x 4 n-tiles x 5 k-steps = 80 mfma_f32_16x16x32_bf16.
// dens kept fp32-exact via densT; featb via bf16 Ct transpose -> 16B stores.
// ============================================================================
__global__ __launch_bounds__(128) void conv3_kernel(
    const unsigned short* __restrict__ A_g,
    const unsigned short* __restrict__ w3b, const float* __restrict__ b3p,
    unsigned short* __restrict__ featb, float* __restrict__ dens)
{
    __shared__ __align__(16) unsigned short At[64 * 168];   // 21 KB
    __shared__ __align__(16) unsigned short Ct[64 * 136];   // 17 KB
    __shared__ float densT[64 * 8];                         // 2 KB
    const int t = threadIdx.x;
    const int v0 = blockIdx.x * 64;

    // stage A tile: fully contiguous global reads (64 rows x 320 B)
    for (int idx = t; idx < 1280; idx += 128) {
        const int v = idx / 20, c = idx % 20;
        const uint4 u = *(const uint4*)(A_g + (size_t)(v0 + v) * 160 + c * 8);
        *(uint4*)(At + v * 168 + c * 8) = u;
    }
    __syncthreads();

    const int wv = t >> 6, lane = t & 63;
    const int quad = lane >> 4, l16 = lane & 15;

    f32x4 acc[4][4];   // [mt][nt]
#pragma unroll
    for (int nt = 0; nt < 4; ++nt) {
        const float bv = b3p[64 * wv + 16 * nt + l16];
#pragma unroll
        for (int mt = 0; mt < 4; ++mt) {
            acc[mt][nt][0] = bv; acc[mt][nt][1] = bv;
            acc[mt][nt][2] = bv; acc[mt][nt][3] = bv;
        }
    }
#pragma unroll
    for (int kq = 0; kq < 5; ++kq) {
        const int k0 = 32 * kq + 8 * quad;
        bf16x8 a[4], b[4];
#pragma unroll
        for (int mt = 0; mt < 4; ++mt) {
            const uint4 u = *(const uint4*)(At + (16 * mt + l16) * 168 + k0);
            a[mt] = __builtin_bit_cast(bf16x8, u);
        }
#pragma unroll
        for (int nt = 0; nt < 4; ++nt) {
            const uint4 u = *(const uint4*)(w3b + (size_t)(64 * wv + 16 * nt + l16) * 160 + k0);
            b[nt] = __builtin_bit_cast(bf16x8, u);
        }
#pragma unroll
        for (int mt = 0; mt < 4; ++mt)
#pragma unroll
            for (int nt = 0; nt < 4; ++nt)
                acc[mt][nt] = __builtin_amdgcn_mfma_f32_16x16x32_bf16(
                    a[mt], b[nt], acc[mt][nt], 0, 0, 0);
    }

    // density (n = 16*s, l==0 lanes) fp32-exact into densT
    if (l16 == 0) {
#pragma unroll
        for (int mt = 0; mt < 4; ++mt)
#pragma unroll
            for (int nt = 0; nt < 4; ++nt) {
                const int s = 4 * wv + nt;
#pragma unroll
                for (int reg = 0; reg < 4; ++reg) {
                    const int v = 16 * mt + 4 * quad + reg;
                    densT[v * 8 + s] = acc[mt][nt][reg];
                }
            }
    }
    // bf16 transpose into Ct[v][n]
#pragma unroll
    for (int mt = 0; mt < 4; ++mt)
#pragma unroll
        for (int nt = 0; nt < 4; ++nt)
#pragma unroll
            for (int reg = 0; reg < 4; ++reg)
                Ct[(16 * mt + 4 * quad + reg) * 136 + 64 * wv + 16 * nt + l16] =
                    (unsigned short)f2bf_u(acc[mt][nt][reg]);
    __syncthreads();

    // epilogue: thread = (voxel, n-half); 16B featb stores + fp32 dens
    const int v = t >> 1, half = t & 1;
    const int vg = v0 + v;
    const int Z = vg & 63, Y = (vg >> 6) & 63, X = vg >> 12;
#pragma unroll
    for (int si = 0; si < 4; ++si) {
        const int s = 4 * half + si;
        const int d2 = (s >> 2) & 1, h2 = (s >> 1) & 1, w2i = s & 1;
        const int ubase = ((2 * X + d2) * 128 + (2 * Y + h2)) * 128 + (2 * Z + w2i);
        const uint4 q0 = *(const uint4*)(Ct + v * 136 + 64 * half + 16 * si);
        const uint4 q1 = *(const uint4*)(Ct + v * 136 + 64 * half + 16 * si + 8);
        *(uint4*)(featb + (size_t)ubase * 16)     = q0;
        *(uint4*)(featb + (size_t)ubase * 16 + 8) = q1;
        dens[ubase] = densT[v * 8 + s];
    }
}

// ============================================================================
// Kernel 2: 5x5x5 Sobel (zero pad) on fp32 density + normalize.
// ============================================================================
__global__ __launch_bounds__(256) void sobel_kernel(const float* __restrict__ dens,
                                                    float* __restrict__ normals)
{
    const int v = blockIdx.x * 256 + threadIdx.x;
    const int z = v & 127, y = (v >> 7) & 127, x = v >> 14;
    const float hw[5] = {1.f, 4.f, 6.f, 4.f, 1.f};
    const float hd[5] = {-1.f, -2.f, 0.f, 2.f, 1.f};
    float sx = 0.f, sy = 0.f, sz = 0.f;
#pragma unroll
    for (int i = 0; i < 5; ++i) {
        const int xx = x + i - 2;
        if (xx < 0 || xx > 127) continue;
#pragma unroll
        for (int j = 0; j < 5; ++j) {
            const int yy = y + j - 2;
            if (yy < 0 || yy > 127) continue;
            const float* row = dens + (xx * 128 + yy) * 128;
            float sh = 0.f, sd = 0.f;
#pragma unroll
            for (int k = 0; k < 5; ++k) {
                const int zz = z + k - 2;
                if (zz < 0 || zz > 127) continue;
                const float d = row[zz];
                sh = fmaf(hw[k], d, sh);
                sd = fmaf(hd[k], d, sd);
            }
            sx = fmaf(hd[i] * hw[j], sh, sx);
            sy = fmaf(hw[i] * hd[j], sh, sy);
            sz = fmaf(hw[i] * hw[j], sd, sz);
        }
    }
    sx *= (1.f / 72.f); sy *= (1.f / 72.f); sz *= (1.f / 72.f);
    const float n = sqrtf(sx * sx + sy * sy + sz * sz);
    const float inv = 1.f / fmaxf(n, 1e-12f);
    normals[v * 3 + 0] = -sx * inv;
    normals[v * 3 + 1] = -sy * inv;
    normals[v * 3 + 2] = -sz * inv;
}

// ============================================================================
// Kernel 3: per-sample shading with MFMA MLP (unchanged from round 6).
// ============================================================================
__device__ __forceinline__ void mfma_layer(const unsigned short* A,
                                           unsigned short* D,
                                           const unsigned short* __restrict__ Wg,
                                           const float* __restrict__ bias,
                                           const int wv, const int lane)
{
    const int quad = lane >> 4, l16 = lane & 15;
    f32x4 acc[4][4];
#pragma unroll
    for (int nt = 0; nt < 4; ++nt) {
        const float bv = bias[16 * nt + l16];
#pragma unroll
        for (int mt = 0; mt < 4; ++mt) {
            acc[mt][nt][0] = bv; acc[mt][nt][1] = bv;
            acc[mt][nt][2] = bv; acc[mt][nt][3] = bv;
        }
    }
#pragma unroll
    for (int kq = 0; kq < 2; ++kq) {
        const int k0 = 32 * kq + 8 * quad;
        bf16x8 a[4], b[4];
#pragma unroll
        for (int mt = 0; mt < 4; ++mt) {
            const uint4 u = *(const uint4*)(A + (64 * wv + 16 * mt + l16) * 72 + k0);
            a[mt] = __builtin_bit_cast(bf16x8, u);
        }
#pragma unroll
        for (int nt = 0; nt < 4; ++nt) {
            const uint4 u = *(const uint4*)(Wg + (16 * nt + l16) * 64 + k0);
            b[nt] = __builtin_bit_cast(bf16x8, u);
        }
#pragma unroll
        for (int mt = 0; mt < 4; ++mt)
#pragma unroll
            for (int nt = 0; nt < 4; ++nt)
                acc[mt][nt] = __builtin_amdgcn_mfma_f32_16x16x32_bf16(
                    a[mt], b[nt], acc[mt][nt], 0, 0, 0);
    }
#pragma unroll
    for (int mt = 0; mt < 4; ++mt)
#pragma unroll
        for (int nt = 0; nt < 4; ++nt)
#pragma unroll
            for (int reg = 0; reg < 4; ++reg) {
                const float v = fmaxf(acc[mt][nt][reg], 0.f);
                D[(64 * wv + 16 * mt + 4 * quad + reg) * 72 + 16 * nt + l16] =
                    (unsigned short)f2bf_u(v);
            }
}

__global__ __launch_bounds__(128) void sample_kernel(
    const float* __restrict__ ro, const float* __restrict__ rd, const float* __restrict__ vd,
    const unsigned short* __restrict__ featb, const float* __restrict__ dens,
    const float* __restrict__ normals,
    const unsigned short* __restrict__ m0t, const float* __restrict__ mb0,
    const unsigned short* __restrict__ m1t, const float* __restrict__ mb1,
    const unsigned short* __restrict__ m2t, const float* __restrict__ mb2,
    const float* __restrict__ mw3, const float* __restrict__ mb3,
    float* __restrict__ sbuf, const int total)
{
    __shared__ __align__(16) unsigned short actA[128 * 72];
    __shared__ __align__(16) unsigned short actB[128 * 72];

    const int t = threadIdx.x;
    const int s = blockIdx.x * 128 + t;
    const bool live = (s < total);
    bool act = false;
    float alpha = 0.f, ndx = 0.f, ndy = 0.f, ndz = 0.f;
    float nsx = 0.f, nsy = 0.f, nsz = 0.f, depth = 0.f;
    float hf[64];
#pragma unroll
    for (int q = 0; q < 64; ++q) hf[q] = 0.f;

    if (live) {
        const int r = s / S_SAMPLES;
        const int j = s - r * S_SAMPLES;

        const float ox = ro[r * 3 + 0], oy = ro[r * 3 + 1], oz = ro[r * 3 + 2];
        const float dx = rd[r * 3 + 0], dy = rd[r * 3 + 1], dz = rd[r * 3 + 2];
        const float vx = vd[r * 3 + 0], vy = vd[r * 3 + 1], vz = vd[r * 3 + 2];

        const float vecx = (dx == 0.f) ? 1e-6f : dx;
        const float vecy = (dy == 0.f) ? 1e-6f : dy;
        const float vecz = (dz == 0.f) ? 1e-6f : dz;
        const float rax = (1.f - ox) / vecx, rbx = (-1.f - ox) / vecx;
        const float ray2 = (1.f - oy) / vecy, rby = (-1.f - oy) / vecy;
        const float raz = (1.f - oz) / vecz, rbz = (-1.f - oz) / vecz;
        float tmin = fmaxf(fmaxf(fminf(rax, rbx), fminf(ray2, rby)), fminf(raz, rbz));
        float tmax = fminf(fminf(fmaxf(rax, rbx), fmaxf(ray2, rby)), fmaxf(raz, rbz));
        tmin = fminf(fmaxf(tmin, 0.2f), 6.0f);
        tmax = fminf(fmaxf(tmax, 0.2f), 6.0f);
        const bool mask_ray = (tmax <= tmin);

        const float ndr = sqrtf(dx * dx + dy * dy + dz * dz);
        const float interpx = tmin + (STEP_VOX * (float)j) / ndr;
        const float px = ox + dx * interpx;
        const float py = oy + dy * interpx;
        const float pz = oz + dz * interpx;
        const bool outbox = mask_ray || (px < -1.f) || (px > 1.f) || (py < -1.f) ||
                            (py > 1.f) || (pz < -1.f) || (pz > 1.f);
        act = !outbox;
        if (act) {
            const float ux = fminf(fmaxf((px + 1.f) * 63.5f, 0.f), 127.f);
            const float uy = fminf(fmaxf((py + 1.f) * 63.5f, 0.f), 127.f);
            const float uz = fminf(fmaxf((pz + 1.f) * 63.5f, 0.f), 127.f);
            const int ix = min(max((int)floorf(ux), 0), 126);
            const int iy = min(max((int)floorf(uy), 0), 126);
            const int iz = min(max((int)floorf(uz), 0), 126);
            const float fx = ux - (float)ix, fy = uy - (float)iy, fz = uz - (float)iz;

            float lat[15];
#pragma unroll
            for (int q = 0; q < 15; ++q) lat[q] = 0.f;
            float na0 = 0.f, na1 = 0.f, na2 = 0.f;
            float c0v[8];
#pragma unroll
            for (int cn = 0; cn < 8; ++cn) {
                const int adx = cn >> 2, ady = (cn >> 1) & 1, adz = cn & 1;
                const int vox = ((ix + adx) * 128 + (iy + ady)) * 128 + (iz + adz);
                const float w = (adx ? fx : 1.f - fx) * (ady ? fy : 1.f - fy) * (adz ? fz : 1.f - fz);
                c0v[cn] = dens[vox];
                const uint4* cp = (const uint4*)(featb + (size_t)vox * 16);
                const uint4 q0 = cp[0], q1 = cp[1];
                lat[0]  = fmaf(w, bf_hi(q0.x), lat[0]);
                lat[1]  = fmaf(w, bf_lo(q0.y), lat[1]);
                lat[2]  = fmaf(w, bf_hi(q0.y), lat[2]);
                lat[3]  = fmaf(w, bf_lo(q0.z), lat[3]);
                lat[4]  = fmaf(w, bf_hi(q0.z), lat[4]);
                lat[5]  = fmaf(w, bf_lo(q0.w), lat[5]);
                lat[6]  = fmaf(w, bf_hi(q0.w), lat[6]);
                lat[7]  = fmaf(w, bf_lo(q1.x), lat[7]);
                lat[8]  = fmaf(w, bf_hi(q1.x), lat[8]);
                lat[9]  = fmaf(w, bf_lo(q1.y), lat[9]);
                lat[10] = fmaf(w, bf_hi(q1.y), lat[10]);
                lat[11] = fmaf(w, bf_lo(q1.z), lat[11]);
                lat[12] = fmaf(w, bf_hi(q1.z), lat[12]);
                lat[13] = fmaf(w, bf_lo(q1.w), lat[13]);
                lat[14] = fmaf(w, bf_hi(q1.w), lat[14]);
                const float* np_ = normals + (size_t)vox * 3;
                na0 = fmaf(w, np_[0], na0);
                na1 = fmaf(w, np_[1], na1);
                na2 = fmaf(w, np_[2], na2);
            }

            const float c00 = c0v[0] * (1.f - fz) + c0v[1] * fz;
            const float c01 = c0v[2] * (1.f - fz) + c0v[3] * fz;
            const float c10 = c0v[4] * (1.f - fz) + c0v[5] * fz;
            const float c11 = c0v[6] * (1.f - fz) + c0v[7] * fz;
            const float e0 = c00 * (1.f - fy) + c01 * fy;
            const float e1 = c10 * (1.f - fy) + c11 * fy;
            const float d0 = e0 * (1.f - fx) + e1 * fx;
            const float dfx = e1 - e0;
            const float dfy = (c01 - c00) * (1.f - fx) + (c11 - c10) * fx;
            const float dfz = ((c0v[1] - c0v[0]) * (1.f - fy) + (c0v[3] - c0v[2]) * fy) * (1.f - fx)
                            + ((c0v[5] - c0v[4]) * (1.f - fy) + (c0v[7] - c0v[6]) * fy) * fx;

            const float zin = d0 + ACT_SHIFT;
            const float splus = fmaxf(zin, 0.f) + log1pf(__expf(-fabsf(zin)));
            const float e = __expf(-splus * 0.5f);
            alpha = 1.f - e;
            const float sig = 1.f / (1.f + __expf(-zin));
            const float dad = e * 0.5f * sig;
            const float gx = dad * dfx * 63.5f;
            const float gy = dad * dfy * 63.5f;
            const float gz = dad * dfz * 63.5f;
            const float gn = sqrtf(gx * gx + gy * gy + gz * gz);
            const float gi = 1.f / fmaxf(gn, 1e-12f);
            ndx = -gx * gi; ndy = -gy * gi; ndz = -gz * gi;

            const float nn = sqrtf(na0 * na0 + na1 * na1 + na2 * na2);
            const float ni = 1.f / fmaxf(nn, 1e-12f);
            nsx = -na0 * ni; nsy = -na1 * ni; nsz = -na2 * ni;

            const float dotv = -(vx * ndx + vy * ndy + vz * ndz);
            const float rx = 2.f * dotv * ndx + vx;
            const float ry = 2.f * dotv * ndy + vy;
            const float rz = 2.f * dotv * ndz + vz;

#pragma unroll
            for (int q = 0; q < 15; ++q) hf[q] = lat[q];
            hf[15] = rx; hf[16] = ry; hf[17] = rz;
#pragma unroll
            for (int fi = 0; fi < 6; ++fi) {
                const float fr = (float)(1 << fi);
                hf[18 + fi * 6 + 0] = __sinf(rx * fr);
                hf[18 + fi * 6 + 1] = __sinf(ry * fr);
                hf[18 + fi * 6 + 2] = __sinf(rz * fr);
                hf[18 + fi * 6 + 3] = __cosf(rx * fr);
                hf[18 + fi * 6 + 4] = __cosf(ry * fr);
                hf[18 + fi * 6 + 5] = __cosf(rz * fr);
            }
            depth = interpx * ndr;
        }
    }

#pragma unroll
    for (int q = 0; q < 8; ++q) {
        uint4 st;
        st.x = f2bf_u(hf[8 * q + 0]) | (f2bf_u(hf[8 * q + 1]) << 16);
        st.y = f2bf_u(hf[8 * q + 2]) | (f2bf_u(hf[8 * q + 3]) << 16);
        st.z = f2bf_u(hf[8 * q + 4]) | (f2bf_u(hf[8 * q + 5]) << 16);
        st.w = f2bf_u(hf[8 * q + 6]) | (f2bf_u(hf[8 * q + 7]) << 16);
        *(uint4*)(actA + t * 72 + 8 * q) = st;
    }
    __syncthreads();

    const int wv = t >> 6, lane = t & 63;
    mfma_layer(actA, actB, m0t, mb0, wv, lane);
    __syncthreads();
    mfma_layer(actB, actA, m1t, mb1, wv, lane);
    __syncthreads();
    mfma_layer(actA, actB, m2t, mb2, wv, lane);
    __syncthreads();

    if (live) {
        float* so = sbuf + (size_t)s * 12;
        if (act) {
            float r0 = mb3[0], r1 = mb3[1], r2 = mb3[2];
            const unsigned short* hr = actB + t * 72;
#pragma unroll
            for (int c8 = 0; c8 < 8; ++c8) {
                const uint4 hu = *(const uint4*)(hr + 8 * c8);
                const float h[8] = {bf_lo(hu.x), bf_hi(hu.x), bf_lo(hu.y), bf_hi(hu.y),
                                    bf_lo(hu.z), bf_hi(hu.z), bf_lo(hu.w), bf_hi(hu.w)};
#pragma unroll
                for (int u = 0; u < 8; ++u) {
                    const int c = 8 * c8 + u;
                    r0 = fmaf(h[u], mw3[c * 3 + 0], r0);
                    r1 = fmaf(h[u], mw3[c * 3 + 1], r1);
                    r2 = fmaf(h[u], mw3[c * 3 + 2], r2);
                }
            }
            so[0] = alpha;
            so[1] = 1.f / (1.f + __expf(-r0));
            so[2] = 1.f / (1.f + __expf(-r1));
            so[3] = 1.f / (1.f + __expf(-r2));
            so[4] = ndx; so[5] = ndy; so[6] = ndz;
            so[7] = nsx; so[8] = nsy; so[9] = nsz;
            so[10] = depth;
            so[11] = 0.f;
        } else {
#pragma unroll
            for (int q = 0; q < 12; ++q) so[q] = 0.f;
        }
    }
}

// ============================================================================
// Kernel 4: per-ray compositing (wave per ray; segmented product scan).
// ============================================================================
__global__ __launch_bounds__(64) void reduce_kernel(const float* __restrict__ sbuf,
                                                    float* __restrict__ out)
{
    const int r = blockIdx.x;
    const int lane = threadIdx.x;
    const int per = (S_SAMPLES + 63) / 64;   // 7
    const int j0 = lane * per;
    const int j1 = min(S_SAMPLES, j0 + per);

    float p = 1.f;
    for (int j = j0; j < j1; ++j) {
        const float a = sbuf[((size_t)r * S_SAMPLES + j) * 12];
        p *= fmaxf(1.f - a, 1e-10f);
    }
    float scan = p;
#pragma unroll
    for (int off = 1; off < 64; off <<= 1) {
        const float nv = __shfl_up(scan, (unsigned)off, 64);
        if (lane >= off) scan *= nv;
    }
    const float total = __shfl(scan, 63, 64);
    float pref = __shfl_up(scan, 1u, 64);
    if (lane == 0) pref = 1.f;

    float s0 = 0, s1 = 0, s2 = 0, s3 = 0, s4 = 0, s5 = 0, s6 = 0, s7 = 0, s8 = 0, s9 = 0, s10 = 0;
    for (int j = j0; j < j1; ++j) {
        const float* sp_ = sbuf + ((size_t)r * S_SAMPLES + j) * 12;
        const float a = sp_[0];
        const float w = a * pref;
        pref *= fmaxf(1.f - a, 1e-10f);
        s0 = fmaf(w, sp_[1], s0);
        s1 = fmaf(w, sp_[2], s1);
        s2 = fmaf(w, sp_[3], s2);
        s3 = fmaf(w, sp_[10], s3);
        s4 += w;
        s5 = fmaf(w, sp_[4], s5);
        s6 = fmaf(w, sp_[5], s6);
        s7 = fmaf(w, sp_[6], s7);
        s8 = fmaf(w, sp_[7], s8);
        s9 = fmaf(w, sp_[8], s9);
        s10 = fmaf(w, sp_[9], s10);
    }
#pragma unroll
    for (int m = 32; m >= 1; m >>= 1) {
        s0 += __shfl_xor(s0, m, 64);
        s1 += __shfl_xor(s1, m, 64);
        s2 += __shfl_xor(s2, m, 64);
        s3 += __shfl_xor(s3, m, 64);
        s4 += __shfl_xor(s4, m, 64);
        s5 += __shfl_xor(s5, m, 64);
        s6 += __shfl_xor(s6, m, 64);
        s7 += __shfl_xor(s7, m, 64);
        s8 += __shfl_xor(s8, m, 64);
        s9 += __shfl_xor(s9, m, 64);
        s10 += __shfl_xor(s10, m, 64);
    }
    if (lane == 0) {
        const float dm = s3 + total * 6.0f;
        out[r * 12 + 0] = s0 + total;
        out[r * 12 + 1] = s1 + total;
        out[r * 12 + 2] = s2 + total;
        out[r * 12 + 3] = dm;
        out[r * 12 + 4] = 1.f / dm;
        out[r * 12 + 5] = s4;
        out[r * 12 + 6] = s5; out[r * 12 + 7] = s6; out[r * 12 + 8] = s7;
        out[r * 12 + 9] = s8; out[r * 12 + 10] = s9; out[r * 12 + 11] = s10;
    }
}

// ============================================================================
extern "C" void kernel_launch(void* const* d_in, const int* in_sizes, int n_in,
                              void* d_out, int out_size, void* d_ws, size_t ws_size,
                              hipStream_t stream)
{
    (void)n_in; (void)out_size; (void)ws_size;
    const float* rays_o   = (const float*)d_in[0];
    const float* rays_d   = (const float*)d_in[1];
    const float* viewdirs = (const float*)d_in[2];
    const float* grid     = (const float*)d_in[3];
    const float* c1_w  = (const float*)d_in[4];
    const float* c1_b  = (const float*)d_in[5];
    const float* bn1_g = (const float*)d_in[6];
    const float* bn1_b = (const float*)d_in[7];
    const float* pr1_a = (const float*)d_in[8];
    const float* c2_w  = (const float*)d_in[9];
    const float* c2_b  = (const float*)d_in[10];
    const float* bn2_g = (const float*)d_in[11];
    const float* bn2_b = (const float*)d_in[12];
    const float* pr2_a = (const float*)d_in[13];
    const float* c3_w  = (const float*)d_in[14];
    const float* c3_b  = (const float*)d_in[15];
    const float* mw0 = (const float*)d_in[16];
    const float* mb0 = (const float*)d_in[17];
    const float* mw1 = (const float*)d_in[18];
    const float* mb1 = (const float*)d_in[19];
    const float* mw2 = (const float*)d_in[20];
    const float* mb2 = (const float*)d_in[21];
    const float* mw3 = (const float*)d_in[22];
    const float* mb3 = (const float*)d_in[23];

    const int N = in_sizes[0] / 3;   // 1024 rays
    const int total = N * S_SAMPLES;

    // ws layout (float units), ~181.4 MB total:
    // featb [0,16777216) | dens [16777216,18874368) | A_g bf16[262144][160]
    // [18874368,39845888) (normals alias its head after conv3) |
    // sbuf [39845888,45337600) | weights after.
    float* wsf = (float*)d_ws;
    unsigned short* featb = (unsigned short*)wsf;
    float* dens    = wsf + (size_t)16777216;
    unsigned short* A_g = (unsigned short*)(wsf + (size_t)18874368);
    float* normals = wsf + (size_t)18874368;                        // alias (A_g dead)
    float* sbuf    = wsf + (size_t)39845888;
    float* w1t = wsf + (size_t)45337600;
    float* w2t = w1t + 1024;
    float* b3p = w2t + 5120;
    unsigned short* w3b = (unsigned short*)(b3p + 128);             // 20480 bf16
    unsigned short* m0t = (unsigned short*)(wsf + (size_t)45354112);
    unsigned short* m1t = (unsigned short*)(wsf + (size_t)45356160);
    unsigned short* m2t = (unsigned short*)(wsf + (size_t)45358208);

    prep_kernel<<<1, 256, 0, stream>>>(c1_w, c2_w, c3_w, c3_b, mw0, mw1, mw2,
                                       w1t, w2t, w3b, b3p, m0t, m1t, m2t);
    conv12_kernel<<<4096, 128, 0, stream>>>(grid, w1t, c1_b, bn1_g, bn1_b, pr1_a,
                                            w2t, c2_b, bn2_g, bn2_b, pr2_a, A_g);
    conv3_kernel<<<4096, 128, 0, stream>>>(A_g, w3b, b3p, featb, dens);
    sobel_kernel<<<8192, 256, 0, stream>>>(dens, normals);
    const int sblocks = (total + 127) / 128;
    sample_kernel<<<sblocks, 128, 0, stream>>>(rays_o, rays_d, viewdirs, featb, dens, normals,
                                               m0t, mb0, m1t, mb1, m2t, mb2, mw3, mb3,
                                               sbuf, total);
    reduce_kernel<<<N, 64, 0, stream>>>(sbuf, (float*)d_out);
}

// Round 8
// 331.301 us; speedup vs baseline: 12.5886x; 1.2101x over previous
//
#include <hip/hip_runtime.h>
#include <math.h>

// ---- constants from the reference ----
#define S_SAMPLES 447                      // int(norm([129]*3)/0.5)+1
#define ACT_SHIFT -9.210240366971207f      // log(1/(1-1e-4) - 1)
#define BN_SCALE_C 0.9999950000374997f     // (1+1e-5)^-0.5
#define STEP_VOX 0.015625f                 // STEPSIZE * VOXEL = 0.5 * (2/64)

__device__ __forceinline__ unsigned f2bf_u(float f) {
    unsigned u = __float_as_uint(f);
    return (u + 0x7fffu + ((u >> 16) & 1u)) >> 16;   // RNE, low 16 bits
}
__device__ __forceinline__ float bf2f(unsigned short u) {
    return __uint_as_float(((unsigned)u) << 16);
}
__device__ __forceinline__ float bf_lo(unsigned u) { return __uint_as_float(u << 16); }
__device__ __forceinline__ float bf_hi(unsigned u) { return __uint_as_float(u & 0xffff0000u); }

typedef __attribute__((ext_vector_type(8))) short bf16x8;   // MFMA A/B frag (4 VGPRs)
typedef __attribute__((ext_vector_type(4))) float f32x4;    // MFMA C/D frag

// ============================================================================
// Kernel 0: prep — weight transposes (all GEMM B operands bf16, k-contiguous).
// A-row k-order everywhere: [x1(0-63) | grid(64-79) | 0(80-95) | x2(96-159)].
// w1b[64][32]: k<16 real. w2b[64][96]: k<80 real. w3b[128 n][160], n = s*16+l.
// MLP: mXt[o][k], K zero-padded to 64.
// ============================================================================
__global__ __launch_bounds__(256) void prep_kernel(
    const float* __restrict__ w1, const float* __restrict__ w2,
    const float* __restrict__ w3, const float* __restrict__ b3,
    const float* __restrict__ mw0, const float* __restrict__ mw1,
    const float* __restrict__ mw2,
    unsigned short* __restrict__ w1b, unsigned short* __restrict__ w2b,
    unsigned short* __restrict__ w3b, float* __restrict__ b3p,
    unsigned short* __restrict__ m0t, unsigned short* __restrict__ m1t,
    unsigned short* __restrict__ m2t)
{
    const int t = threadIdx.x;
    for (int idx = t; idx < 2048; idx += 256) {          // w1b [64 o][32 k]
        const int o = idx >> 5, k = idx & 31;
        w1b[idx] = (k < 16) ? (unsigned short)f2bf_u(w1[o * 16 + k]) : 0;
    }
    for (int idx = t; idx < 6144; idx += 256) {          // w2b [64 o][96 k]
        const int o = idx / 96, k = idx % 96;
        w2b[idx] = (k < 80) ? (unsigned short)f2bf_u(w2[o * 80 + k]) : 0;
    }
    for (int idx = t; idx < 20480; idx += 256) {         // w3b [128 n][160 k]
        const int n = idx / 160, k = idx % 160;
        const int s = n >> 4, l = n & 15;
        const int o = l * 8 + s;
        float val = 0.f;
        if (k < 64)       val = w3[o * 144 + k];             // x1 part
        else if (k < 80)  val = w3[o * 144 + 128 + (k - 64)];// grid part
        else if (k >= 96) val = w3[o * 144 + 64 + (k - 96)]; // x2 part
        w3b[idx] = (unsigned short)f2bf_u(val);
    }
    if (t < 128) {
        const int o = t;
        b3p[(o & 7) * 16 + (o >> 3)] = b3[o];
    }
    for (int idx = t; idx < 4096; idx += 256) {
        const int o = idx >> 6, k = idx & 63;
        m0t[o * 64 + k] = (k < 54) ? (unsigned short)f2bf_u(mw0[k * 64 + o]) : 0;
    }
    for (int idx = t; idx < 4096; idx += 256) {
        const int o = idx >> 6, k = idx & 63;
        m1t[o * 64 + k] = (unsigned short)f2bf_u(mw1[k * 64 + o]);
    }
    for (int idx = t; idx < 4096; idx += 256) {
        const int o = idx >> 6, k = idx & 63;
        m2t[o * 64 + k] = (unsigned short)f2bf_u(mw2[k * 64 + o]);
    }
}

// ============================================================================
// Kernel 1a: conv1+conv2 on the matrix pipe. Block = 128 thr (2 waves) =
// 64 voxels. LDS AT[64][168] bf16 holds the A-row being built:
// cols 64-79 grid, 0-63 x1 (conv1 out), 96-159 x2 (conv2 out), 80-95 zero.
// conv1: K=32 (cols 64-95), 8 MFMA/wave. conv2: K=96 (cols 0-95), 24 MFMA/wave.
// BN+PReLU fp32 in the D-layout epilogues. One coalesced copy-out to A_g.
// ============================================================================
__global__ __launch_bounds__(128) void conv12_kernel(
    const float* __restrict__ grid,
    const unsigned short* __restrict__ w1b, const float* __restrict__ b1,
    const float* __restrict__ g1, const float* __restrict__ bb1, const float* __restrict__ a1,
    const unsigned short* __restrict__ w2b, const float* __restrict__ b2,
    const float* __restrict__ g2, const float* __restrict__ bb2, const float* __restrict__ a2,
    unsigned short* __restrict__ A_g)
{
    __shared__ __align__(16) unsigned short AT[64 * 168];   // 21 KB
    const int t = threadIdx.x;
    const int v0 = blockIdx.x * 64;

    // zero cols 80..95
    for (int idx = t; idx < 512; idx += 128) {
        const int v = idx >> 3, c = idx & 7;
        *(unsigned*)(AT + v * 168 + 80 + c * 2) = 0;
    }
    // grid -> AT cols 64..79 (bf16)
    {
        const int vv = t & 63, half = t >> 6;
        for (int c = half; c < 16; c += 2) {
            const float gv = grid[(size_t)c * 262144 + v0 + vv];
            AT[vv * 168 + 64 + c] = (unsigned short)f2bf_u(gv);
        }
    }
    __syncthreads();

    const int wv = t >> 6, lane = t & 63;
    const int quad = lane >> 4, l16 = lane & 15;
    const int ch0 = 32 * wv + l16;          // nt adds 16

    // ---- conv1: A cols 64..95, out -> cols 0..63 ----
    {
        f32x4 acc[4][2];
        float gs[2], bb[2], al[2];
#pragma unroll
        for (int nt = 0; nt < 2; ++nt) {
            const int ch = ch0 + 16 * nt;
            const float bch = b1[ch];
            gs[nt] = BN_SCALE_C * g1[ch]; bb[nt] = bb1[ch]; al[nt] = a1[ch];
#pragma unroll
            for (int mt = 0; mt < 4; ++mt) {
                acc[mt][nt][0] = bch; acc[mt][nt][1] = bch;
                acc[mt][nt][2] = bch; acc[mt][nt][3] = bch;
            }
        }
        const int k0 = 8 * quad;
        bf16x8 a[4], b[2];
#pragma unroll
        for (int mt = 0; mt < 4; ++mt)
            a[mt] = __builtin_bit_cast(bf16x8, *(const uint4*)(AT + (16 * mt + l16) * 168 + 64 + k0));
#pragma unroll
        for (int nt = 0; nt < 2; ++nt)
            b[nt] = __builtin_bit_cast(bf16x8, *(const uint4*)(w1b + (ch0 + 16 * nt) * 32 + k0));
#pragma unroll
        for (int mt = 0; mt < 4; ++mt)
#pragma unroll
            for (int nt = 0; nt < 2; ++nt)
                acc[mt][nt] = __builtin_amdgcn_mfma_f32_16x16x32_bf16(a[mt], b[nt], acc[mt][nt], 0, 0, 0);
#pragma unroll
        for (int mt = 0; mt < 4; ++mt)
#pragma unroll
            for (int nt = 0; nt < 2; ++nt)
#pragma unroll
                for (int reg = 0; reg < 4; ++reg) {
                    float x = acc[mt][nt][reg] * gs[nt] + bb[nt];
                    x = (x >= 0.f) ? x : al[nt] * x;
                    AT[(16 * mt + 4 * quad + reg) * 168 + ch0 + 16 * nt] = (unsigned short)f2bf_u(x);
                }
    }
    __syncthreads();

    // ---- conv2: A cols 0..95 (K=96), out -> cols 96..159 ----
    {
        f32x4 acc[4][2];
        float gs[2], bb[2], al[2];
#pragma unroll
        for (int nt = 0; nt < 2; ++nt) {
            const int ch = ch0 + 16 * nt;
            const float bch = b2[ch];
            gs[nt] = BN_SCALE_C * g2[ch]; bb[nt] = bb2[ch]; al[nt] = a2[ch];
#pragma unroll
            for (int mt = 0; mt < 4; ++mt) {
                acc[mt][nt][0] = bch; acc[mt][nt][1] = bch;
                acc[mt][nt][2] = bch; acc[mt][nt][3] = bch;
            }
        }
#pragma unroll
        for (int kq = 0; kq < 3; ++kq) {
            const int k0 = 32 * kq + 8 * quad;
            bf16x8 a[4], b[2];
#pragma unroll
            for (int mt = 0; mt < 4; ++mt)
                a[mt] = __builtin_bit_cast(bf16x8, *(const uint4*)(AT + (16 * mt + l16) * 168 + k0));
#pragma unroll
            for (int nt = 0; nt < 2; ++nt)
                b[nt] = __builtin_bit_cast(bf16x8, *(const uint4*)(w2b + (ch0 + 16 * nt) * 96 + k0));
#pragma unroll
            for (int mt = 0; mt < 4; ++mt)
#pragma unroll
                for (int nt = 0; nt < 2; ++nt)
                    acc[mt][nt] = __builtin_amdgcn_mfma_f32_16x16x32_bf16(a[mt], b[nt], acc[mt][nt], 0, 0, 0);
        }
#pragma unroll
        for (int mt = 0; mt < 4; ++mt)
#pragma unroll
            for (int nt = 0; nt < 2; ++nt)
#pragma unroll
                for (int reg = 0; reg < 4; ++reg) {
                    float x = acc[mt][nt][reg] * gs[nt] + bb[nt];
                    x = (x >= 0.f) ? x : al[nt] * x;
                    AT[(16 * mt + 4 * quad + reg) * 168 + 96 + ch0 + 16 * nt] = (unsigned short)f2bf_u(x);
                }
    }
    __syncthreads();

    // copy out rows (160 shorts each)
    for (int idx = t; idx < 1280; idx += 128) {
        const int v = idx / 20, c = idx % 20;
        *(uint4*)(A_g + (size_t)(v0 + v) * 160 + c * 8) = *(const uint4*)(AT + v * 168 + c * 8);
    }
}

// ============================================================================
// Kernel 1b: conv3 on the matrix pipe (unchanged; A-row k-order is opaque).
// ============================================================================
__global__ __launch_bounds__(128) void conv3_kernel(
    const unsigned short* __restrict__ A_g,
    const unsigned short* __restrict__ w3b, const float* __restrict__ b3p,
    unsigned short* __restrict__ featb, float* __restrict__ dens)
{
    __shared__ __align__(16) unsigned short At[64 * 168];   // 21 KB
    __shared__ __align__(16) unsigned short Ct[64 * 136];   // 17 KB
    __shared__ float densT[64 * 8];                         // 2 KB
    const int t = threadIdx.x;
    const int v0 = blockIdx.x * 64;

    for (int idx = t; idx < 1280; idx += 128) {
        const int v = idx / 20, c = idx % 20;
        const uint4 u = *(const uint4*)(A_g + (size_t)(v0 + v) * 160 + c * 8);
        *(uint4*)(At + v * 168 + c * 8) = u;
    }
    __syncthreads();

    const int wv = t >> 6, lane = t & 63;
    const int quad = lane >> 4, l16 = lane & 15;

    f32x4 acc[4][4];
#pragma unroll
    for (int nt = 0; nt < 4; ++nt) {
        const float bv = b3p[64 * wv + 16 * nt + l16];
#pragma unroll
        for (int mt = 0; mt < 4; ++mt) {
            acc[mt][nt][0] = bv; acc[mt][nt][1] = bv;
            acc[mt][nt][2] = bv; acc[mt][nt][3] = bv;
        }
    }
#pragma unroll
    for (int kq = 0; kq < 5; ++kq) {
        const int k0 = 32 * kq + 8 * quad;
        bf16x8 a[4], b[4];
#pragma unroll
        for (int mt = 0; mt < 4; ++mt)
            a[mt] = __builtin_bit_cast(bf16x8, *(const uint4*)(At + (16 * mt + l16) * 168 + k0));
#pragma unroll
        for (int nt = 0; nt < 4; ++nt)
            b[nt] = __builtin_bit_cast(bf16x8, *(const uint4*)(w3b + (size_t)(64 * wv + 16 * nt + l16) * 160 + k0));
#pragma unroll
        for (int mt = 0; mt < 4; ++mt)
#pragma unroll
            for (int nt = 0; nt < 4; ++nt)
                acc[mt][nt] = __builtin_amdgcn_mfma_f32_16x16x32_bf16(a[mt], b[nt], acc[mt][nt], 0, 0, 0);
    }

    if (l16 == 0) {
#pragma unroll
        for (int mt = 0; mt < 4; ++mt)
#pragma unroll
            for (int nt = 0; nt < 4; ++nt) {
                const int s = 4 * wv + nt;
#pragma unroll
                for (int reg = 0; reg < 4; ++reg)
                    densT[(16 * mt + 4 * quad + reg) * 8 + s] = acc[mt][nt][reg];
            }
    }
#pragma unroll
    for (int mt = 0; mt < 4; ++mt)
#pragma unroll
        for (int nt = 0; nt < 4; ++nt)
#pragma unroll
            for (int reg = 0; reg < 4; ++reg)
                Ct[(16 * mt + 4 * quad + reg) * 136 + 64 * wv + 16 * nt + l16] =
                    (unsigned short)f2bf_u(acc[mt][nt][reg]);
    __syncthreads();

    const int v = t >> 1, half = t & 1;
    const int vg = v0 + v;
    const int Z = vg & 63, Y = (vg >> 6) & 63, X = vg >> 12;
#pragma unroll
    for (int si = 0; si < 4; ++si) {
        const int s = 4 * half + si;
        const int d2 = (s >> 2) & 1, h2 = (s >> 1) & 1, w2i = s & 1;
        const int ubase = ((2 * X + d2) * 128 + (2 * Y + h2)) * 128 + (2 * Z + w2i);
        const uint4 q0 = *(const uint4*)(Ct + v * 136 + 64 * half + 16 * si);
        const uint4 q1 = *(const uint4*)(Ct + v * 136 + 64 * half + 16 * si + 8);
        *(uint4*)(featb + (size_t)ubase * 16)     = q0;
        *(uint4*)(featb + (size_t)ubase * 16 + 8) = q1;
        dens[ubase] = densT[v * 8 + s];
    }
}

// ============================================================================
// Kernel 2: separable Sobel — three 1-D passes (kernel is a tensor product).
// Z: (az,bz) = (h_z, hd_z)*d. Y: (c1,c2,c3) = (h_y az, hd_y az, h_y bz).
// X: sx = hd_x c1, sy = h_x c2, sz = h_x c3; then /72, normalize, negate.
// ============================================================================
__global__ __launch_bounds__(256) void sobelZ_kernel(const float* __restrict__ dens,
                                                     float2* __restrict__ zbuf)
{
    const int v = blockIdx.x * 256 + threadIdx.x;
    const int z = v & 127;
    float d[5];
#pragma unroll
    for (int k = 0; k < 5; ++k) {
        const int zz = z + k - 2;
        d[k] = (zz >= 0 && zz < 128) ? dens[v + (k - 2)] : 0.f;
    }
    const float az = d[0] + 4.f * d[1] + 6.f * d[2] + 4.f * d[3] + d[4];
    const float bz = -d[0] - 2.f * d[1] + 2.f * d[3] + d[4];
    zbuf[v] = make_float2(az, bz);
}

__global__ __launch_bounds__(256) void sobelY_kernel(const float2* __restrict__ zbuf,
                                                     float4* __restrict__ cbuf)
{
    const int v = blockIdx.x * 256 + threadIdx.x;
    const int y = (v >> 7) & 127;
    float2 e[5];
#pragma unroll
    for (int j = 0; j < 5; ++j) {
        const int yy = y + j - 2;
        e[j] = (yy >= 0 && yy < 128) ? zbuf[v + (j - 2) * 128] : make_float2(0.f, 0.f);
    }
    const float c1 = e[0].x + 4.f * e[1].x + 6.f * e[2].x + 4.f * e[3].x + e[4].x;
    const float c2 = -e[0].x - 2.f * e[1].x + 2.f * e[3].x + e[4].x;
    const float c3 = e[0].y + 4.f * e[1].y + 6.f * e[2].y + 4.f * e[3].y + e[4].y;
    cbuf[v] = make_float4(c1, c2, c3, 0.f);
}

__global__ __launch_bounds__(256) void sobelX_kernel(const float4* __restrict__ cbuf,
                                                     float* __restrict__ normals)
{
    const int v = blockIdx.x * 256 + threadIdx.x;
    const int x = v >> 14;
    float4 q[5];
#pragma unroll
    for (int i = 0; i < 5; ++i) {
        const int xx = x + i - 2;
        q[i] = (xx >= 0 && xx < 128) ? cbuf[v + (i - 2) * 16384]
                                     : make_float4(0.f, 0.f, 0.f, 0.f);
    }
    float sx = -q[0].x - 2.f * q[1].x + 2.f * q[3].x + q[4].x;
    float sy = q[0].y + 4.f * q[1].y + 6.f * q[2].y + 4.f * q[3].y + q[4].y;
    float sz = q[0].z + 4.f * q[1].z + 6.f * q[2].z + 4.f * q[3].z + q[4].z;
    sx *= (1.f / 72.f); sy *= (1.f / 72.f); sz *= (1.f / 72.f);
    const float n = sqrtf(sx * sx + sy * sy + sz * sz);
    const float inv = 1.f / fmaxf(n, 1e-12f);
    normals[v * 3 + 0] = -sx * inv;
    normals[v * 3 + 1] = -sy * inv;
    normals[v * 3 + 2] = -sz * inv;
}

// ============================================================================
// Kernel 3: per-sample shading with MFMA MLP (unchanged from round 7).
// ============================================================================
__device__ __forceinline__ void mfma_layer(const unsigned short* A,
                                           unsigned short* D,
                                           const unsigned short* __restrict__ Wg,
                                           const float* __restrict__ bias,
                                           const int wv, const int lane)
{
    const int quad = lane >> 4, l16 = lane & 15;
    f32x4 acc[4][4];
#pragma unroll
    for (int nt = 0; nt < 4; ++nt) {
        const float bv = bias[16 * nt + l16];
#pragma unroll
        for (int mt = 0; mt < 4; ++mt) {
            acc[mt][nt][0] = bv; acc[mt][nt][1] = bv;
            acc[mt][nt][2] = bv; acc[mt][nt][3] = bv;
        }
    }
#pragma unroll
    for (int kq = 0; kq < 2; ++kq) {
        const int k0 = 32 * kq + 8 * quad;
        bf16x8 a[4], b[4];
#pragma unroll
        for (int mt = 0; mt < 4; ++mt)
            a[mt] = __builtin_bit_cast(bf16x8, *(const uint4*)(A + (64 * wv + 16 * mt + l16) * 72 + k0));
#pragma unroll
        for (int nt = 0; nt < 4; ++nt)
            b[nt] = __builtin_bit_cast(bf16x8, *(const uint4*)(Wg + (16 * nt + l16) * 64 + k0));
#pragma unroll
        for (int mt = 0; mt < 4; ++mt)
#pragma unroll
            for (int nt = 0; nt < 4; ++nt)
                acc[mt][nt] = __builtin_amdgcn_mfma_f32_16x16x32_bf16(a[mt], b[nt], acc[mt][nt], 0, 0, 0);
    }
#pragma unroll
    for (int mt = 0; mt < 4; ++mt)
#pragma unroll
        for (int nt = 0; nt < 4; ++nt)
#pragma unroll
            for (int reg = 0; reg < 4; ++reg) {
                const float v = fmaxf(acc[mt][nt][reg], 0.f);
                D[(64 * wv + 16 * mt + 4 * quad + reg) * 72 + 16 * nt + l16] =
                    (unsigned short)f2bf_u(v);
            }
}

__global__ __launch_bounds__(128) void sample_kernel(
    const float* __restrict__ ro, const float* __restrict__ rd, const float* __restrict__ vd,
    const unsigned short* __restrict__ featb, const float* __restrict__ dens,
    const float* __restrict__ normals,
    const unsigned short* __restrict__ m0t, const float* __restrict__ mb0,
    const unsigned short* __restrict__ m1t, const float* __restrict__ mb1,
    const unsigned short* __restrict__ m2t, const float* __restrict__ mb2,
    const float* __restrict__ mw3, const float* __restrict__ mb3,
    float* __restrict__ sbuf, const int total)
{
    __shared__ __align__(16) unsigned short actA[128 * 72];
    __shared__ __align__(16) unsigned short actB[128 * 72];

    const int t = threadIdx.x;
    const int s = blockIdx.x * 128 + t;
    const bool live = (s < total);
    bool act = false;
    float alpha = 0.f, ndx = 0.f, ndy = 0.f, ndz = 0.f;
    float nsx = 0.f, nsy = 0.f, nsz = 0.f, depth = 0.f;
    float hf[64];
#pragma unroll
    for (int q = 0; q < 64; ++q) hf[q] = 0.f;

    if (live) {
        const int r = s / S_SAMPLES;
        const int j = s - r * S_SAMPLES;

        const float ox = ro[r * 3 + 0], oy = ro[r * 3 + 1], oz = ro[r * 3 + 2];
        const float dx = rd[r * 3 + 0], dy = rd[r * 3 + 1], dz = rd[r * 3 + 2];
        const float vx = vd[r * 3 + 0], vy = vd[r * 3 + 1], vz = vd[r * 3 + 2];

        const float vecx = (dx == 0.f) ? 1e-6f : dx;
        const float vecy = (dy == 0.f) ? 1e-6f : dy;
        const float vecz = (dz == 0.f) ? 1e-6f : dz;
        const float rax = (1.f - ox) / vecx, rbx = (-1.f - ox) / vecx;
        const float ray2 = (1.f - oy) / vecy, rby = (-1.f - oy) / vecy;
        const float raz = (1.f - oz) / vecz, rbz = (-1.f - oz) / vecz;
        float tmin = fmaxf(fmaxf(fminf(rax, rbx), fminf(ray2, rby)), fminf(raz, rbz));
        float tmax = fminf(fminf(fmaxf(rax, rbx), fmaxf(ray2, rby)), fmaxf(raz, rbz));
        tmin = fminf(fmaxf(tmin, 0.2f), 6.0f);
        tmax = fminf(fmaxf(tmax, 0.2f), 6.0f);
        const bool mask_ray = (tmax <= tmin);

        const float ndr = sqrtf(dx * dx + dy * dy + dz * dz);
        const float interpx = tmin + (STEP_VOX * (float)j) / ndr;
        const float px = ox + dx * interpx;
        const float py = oy + dy * interpx;
        const float pz = oz + dz * interpx;
        const bool outbox = mask_ray || (px < -1.f) || (px > 1.f) || (py < -1.f) ||
                            (py > 1.f) || (pz < -1.f) || (pz > 1.f);
        act = !outbox;
        if (act) {
            const float ux = fminf(fmaxf((px + 1.f) * 63.5f, 0.f), 127.f);
            const float uy = fminf(fmaxf((py + 1.f) * 63.5f, 0.f), 127.f);
            const float uz = fminf(fmaxf((pz + 1.f) * 63.5f, 0.f), 127.f);
            const int ix = min(max((int)floorf(ux), 0), 126);
            const int iy = min(max((int)floorf(uy), 0), 126);
            const int iz = min(max((int)floorf(uz), 0), 126);
            const float fx = ux - (float)ix, fy = uy - (float)iy, fz = uz - (float)iz;

            float lat[15];
#pragma unroll
            for (int q = 0; q < 15; ++q) lat[q] = 0.f;
            float na0 = 0.f, na1 = 0.f, na2 = 0.f;
            float c0v[8];
#pragma unroll
            for (int cn = 0; cn < 8; ++cn) {
                const int adx = cn >> 2, ady = (cn >> 1) & 1, adz = cn & 1;
                const int vox = ((ix + adx) * 128 + (iy + ady)) * 128 + (iz + adz);
                const float w = (adx ? fx : 1.f - fx) * (ady ? fy : 1.f - fy) * (adz ? fz : 1.f - fz);
                c0v[cn] = dens[vox];
                const uint4* cp = (const uint4*)(featb + (size_t)vox * 16);
                const uint4 q0 = cp[0], q1 = cp[1];
                lat[0]  = fmaf(w, bf_hi(q0.x), lat[0]);
                lat[1]  = fmaf(w, bf_lo(q0.y), lat[1]);
                lat[2]  = fmaf(w, bf_hi(q0.y), lat[2]);
                lat[3]  = fmaf(w, bf_lo(q0.z), lat[3]);
                lat[4]  = fmaf(w, bf_hi(q0.z), lat[4]);
                lat[5]  = fmaf(w, bf_lo(q0.w), lat[5]);
                lat[6]  = fmaf(w, bf_hi(q0.w), lat[6]);
                lat[7]  = fmaf(w, bf_lo(q1.x), lat[7]);
                lat[8]  = fmaf(w, bf_hi(q1.x), lat[8]);
                lat[9]  = fmaf(w, bf_lo(q1.y), lat[9]);
                lat[10] = fmaf(w, bf_hi(q1.y), lat[10]);
                lat[11] = fmaf(w, bf_lo(q1.z), lat[11]);
                lat[12] = fmaf(w, bf_hi(q1.z), lat[12]);
                lat[13] = fmaf(w, bf_lo(q1.w), lat[13]);
                lat[14] = fmaf(w, bf_hi(q1.w), lat[14]);
                const float* np_ = normals + (size_t)vox * 3;
                na0 = fmaf(w, np_[0], na0);
                na1 = fmaf(w, np_[1], na1);
                na2 = fmaf(w, np_[2], na2);
            }

            const float c00 = c0v[0] * (1.f - fz) + c0v[1] * fz;
            const float c01 = c0v[2] * (1.f - fz) + c0v[3] * fz;
            const float c10 = c0v[4] * (1.f - fz) + c0v[5] * fz;
            const float c11 = c0v[6] * (1.f - fz) + c0v[7] * fz;
            const float e0 = c00 * (1.f - fy) + c01 * fy;
            const float e1 = c10 * (1.f - fy) + c11 * fy;
            const float d0 = e0 * (1.f - fx) + e1 * fx;
            const float dfx = e1 - e0;
            const float dfy = (c01 - c00) * (1.f - fx) + (c11 - c10) * fx;
            const float dfz = ((c0v[1] - c0v[0]) * (1.f - fy) + (c0v[3] - c0v[2]) * fy) * (1.f - fx)
                            + ((c0v[5] - c0v[4]) * (1.f - fy) + (c0v[7] - c0v[6]) * fy) * fx;

            const float zin = d0 + ACT_SHIFT;
            const float splus = fmaxf(zin, 0.f) + log1pf(__expf(-fabsf(zin)));
            const float e = __expf(-splus * 0.5f);
            alpha = 1.f - e;
            const float sig = 1.f / (1.f + __expf(-zin));
            const float dad = e * 0.5f * sig;
            const float gx = dad * dfx * 63.5f;
            const float gy = dad * dfy * 63.5f;
            const float gz = dad * dfz * 63.5f;
            const float gn = sqrtf(gx * gx + gy * gy + gz * gz);
            const float gi = 1.f / fmaxf(gn, 1e-12f);
            ndx = -gx * gi; ndy = -gy * gi; ndz = -gz * gi;

            const float nn = sqrtf(na0 * na0 + na1 * na1 + na2 * na2);
            const float ni = 1.f / fmaxf(nn, 1e-12f);
            nsx = -na0 * ni; nsy = -na1 * ni; nsz = -na2 * ni;

            const float dotv = -(vx * ndx + vy * ndy + vz * ndz);
            const float rx = 2.f * dotv * ndx + vx;
            const float ry = 2.f * dotv * ndy + vy;
            const float rz = 2.f * dotv * ndz + vz;

#pragma unroll
            for (int q = 0; q < 15; ++q) hf[q] = lat[q];
            hf[15] = rx; hf[16] = ry; hf[17] = rz;
#pragma unroll
            for (int fi = 0; fi < 6; ++fi) {
                const float fr = (float)(1 << fi);
                hf[18 + fi * 6 + 0] = __sinf(rx * fr);
                hf[18 + fi * 6 + 1] = __sinf(ry * fr);
                hf[18 + fi * 6 + 2] = __sinf(rz * fr);
                hf[18 + fi * 6 + 3] = __cosf(rx * fr);
                hf[18 + fi * 6 + 4] = __cosf(ry * fr);
                hf[18 + fi * 6 + 5] = __cosf(rz * fr);
            }
            depth = interpx * ndr;
        }
    }

#pragma unroll
    for (int q = 0; q < 8; ++q) {
        uint4 st;
        st.x = f2bf_u(hf[8 * q + 0]) | (f2bf_u(hf[8 * q + 1]) << 16);
        st.y = f2bf_u(hf[8 * q + 2]) | (f2bf_u(hf[8 * q + 3]) << 16);
        st.z = f2bf_u(hf[8 * q + 4]) | (f2bf_u(hf[8 * q + 5]) << 16);
        st.w = f2bf_u(hf[8 * q + 6]) | (f2bf_u(hf[8 * q + 7]) << 16);
        *(uint4*)(actA + t * 72 + 8 * q) = st;
    }
    __syncthreads();

    const int wv = t >> 6, lane = t & 63;
    mfma_layer(actA, actB, m0t, mb0, wv, lane);
    __syncthreads();
    mfma_layer(actB, actA, m1t, mb1, wv, lane);
    __syncthreads();
    mfma_layer(actA, actB, m2t, mb2, wv, lane);
    __syncthreads();

    if (live) {
        float* so = sbuf + (size_t)s * 12;
        if (act) {
            float r0 = mb3[0], r1 = mb3[1], r2 = mb3[2];
            const unsigned short* hr = actB + t * 72;
#pragma unroll
            for (int c8 = 0; c8 < 8; ++c8) {
                const uint4 hu = *(const uint4*)(hr + 8 * c8);
                const float h[8] = {bf_lo(hu.x), bf_hi(hu.x), bf_lo(hu.y), bf_hi(hu.y),
                                    bf_lo(hu.z), bf_hi(hu.z), bf_lo(hu.w), bf_hi(hu.w)};
#pragma unroll
                for (int u = 0; u < 8; ++u) {
                    const int c = 8 * c8 + u;
                    r0 = fmaf(h[u], mw3[c * 3 + 0], r0);
                    r1 = fmaf(h[u], mw3[c * 3 + 1], r1);
                    r2 = fmaf(h[u], mw3[c * 3 + 2], r2);
                }
            }
            so[0] = alpha;
            so[1] = 1.f / (1.f + __expf(-r0));
            so[2] = 1.f / (1.f + __expf(-r1));
            so[3] = 1.f / (1.f + __expf(-r2));
            so[4] = ndx; so[5] = ndy; so[6] = ndz;
            so[7] = nsx; so[8] = nsy; so[9] = nsz;
            so[10] = depth;
            so[11] = 0.f;
        } else {
#pragma unroll
            for (int q = 0; q < 12; ++q) so[q] = 0.f;
        }
    }
}

// ============================================================================
// Kernel 4: per-ray compositing (wave per ray; segmented product scan).
// ============================================================================
__global__ __launch_bounds__(64) void reduce_kernel(const float* __restrict__ sbuf,
                                                    float* __restrict__ out)
{
    const int r = blockIdx.x;
    const int lane = threadIdx.x;
    const int per = (S_SAMPLES + 63) / 64;   // 7
    const int j0 = lane * per;
    const int j1 = min(S_SAMPLES, j0 + per);

    float p = 1.f;
    for (int j = j0; j < j1; ++j) {
        const float a = sbuf[((size_t)r * S_SAMPLES + j) * 12];
        p *= fmaxf(1.f - a, 1e-10f);
    }
    float scan = p;
#pragma unroll
    for (int off = 1; off < 64; off <<= 1) {
        const float nv = __shfl_up(scan, (unsigned)off, 64);
        if (lane >= off) scan *= nv;
    }
    const float total = __shfl(scan, 63, 64);
    float pref = __shfl_up(scan, 1u, 64);
    if (lane == 0) pref = 1.f;

    float s0 = 0, s1 = 0, s2 = 0, s3 = 0, s4 = 0, s5 = 0, s6 = 0, s7 = 0, s8 = 0, s9 = 0, s10 = 0;
    for (int j = j0; j < j1; ++j) {
        const float* sp_ = sbuf + ((size_t)r * S_SAMPLES + j) * 12;
        const float a = sp_[0];
        const float w = a * pref;
        pref *= fmaxf(1.f - a, 1e-10f);
        s0 = fmaf(w, sp_[1], s0);
        s1 = fmaf(w, sp_[2], s1);
        s2 = fmaf(w, sp_[3], s2);
        s3 = fmaf(w, sp_[10], s3);
        s4 += w;
        s5 = fmaf(w, sp_[4], s5);
        s6 = fmaf(w, sp_[5], s6);
        s7 = fmaf(w, sp_[6], s7);
        s8 = fmaf(w, sp_[7], s8);
        s9 = fmaf(w, sp_[8], s9);
        s10 = fmaf(w, sp_[9], s10);
    }
#pragma unroll
    for (int m = 32; m >= 1; m >>= 1) {
        s0 += __shfl_xor(s0, m, 64);
        s1 += __shfl_xor(s1, m, 64);
        s2 += __shfl_xor(s2, m, 64);
        s3 += __shfl_xor(s3, m, 64);
        s4 += __shfl_xor(s4, m, 64);
        s5 += __shfl_xor(s5, m, 64);
        s6 += __shfl_xor(s6, m, 64);
        s7 += __shfl_xor(s7, m, 64);
        s8 += __shfl_xor(s8, m, 64);
        s9 += __shfl_xor(s9, m, 64);
        s10 += __shfl_xor(s10, m, 64);
    }
    if (lane == 0) {
        const float dm = s3 + total * 6.0f;
        out[r * 12 + 0] = s0 + total;
        out[r * 12 + 1] = s1 + total;
        out[r * 12 + 2] = s2 + total;
        out[r * 12 + 3] = dm;
        out[r * 12 + 4] = 1.f / dm;
        out[r * 12 + 5] = s4;
        out[r * 12 + 6] = s5; out[r * 12 + 7] = s6; out[r * 12 + 8] = s7;
        out[r * 12 + 9] = s8; out[r * 12 + 10] = s9; out[r * 12 + 11] = s10;
    }
}

// ============================================================================
extern "C" void kernel_launch(void* const* d_in, const int* in_sizes, int n_in,
                              void* d_out, int out_size, void* d_ws, size_t ws_size,
                              hipStream_t stream)
{
    (void)n_in; (void)out_size; (void)ws_size;
    const float* rays_o   = (const float*)d_in[0];
    const float* rays_d   = (const float*)d_in[1];
    const float* viewdirs = (const float*)d_in[2];
    const float* grid     = (const float*)d_in[3];
    const float* c1_w  = (const float*)d_in[4];
    const float* c1_b  = (const float*)d_in[5];
    const float* bn1_g = (const float*)d_in[6];
    const float* bn1_b = (const float*)d_in[7];
    const float* pr1_a = (const float*)d_in[8];
    const float* c2_w  = (const float*)d_in[9];
    const float* c2_b  = (const float*)d_in[10];
    const float* bn2_g = (const float*)d_in[11];
    const float* bn2_b = (const float*)d_in[12];
    const float* pr2_a = (const float*)d_in[13];
    const float* c3_w  = (const float*)d_in[14];
    const float* c3_b  = (const float*)d_in[15];
    const float* mw0 = (const float*)d_in[16];
    const float* mb0 = (const float*)d_in[17];
    const float* mw1 = (const float*)d_in[18];
    const float* mb1 = (const float*)d_in[19];
    const float* mw2 = (const float*)d_in[20];
    const float* mb2 = (const float*)d_in[21];
    const float* mw3 = (const float*)d_in[22];
    const float* mb3 = (const float*)d_in[23];

    const int N = in_sizes[0] / 3;   // 1024 rays
    const int total = N * S_SAMPLES;

    // ws layout (float units), ~181.4 MB total:
    // featb [0,16777216) | dens [16777216,18874368) |
    // A_g bf16[262144][160] = [18874368,39845888)
    //   after conv3, A_g region is recycled:
    //   normals [18874368,25165824) | zbuf f2 [25165824,29360128) |
    //   cbuf f4 [29360128,37748736)
    // sbuf [39845888,45337600) | weights [45337600,...)
    float* wsf = (float*)d_ws;
    unsigned short* featb = (unsigned short*)wsf;
    float* dens    = wsf + (size_t)16777216;
    unsigned short* A_g = (unsigned short*)(wsf + (size_t)18874368);
    float* normals = wsf + (size_t)18874368;
    float2* zbuf   = (float2*)(wsf + (size_t)25165824);
    float4* cbuf   = (float4*)(wsf + (size_t)29360128);
    float* sbuf    = wsf + (size_t)39845888;
    float* b3p = wsf + (size_t)45337600;
    unsigned short* w1b = (unsigned short*)(wsf + (size_t)45337728);   // 2048 bf16
    unsigned short* w2b = (unsigned short*)(wsf + (size_t)45338752);   // 6144 bf16
    unsigned short* w3b = (unsigned short*)(wsf + (size_t)45341824);   // 20480 bf16
    unsigned short* m0t = (unsigned short*)(wsf + (size_t)45352064);
    unsigned short* m1t = (unsigned short*)(wsf + (size_t)45354112);
    unsigned short* m2t = (unsigned short*)(wsf + (size_t)45356160);

    prep_kernel<<<1, 256, 0, stream>>>(c1_w, c2_w, c3_w, c3_b, mw0, mw1, mw2,
                                       w1b, w2b, w3b, b3p, m0t, m1t, m2t);
    conv12_kernel<<<4096, 128, 0, stream>>>(grid, w1b, c1_b, bn1_g, bn1_b, pr1_a,
                                            w2b, c2_b, bn2_g, bn2_b, pr2_a, A_g);
    conv3_kernel<<<4096, 128, 0, stream>>>(A_g, w3b, b3p, featb, dens);
    sobelZ_kernel<<<8192, 256, 0, stream>>>(dens, zbuf);
    sobelY_kernel<<<8192, 256, 0, stream>>>(zbuf, cbuf);
    sobelX_kernel<<<8192, 256, 0, stream>>>(cbuf, normals);
    const int sblocks = (total + 127) / 128;
    sample_kernel<<<sblocks, 128, 0, stream>>>(rays_o, rays_d, viewdirs, featb, dens, normals,
                                               m0t, mb0, m1t, mb1, m2t, mb2, mw3, mb3,
                                               sbuf, total);
    reduce_kernel<<<N, 64, 0, stream>>>(sbuf, (float*)d_out);
}

// Round 9
// 258.857 us; speedup vs baseline: 16.1117x; 1.2799x over previous
//
#include <hip/hip_runtime.h>
#include <math.h>

// ---- constants from the reference ----
#define S_SAMPLES 447                      // int(norm([129]*3)/0.5)+1
#define ACT_SHIFT -9.210240366971207f      // log(1/(1-1e-4) - 1)
#define BN_SCALE_C 0.9999950000374997f     // (1+1e-5)^-0.5
#define STEP_VOX 0.015625f                 // STEPSIZE * VOXEL = 0.5 * (2/64)

__device__ __forceinline__ unsigned f2bf_u(float f) {
    unsigned u = __float_as_uint(f);
    return (u + 0x7fffu + ((u >> 16) & 1u)) >> 16;   // RNE, low 16 bits
}
__device__ __forceinline__ float bf2f(unsigned short u) {
    return __uint_as_float(((unsigned)u) << 16);
}
__device__ __forceinline__ float bf_lo(unsigned u) { return __uint_as_float(u << 16); }
__device__ __forceinline__ float bf_hi(unsigned u) { return __uint_as_float(u & 0xffff0000u); }

typedef __attribute__((ext_vector_type(8))) short bf16x8;   // MFMA A/B frag (4 VGPRs)
typedef __attribute__((ext_vector_type(4))) float f32x4;    // MFMA C/D frag

// ============================================================================
// Kernel 0: prep — weight transposes. GRID-STRIDE over 64 blocks (a single
// block serialized on one CU cost 60-80 us in round 8!).
// A-row k-order: [x1(0-63) | grid(64-79) | 0(80-95) | x2(96-159)].
// ============================================================================
__global__ __launch_bounds__(256) void prep_kernel(
    const float* __restrict__ w1, const float* __restrict__ w2,
    const float* __restrict__ w3, const float* __restrict__ b3,
    const float* __restrict__ mw0, const float* __restrict__ mw1,
    const float* __restrict__ mw2,
    unsigned short* __restrict__ w1b, unsigned short* __restrict__ w2b,
    unsigned short* __restrict__ w3b, float* __restrict__ b3p,
    unsigned short* __restrict__ m0t, unsigned short* __restrict__ m1t,
    unsigned short* __restrict__ m2t)
{
    const int gid = blockIdx.x * 256 + threadIdx.x;
    const int gs = gridDim.x * 256;
    for (int idx = gid; idx < 2048; idx += gs) {         // w1b [64 o][32 k]
        const int o = idx >> 5, k = idx & 31;
        w1b[idx] = (k < 16) ? (unsigned short)f2bf_u(w1[o * 16 + k]) : 0;
    }
    for (int idx = gid; idx < 6144; idx += gs) {         // w2b [64 o][96 k]
        const int o = idx / 96, k = idx % 96;
        w2b[idx] = (k < 80) ? (unsigned short)f2bf_u(w2[o * 80 + k]) : 0;
    }
    for (int idx = gid; idx < 20480; idx += gs) {        // w3b [128 n][160 k]
        const int n = idx / 160, k = idx % 160;
        const int s = n >> 4, l = n & 15;
        const int o = l * 8 + s;
        float val = 0.f;
        if (k < 64)       val = w3[o * 144 + k];             // x1 part
        else if (k < 80)  val = w3[o * 144 + 128 + (k - 64)];// grid part
        else if (k >= 96) val = w3[o * 144 + 64 + (k - 96)]; // x2 part
        w3b[idx] = (unsigned short)f2bf_u(val);
    }
    for (int idx = gid; idx < 128; idx += gs) {
        const int o = idx;
        b3p[(o & 7) * 16 + (o >> 3)] = b3[o];
    }
    for (int idx = gid; idx < 4096; idx += gs) {
        const int o = idx >> 6, k = idx & 63;
        m0t[o * 64 + k] = (k < 54) ? (unsigned short)f2bf_u(mw0[k * 64 + o]) : 0;
    }
    for (int idx = gid; idx < 4096; idx += gs) {
        const int o = idx >> 6, k = idx & 63;
        m1t[o * 64 + k] = (unsigned short)f2bf_u(mw1[k * 64 + o]);
    }
    for (int idx = gid; idx < 4096; idx += gs) {
        const int o = idx >> 6, k = idx & 63;
        m2t[o * 64 + k] = (unsigned short)f2bf_u(mw2[k * 64 + o]);
    }
}

// ============================================================================
// Kernel 1: FUSED conv1+conv2+conv3 on the matrix pipe. Block = 128 thr
// (2 waves) = 64 voxels. The AT tile (bf16 [64 v][168]) is built in LDS:
// grid->cols 64-79, conv1 out->cols 0-63, conv2 out->cols 96-159, 80-95 zero.
// conv3 (K=160, 80 MFMA/wave) reads AT directly — no A_g HBM round-trip.
// Epilogue: Ct bf16 transpose -> 16B featb stores; densT fp32-exact.
// ============================================================================
__global__ __launch_bounds__(128) void conv_fused_kernel(
    const float* __restrict__ grid,
    const unsigned short* __restrict__ w1b, const float* __restrict__ b1,
    const float* __restrict__ g1, const float* __restrict__ bb1, const float* __restrict__ a1,
    const unsigned short* __restrict__ w2b, const float* __restrict__ b2,
    const float* __restrict__ g2, const float* __restrict__ bb2, const float* __restrict__ a2,
    const unsigned short* __restrict__ w3b, const float* __restrict__ b3p,
    unsigned short* __restrict__ featb, float* __restrict__ dens)
{
    __shared__ __align__(16) unsigned short AT[64 * 168];   // 21 KB
    __shared__ __align__(16) unsigned short Ct[64 * 136];   // 17 KB
    __shared__ float densT[64 * 8];                         // 2 KB
    const int t = threadIdx.x;
    const int v0 = blockIdx.x * 64;

    // zero cols 80..95
    for (int idx = t; idx < 512; idx += 128) {
        const int v = idx >> 3, c = idx & 7;
        *(unsigned*)(AT + v * 168 + 80 + c * 2) = 0;
    }
    // grid -> AT cols 64..79 (bf16)
    {
        const int vv = t & 63, half = t >> 6;
        for (int c = half; c < 16; c += 2) {
            const float gv = grid[(size_t)c * 262144 + v0 + vv];
            AT[vv * 168 + 64 + c] = (unsigned short)f2bf_u(gv);
        }
    }
    __syncthreads();

    const int wv = t >> 6, lane = t & 63;
    const int quad = lane >> 4, l16 = lane & 15;
    const int ch0 = 32 * wv + l16;          // nt adds 16

    // ---- conv1: A cols 64..95 (K=32), out -> cols 0..63 ----
    {
        f32x4 acc[4][2];
        float gs[2], bb[2], al[2];
#pragma unroll
        for (int nt = 0; nt < 2; ++nt) {
            const int ch = ch0 + 16 * nt;
            const float bch = b1[ch];
            gs[nt] = BN_SCALE_C * g1[ch]; bb[nt] = bb1[ch]; al[nt] = a1[ch];
#pragma unroll
            for (int mt = 0; mt < 4; ++mt) {
                acc[mt][nt][0] = bch; acc[mt][nt][1] = bch;
                acc[mt][nt][2] = bch; acc[mt][nt][3] = bch;
            }
        }
        const int k0 = 8 * quad;
        bf16x8 a[4], b[2];
#pragma unroll
        for (int mt = 0; mt < 4; ++mt)
            a[mt] = __builtin_bit_cast(bf16x8, *(const uint4*)(AT + (16 * mt + l16) * 168 + 64 + k0));
#pragma unroll
        for (int nt = 0; nt < 2; ++nt)
            b[nt] = __builtin_bit_cast(bf16x8, *(const uint4*)(w1b + (ch0 + 16 * nt) * 32 + k0));
#pragma unroll
        for (int mt = 0; mt < 4; ++mt)
#pragma unroll
            for (int nt = 0; nt < 2; ++nt)
                acc[mt][nt] = __builtin_amdgcn_mfma_f32_16x16x32_bf16(a[mt], b[nt], acc[mt][nt], 0, 0, 0);
#pragma unroll
        for (int mt = 0; mt < 4; ++mt)
#pragma unroll
            for (int nt = 0; nt < 2; ++nt)
#pragma unroll
                for (int reg = 0; reg < 4; ++reg) {
                    float x = acc[mt][nt][reg] * gs[nt] + bb[nt];
                    x = (x >= 0.f) ? x : al[nt] * x;
                    AT[(16 * mt + 4 * quad + reg) * 168 + ch0 + 16 * nt] = (unsigned short)f2bf_u(x);
                }
    }
    __syncthreads();

    // ---- conv2: A cols 0..95 (K=96), out -> cols 96..159 ----
    {
        f32x4 acc[4][2];
        float gs[2], bb[2], al[2];
#pragma unroll
        for (int nt = 0; nt < 2; ++nt) {
            const int ch = ch0 + 16 * nt;
            const float bch = b2[ch];
            gs[nt] = BN_SCALE_C * g2[ch]; bb[nt] = bb2[ch]; al[nt] = a2[ch];
#pragma unroll
            for (int mt = 0; mt < 4; ++mt) {
                acc[mt][nt][0] = bch; acc[mt][nt][1] = bch;
                acc[mt][nt][2] = bch; acc[mt][nt][3] = bch;
            }
        }
#pragma unroll
        for (int kq = 0; kq < 3; ++kq) {
            const int k0 = 32 * kq + 8 * quad;
            bf16x8 a[4], b[2];
#pragma unroll
            for (int mt = 0; mt < 4; ++mt)
                a[mt] = __builtin_bit_cast(bf16x8, *(const uint4*)(AT + (16 * mt + l16) * 168 + k0));
#pragma unroll
            for (int nt = 0; nt < 2; ++nt)
                b[nt] = __builtin_bit_cast(bf16x8, *(const uint4*)(w2b + (ch0 + 16 * nt) * 96 + k0));
#pragma unroll
            for (int mt = 0; mt < 4; ++mt)
#pragma unroll
                for (int nt = 0; nt < 2; ++nt)
                    acc[mt][nt] = __builtin_amdgcn_mfma_f32_16x16x32_bf16(a[mt], b[nt], acc[mt][nt], 0, 0, 0);
        }
#pragma unroll
        for (int mt = 0; mt < 4; ++mt)
#pragma unroll
            for (int nt = 0; nt < 2; ++nt)
#pragma unroll
                for (int reg = 0; reg < 4; ++reg) {
                    float x = acc[mt][nt][reg] * gs[nt] + bb[nt];
                    x = (x >= 0.f) ? x : al[nt] * x;
                    AT[(16 * mt + 4 * quad + reg) * 168 + 96 + ch0 + 16 * nt] = (unsigned short)f2bf_u(x);
                }
    }
    __syncthreads();

    // ---- conv3: A cols 0..159 (K=160), 4x4 tiles ----
    {
        f32x4 acc[4][4];
#pragma unroll
        for (int nt = 0; nt < 4; ++nt) {
            const float bv = b3p[64 * wv + 16 * nt + l16];
#pragma unroll
            for (int mt = 0; mt < 4; ++mt) {
                acc[mt][nt][0] = bv; acc[mt][nt][1] = bv;
                acc[mt][nt][2] = bv; acc[mt][nt][3] = bv;
            }
        }
#pragma unroll
        for (int kq = 0; kq < 5; ++kq) {
            const int k0 = 32 * kq + 8 * quad;
            bf16x8 a[4], b[4];
#pragma unroll
            for (int mt = 0; mt < 4; ++mt)
                a[mt] = __builtin_bit_cast(bf16x8, *(const uint4*)(AT + (16 * mt + l16) * 168 + k0));
#pragma unroll
            for (int nt = 0; nt < 4; ++nt)
                b[nt] = __builtin_bit_cast(bf16x8, *(const uint4*)(w3b + (size_t)(64 * wv + 16 * nt + l16) * 160 + k0));
#pragma unroll
            for (int mt = 0; mt < 4; ++mt)
#pragma unroll
                for (int nt = 0; nt < 4; ++nt)
                    acc[mt][nt] = __builtin_amdgcn_mfma_f32_16x16x32_bf16(a[mt], b[nt], acc[mt][nt], 0, 0, 0);
        }

        if (l16 == 0) {
#pragma unroll
            for (int mt = 0; mt < 4; ++mt)
#pragma unroll
                for (int nt = 0; nt < 4; ++nt) {
                    const int s = 4 * wv + nt;
#pragma unroll
                    for (int reg = 0; reg < 4; ++reg)
                        densT[(16 * mt + 4 * quad + reg) * 8 + s] = acc[mt][nt][reg];
                }
        }
#pragma unroll
        for (int mt = 0; mt < 4; ++mt)
#pragma unroll
            for (int nt = 0; nt < 4; ++nt)
#pragma unroll
                for (int reg = 0; reg < 4; ++reg)
                    Ct[(16 * mt + 4 * quad + reg) * 136 + 64 * wv + 16 * nt + l16] =
                        (unsigned short)f2bf_u(acc[mt][nt][reg]);
    }
    __syncthreads();

    // epilogue: thread = (voxel, n-half); 16B featb stores + fp32 dens
    const int v = t >> 1, half = t & 1;
    const int vg = v0 + v;
    const int Z = vg & 63, Y = (vg >> 6) & 63, X = vg >> 12;
#pragma unroll
    for (int si = 0; si < 4; ++si) {
        const int s = 4 * half + si;
        const int d2 = (s >> 2) & 1, h2 = (s >> 1) & 1, w2i = s & 1;
        const int ubase = ((2 * X + d2) * 128 + (2 * Y + h2)) * 128 + (2 * Z + w2i);
        const uint4 q0 = *(const uint4*)(Ct + v * 136 + 64 * half + 16 * si);
        const uint4 q1 = *(const uint4*)(Ct + v * 136 + 64 * half + 16 * si + 8);
        *(uint4*)(featb + (size_t)ubase * 16)     = q0;
        *(uint4*)(featb + (size_t)ubase * 16 + 8) = q1;
        dens[ubase] = densT[v * 8 + s];
    }
}

// ============================================================================
// Kernel 2: separable Sobel — three 1-D passes.
// ============================================================================
__global__ __launch_bounds__(256) void sobelZ_kernel(const float* __restrict__ dens,
                                                     float2* __restrict__ zbuf)
{
    const int v = blockIdx.x * 256 + threadIdx.x;
    const int z = v & 127;
    float d[5];
#pragma unroll
    for (int k = 0; k < 5; ++k) {
        const int zz = z + k - 2;
        d[k] = (zz >= 0 && zz < 128) ? dens[v + (k - 2)] : 0.f;
    }
    const float az = d[0] + 4.f * d[1] + 6.f * d[2] + 4.f * d[3] + d[4];
    const float bz = -d[0] - 2.f * d[1] + 2.f * d[3] + d[4];
    zbuf[v] = make_float2(az, bz);
}

__global__ __launch_bounds__(256) void sobelY_kernel(const float2* __restrict__ zbuf,
                                                     float4* __restrict__ cbuf)
{
    const int v = blockIdx.x * 256 + threadIdx.x;
    const int y = (v >> 7) & 127;
    float2 e[5];
#pragma unroll
    for (int j = 0; j < 5; ++j) {
        const int yy = y + j - 2;
        e[j] = (yy >= 0 && yy < 128) ? zbuf[v + (j - 2) * 128] : make_float2(0.f, 0.f);
    }
    const float c1 = e[0].x + 4.f * e[1].x + 6.f * e[2].x + 4.f * e[3].x + e[4].x;
    const float c2 = -e[0].x - 2.f * e[1].x + 2.f * e[3].x + e[4].x;
    const float c3 = e[0].y + 4.f * e[1].y + 6.f * e[2].y + 4.f * e[3].y + e[4].y;
    cbuf[v] = make_float4(c1, c2, c3, 0.f);
}

__global__ __launch_bounds__(256) void sobelX_kernel(const float4* __restrict__ cbuf,
                                                     float* __restrict__ normals)
{
    const int v = blockIdx.x * 256 + threadIdx.x;
    const int x = v >> 14;
    float4 q[5];
#pragma unroll
    for (int i = 0; i < 5; ++i) {
        const int xx = x + i - 2;
        q[i] = (xx >= 0 && xx < 128) ? cbuf[v + (i - 2) * 16384]
                                     : make_float4(0.f, 0.f, 0.f, 0.f);
    }
    float sx = -q[0].x - 2.f * q[1].x + 2.f * q[3].x + q[4].x;
    float sy = q[0].y + 4.f * q[1].y + 6.f * q[2].y + 4.f * q[3].y + q[4].y;
    float sz = q[0].z + 4.f * q[1].z + 6.f * q[2].z + 4.f * q[3].z + q[4].z;
    sx *= (1.f / 72.f); sy *= (1.f / 72.f); sz *= (1.f / 72.f);
    const float n = sqrtf(sx * sx + sy * sy + sz * sz);
    const float inv = 1.f / fmaxf(n, 1e-12f);
    normals[v * 3 + 0] = -sx * inv;
    normals[v * 3 + 1] = -sy * inv;
    normals[v * 3 + 2] = -sz * inv;
}

// ============================================================================
// Kernel 3: per-sample shading with MFMA MLP (unchanged from round 8).
// ============================================================================
__device__ __forceinline__ void mfma_layer(const unsigned short* A,
                                           unsigned short* D,
                                           const unsigned short* __restrict__ Wg,
                                           const float* __restrict__ bias,
                                           const int wv, const int lane)
{
    const int quad = lane >> 4, l16 = lane & 15;
    f32x4 acc[4][4];
#pragma unroll
    for (int nt = 0; nt < 4; ++nt) {
        const float bv = bias[16 * nt + l16];
#pragma unroll
        for (int mt = 0; mt < 4; ++mt) {
            acc[mt][nt][0] = bv; acc[mt][nt][1] = bv;
            acc[mt][nt][2] = bv; acc[mt][nt][3] = bv;
        }
    }
#pragma unroll
    for (int kq = 0; kq < 2; ++kq) {
        const int k0 = 32 * kq + 8 * quad;
        bf16x8 a[4], b[4];
#pragma unroll
        for (int mt = 0; mt < 4; ++mt)
            a[mt] = __builtin_bit_cast(bf16x8, *(const uint4*)(A + (64 * wv + 16 * mt + l16) * 72 + k0));
#pragma unroll
        for (int nt = 0; nt < 4; ++nt)
            b[nt] = __builtin_bit_cast(bf16x8, *(const uint4*)(Wg + (16 * nt + l16) * 64 + k0));
#pragma unroll
        for (int mt = 0; mt < 4; ++mt)
#pragma unroll
            for (int nt = 0; nt < 4; ++nt)
                acc[mt][nt] = __builtin_amdgcn_mfma_f32_16x16x32_bf16(a[mt], b[nt], acc[mt][nt], 0, 0, 0);
    }
#pragma unroll
    for (int mt = 0; mt < 4; ++mt)
#pragma unroll
        for (int nt = 0; nt < 4; ++nt)
#pragma unroll
            for (int reg = 0; reg < 4; ++reg) {
                const float v = fmaxf(acc[mt][nt][reg], 0.f);
                D[(64 * wv + 16 * mt + 4 * quad + reg) * 72 + 16 * nt + l16] =
                    (unsigned short)f2bf_u(v);
            }
}

__global__ __launch_bounds__(128) void sample_kernel(
    const float* __restrict__ ro, const float* __restrict__ rd, const float* __restrict__ vd,
    const unsigned short* __restrict__ featb, const float* __restrict__ dens,
    const float* __restrict__ normals,
    const unsigned short* __restrict__ m0t, const float* __restrict__ mb0,
    const unsigned short* __restrict__ m1t, const float* __restrict__ mb1,
    const unsigned short* __restrict__ m2t, const float* __restrict__ mb2,
    const float* __restrict__ mw3, const float* __restrict__ mb3,
    float* __restrict__ sbuf, const int total)
{
    __shared__ __align__(16) unsigned short actA[128 * 72];
    __shared__ __align__(16) unsigned short actB[128 * 72];

    const int t = threadIdx.x;
    const int s = blockIdx.x * 128 + t;
    const bool live = (s < total);
    bool act = false;
    float alpha = 0.f, ndx = 0.f, ndy = 0.f, ndz = 0.f;
    float nsx = 0.f, nsy = 0.f, nsz = 0.f, depth = 0.f;
    float hf[64];
#pragma unroll
    for (int q = 0; q < 64; ++q) hf[q] = 0.f;

    if (live) {
        const int r = s / S_SAMPLES;
        const int j = s - r * S_SAMPLES;

        const float ox = ro[r * 3 + 0], oy = ro[r * 3 + 1], oz = ro[r * 3 + 2];
        const float dx = rd[r * 3 + 0], dy = rd[r * 3 + 1], dz = rd[r * 3 + 2];
        const float vx = vd[r * 3 + 0], vy = vd[r * 3 + 1], vz = vd[r * 3 + 2];

        const float vecx = (dx == 0.f) ? 1e-6f : dx;
        const float vecy = (dy == 0.f) ? 1e-6f : dy;
        const float vecz = (dz == 0.f) ? 1e-6f : dz;
        const float rax = (1.f - ox) / vecx, rbx = (-1.f - ox) / vecx;
        const float ray2 = (1.f - oy) / vecy, rby = (-1.f - oy) / vecy;
        const float raz = (1.f - oz) / vecz, rbz = (-1.f - oz) / vecz;
        float tmin = fmaxf(fmaxf(fminf(rax, rbx), fminf(ray2, rby)), fminf(raz, rbz));
        float tmax = fminf(fminf(fmaxf(rax, rbx), fmaxf(ray2, rby)), fmaxf(raz, rbz));
        tmin = fminf(fmaxf(tmin, 0.2f), 6.0f);
        tmax = fminf(fmaxf(tmax, 0.2f), 6.0f);
        const bool mask_ray = (tmax <= tmin);

        const float ndr = sqrtf(dx * dx + dy * dy + dz * dz);
        const float interpx = tmin + (STEP_VOX * (float)j) / ndr;
        const float px = ox + dx * interpx;
        const float py = oy + dy * interpx;
        const float pz = oz + dz * interpx;
        const bool outbox = mask_ray || (px < -1.f) || (px > 1.f) || (py < -1.f) ||
                            (py > 1.f) || (pz < -1.f) || (pz > 1.f);
        act = !outbox;
        if (act) {
            const float ux = fminf(fmaxf((px + 1.f) * 63.5f, 0.f), 127.f);
            const float uy = fminf(fmaxf((py + 1.f) * 63.5f, 0.f), 127.f);
            const float uz = fminf(fmaxf((pz + 1.f) * 63.5f, 0.f), 127.f);
            const int ix = min(max((int)floorf(ux), 0), 126);
            const int iy = min(max((int)floorf(uy), 0), 126);
            const int iz = min(max((int)floorf(uz), 0), 126);
            const float fx = ux - (float)ix, fy = uy - (float)iy, fz = uz - (float)iz;

            float lat[15];
#pragma unroll
            for (int q = 0; q < 15; ++q) lat[q] = 0.f;
            float na0 = 0.f, na1 = 0.f, na2 = 0.f;
            float c0v[8];
#pragma unroll
            for (int cn = 0; cn < 8; ++cn) {
                const int adx = cn >> 2, ady = (cn >> 1) & 1, adz = cn & 1;
                const int vox = ((ix + adx) * 128 + (iy + ady)) * 128 + (iz + adz);
                const float w = (adx ? fx : 1.f - fx) * (ady ? fy : 1.f - fy) * (adz ? fz : 1.f - fz);
                c0v[cn] = dens[vox];
                const uint4* cp = (const uint4*)(featb + (size_t)vox * 16);
                const uint4 q0 = cp[0], q1 = cp[1];
                lat[0]  = fmaf(w, bf_hi(q0.x), lat[0]);
                lat[1]  = fmaf(w, bf_lo(q0.y), lat[1]);
                lat[2]  = fmaf(w, bf_hi(q0.y), lat[2]);
                lat[3]  = fmaf(w, bf_lo(q0.z), lat[3]);
                lat[4]  = fmaf(w, bf_hi(q0.z), lat[4]);
                lat[5]  = fmaf(w, bf_lo(q0.w), lat[5]);
                lat[6]  = fmaf(w, bf_hi(q0.w), lat[6]);
                lat[7]  = fmaf(w, bf_lo(q1.x), lat[7]);
                lat[8]  = fmaf(w, bf_hi(q1.x), lat[8]);
                lat[9]  = fmaf(w, bf_lo(q1.y), lat[9]);
                lat[10] = fmaf(w, bf_hi(q1.y), lat[10]);
                lat[11] = fmaf(w, bf_lo(q1.z), lat[11]);
                lat[12] = fmaf(w, bf_hi(q1.z), lat[12]);
                lat[13] = fmaf(w, bf_lo(q1.w), lat[13]);
                lat[14] = fmaf(w, bf_hi(q1.w), lat[14]);
                const float* np_ = normals + (size_t)vox * 3;
                na0 = fmaf(w, np_[0], na0);
                na1 = fmaf(w, np_[1], na1);
                na2 = fmaf(w, np_[2], na2);
            }

            const float c00 = c0v[0] * (1.f - fz) + c0v[1] * fz;
            const float c01 = c0v[2] * (1.f - fz) + c0v[3] * fz;
            const float c10 = c0v[4] * (1.f - fz) + c0v[5] * fz;
            const float c11 = c0v[6] * (1.f - fz) + c0v[7] * fz;
            const float e0 = c00 * (1.f - fy) + c01 * fy;
            const float e1 = c10 * (1.f - fy) + c11 * fy;
            const float d0 = e0 * (1.f - fx) + e1 * fx;
            const float dfx = e1 - e0;
            const float dfy = (c01 - c00) * (1.f - fx) + (c11 - c10) * fx;
            const float dfz = ((c0v[1] - c0v[0]) * (1.f - fy) + (c0v[3] - c0v[2]) * fy) * (1.f - fx)
                            + ((c0v[5] - c0v[4]) * (1.f - fy) + (c0v[7] - c0v[6]) * fy) * fx;

            const float zin = d0 + ACT_SHIFT;
            const float splus = fmaxf(zin, 0.f) + log1pf(__expf(-fabsf(zin)));
            const float e = __expf(-splus * 0.5f);
            alpha = 1.f - e;
            const float sig = 1.f / (1.f + __expf(-zin));
            const float dad = e * 0.5f * sig;
            const float gx = dad * dfx * 63.5f;
            const float gy = dad * dfy * 63.5f;
            const float gz = dad * dfz * 63.5f;
            const float gn = sqrtf(gx * gx + gy * gy + gz * gz);
            const float gi = 1.f / fmaxf(gn, 1e-12f);
            ndx = -gx * gi; ndy = -gy * gi; ndz = -gz * gi;

            const float nn = sqrtf(na0 * na0 + na1 * na1 + na2 * na2);
            const float ni = 1.f / fmaxf(nn, 1e-12f);
            nsx = -na0 * ni; nsy = -na1 * ni; nsz = -na2 * ni;

            const float dotv = -(vx * ndx + vy * ndy + vz * ndz);
            const float rx = 2.f * dotv * ndx + vx;
            const float ry = 2.f * dotv * ndy + vy;
            const float rz = 2.f * dotv * ndz + vz;

#pragma unroll
            for (int q = 0; q < 15; ++q) hf[q] = lat[q];
            hf[15] = rx; hf[16] = ry; hf[17] = rz;
#pragma unroll
            for (int fi = 0; fi < 6; ++fi) {
                const float fr = (float)(1 << fi);
                hf[18 + fi * 6 + 0] = __sinf(rx * fr);
                hf[18 + fi * 6 + 1] = __sinf(ry * fr);
                hf[18 + fi * 6 + 2] = __sinf(rz * fr);
                hf[18 + fi * 6 + 3] = __cosf(rx * fr);
                hf[18 + fi * 6 + 4] = __cosf(ry * fr);
                hf[18 + fi * 6 + 5] = __cosf(rz * fr);
            }
            depth = interpx * ndr;
        }
    }

#pragma unroll
    for (int q = 0; q < 8; ++q) {
        uint4 st;
        st.x = f2bf_u(hf[8 * q + 0]) | (f2bf_u(hf[8 * q + 1]) << 16);
        st.y = f2bf_u(hf[8 * q + 2]) | (f2bf_u(hf[8 * q + 3]) << 16);
        st.z = f2bf_u(hf[8 * q + 4]) | (f2bf_u(hf[8 * q + 5]) << 16);
        st.w = f2bf_u(hf[8 * q + 6]) | (f2bf_u(hf[8 * q + 7]) << 16);
        *(uint4*)(actA + t * 72 + 8 * q) = st;
    }
    __syncthreads();

    const int wv = t >> 6, lane = t & 63;
    mfma_layer(actA, actB, m0t, mb0, wv, lane);
    __syncthreads();
    mfma_layer(actB, actA, m1t, mb1, wv, lane);
    __syncthreads();
    mfma_layer(actA, actB, m2t, mb2, wv, lane);
    __syncthreads();

    if (live) {
        float* so = sbuf + (size_t)s * 12;
        if (act) {
            float r0 = mb3[0], r1 = mb3[1], r2 = mb3[2];
            const unsigned short* hr = actB + t * 72;
#pragma unroll
            for (int c8 = 0; c8 < 8; ++c8) {
                const uint4 hu = *(const uint4*)(hr + 8 * c8);
                const float h[8] = {bf_lo(hu.x), bf_hi(hu.x), bf_lo(hu.y), bf_hi(hu.y),
                                    bf_lo(hu.z), bf_hi(hu.z), bf_lo(hu.w), bf_hi(hu.w)};
#pragma unroll
                for (int u = 0; u < 8; ++u) {
                    const int c = 8 * c8 + u;
                    r0 = fmaf(h[u], mw3[c * 3 + 0], r0);
                    r1 = fmaf(h[u], mw3[c * 3 + 1], r1);
                    r2 = fmaf(h[u], mw3[c * 3 + 2], r2);
                }
            }
            so[0] = alpha;
            so[1] = 1.f / (1.f + __expf(-r0));
            so[2] = 1.f / (1.f + __expf(-r1));
            so[3] = 1.f / (1.f + __expf(-r2));
            so[4] = ndx; so[5] = ndy; so[6] = ndz;
            so[7] = nsx; so[8] = nsy; so[9] = nsz;
            so[10] = depth;
            so[11] = 0.f;
        } else {
#pragma unroll
            for (int q = 0; q < 12; ++q) so[q] = 0.f;
        }
    }
}

// ============================================================================
// Kernel 4: per-ray compositing (wave per ray; segmented product scan).
// ============================================================================
__global__ __launch_bounds__(64) void reduce_kernel(const float* __restrict__ sbuf,
                                                    float* __restrict__ out)
{
    const int r = blockIdx.x;
    const int lane = threadIdx.x;
    const int per = (S_SAMPLES + 63) / 64;   // 7
    const int j0 = lane * per;
    const int j1 = min(S_SAMPLES, j0 + per);

    float p = 1.f;
    for (int j = j0; j < j1; ++j) {
        const float a = sbuf[((size_t)r * S_SAMPLES + j) * 12];
        p *= fmaxf(1.f - a, 1e-10f);
    }
    float scan = p;
#pragma unroll
    for (int off = 1; off < 64; off <<= 1) {
        const float nv = __shfl_up(scan, (unsigned)off, 64);
        if (lane >= off) scan *= nv;
    }
    const float total = __shfl(scan, 63, 64);
    float pref = __shfl_up(scan, 1u, 64);
    if (lane == 0) pref = 1.f;

    float s0 = 0, s1 = 0, s2 = 0, s3 = 0, s4 = 0, s5 = 0, s6 = 0, s7 = 0, s8 = 0, s9 = 0, s10 = 0;
    for (int j = j0; j < j1; ++j) {
        const float* sp_ = sbuf + ((size_t)r * S_SAMPLES + j) * 12;
        const float a = sp_[0];
        const float w = a * pref;
        pref *= fmaxf(1.f - a, 1e-10f);
        s0 = fmaf(w, sp_[1], s0);
        s1 = fmaf(w, sp_[2], s1);
        s2 = fmaf(w, sp_[3], s2);
        s3 = fmaf(w, sp_[10], s3);
        s4 += w;
        s5 = fmaf(w, sp_[4], s5);
        s6 = fmaf(w, sp_[5], s6);
        s7 = fmaf(w, sp_[6], s7);
        s8 = fmaf(w, sp_[7], s8);
        s9 = fmaf(w, sp_[8], s9);
        s10 = fmaf(w, sp_[9], s10);
    }
#pragma unroll
    for (int m = 32; m >= 1; m >>= 1) {
        s0 += __shfl_xor(s0, m, 64);
        s1 += __shfl_xor(s1, m, 64);
        s2 += __shfl_xor(s2, m, 64);
        s3 += __shfl_xor(s3, m, 64);
        s4 += __shfl_xor(s4, m, 64);
        s5 += __shfl_xor(s5, m, 64);
        s6 += __shfl_xor(s6, m, 64);
        s7 += __shfl_xor(s7, m, 64);
        s8 += __shfl_xor(s8, m, 64);
        s9 += __shfl_xor(s9, m, 64);
        s10 += __shfl_xor(s10, m, 64);
    }
    if (lane == 0) {
        const float dm = s3 + total * 6.0f;
        out[r * 12 + 0] = s0 + total;
        out[r * 12 + 1] = s1 + total;
        out[r * 12 + 2] = s2 + total;
        out[r * 12 + 3] = dm;
        out[r * 12 + 4] = 1.f / dm;
        out[r * 12 + 5] = s4;
        out[r * 12 + 6] = s5; out[r * 12 + 7] = s6; out[r * 12 + 8] = s7;
        out[r * 12 + 9] = s8; out[r * 12 + 10] = s9; out[r * 12 + 11] = s10;
    }
}

// ============================================================================
extern "C" void kernel_launch(void* const* d_in, const int* in_sizes, int n_in,
                              void* d_out, int out_size, void* d_ws, size_t ws_size,
                              hipStream_t stream)
{
    (void)n_in; (void)out_size; (void)ws_size;
    const float* rays_o   = (const float*)d_in[0];
    const float* rays_d   = (const float*)d_in[1];
    const float* viewdirs = (const float*)d_in[2];
    const float* grid     = (const float*)d_in[3];
    const float* c1_w  = (const float*)d_in[4];
    const float* c1_b  = (const float*)d_in[5];
    const float* bn1_g = (const float*)d_in[6];
    const float* bn1_b = (const float*)d_in[7];
    const float* pr1_a = (const float*)d_in[8];
    const float* c2_w  = (const float*)d_in[9];
    const float* c2_b  = (const float*)d_in[10];
    const float* bn2_g = (const float*)d_in[11];
    const float* bn2_b = (const float*)d_in[12];
    const float* pr2_a = (const float*)d_in[13];
    const float* c3_w  = (const float*)d_in[14];
    const float* c3_b  = (const float*)d_in[15];
    const float* mw0 = (const float*)d_in[16];
    const float* mb0 = (const float*)d_in[17];
    const float* mw1 = (const float*)d_in[18];
    const float* mb1 = (const float*)d_in[19];
    const float* mw2 = (const float*)d_in[20];
    const float* mb2 = (const float*)d_in[21];
    const float* mw3 = (const float*)d_in[22];
    const float* mb3 = (const float*)d_in[23];

    const int N = in_sizes[0] / 3;   // 1024 rays
    const int total = N * S_SAMPLES;

    // ws layout (float units):
    // featb [0,16777216) | dens [16777216,18874368) |
    // normals [18874368,25165824) | zbuf f2 [25165824,29360128) |
    // cbuf f4 [29360128,37748736) | sbuf [39845888,45337600) | weights after
    float* wsf = (float*)d_ws;
    unsigned short* featb = (unsigned short*)wsf;
    float* dens    = wsf + (size_t)16777216;
    float* normals = wsf + (size_t)18874368;
    float2* zbuf   = (float2*)(wsf + (size_t)25165824);
    float4* cbuf   = (float4*)(wsf + (size_t)29360128);
    float* sbuf    = wsf + (size_t)39845888;
    float* b3p = wsf + (size_t)45337600;
    unsigned short* w1b = (unsigned short*)(wsf + (size_t)45337728);   // 2048 bf16
    unsigned short* w2b = (unsigned short*)(wsf + (size_t)45338752);   // 6144 bf16
    unsigned short* w3b = (unsigned short*)(wsf + (size_t)45341824);   // 20480 bf16
    unsigned short* m0t = (unsigned short*)(wsf + (size_t)45352064);
    unsigned short* m1t = (unsigned short*)(wsf + (size_t)45354112);
    unsigned short* m2t = (unsigned short*)(wsf + (size_t)45356160);

    prep_kernel<<<64, 256, 0, stream>>>(c1_w, c2_w, c3_w, c3_b, mw0, mw1, mw2,
                                        w1b, w2b, w3b, b3p, m0t, m1t, m2t);
    conv_fused_kernel<<<4096, 128, 0, stream>>>(grid, w1b, c1_b, bn1_g, bn1_b, pr1_a,
                                                w2b, c2_b, bn2_g, bn2_b, pr2_a,
                                                w3b, b3p, featb, dens);
    sobelZ_kernel<<<8192, 256, 0, stream>>>(dens, zbuf);
    sobelY_kernel<<<8192, 256, 0, stream>>>(zbuf, cbuf);
    sobelX_kernel<<<8192, 256, 0, stream>>>(cbuf, normals);
    const int sblocks = (total + 127) / 128;
    sample_kernel<<<sblocks, 128, 0, stream>>>(rays_o, rays_d, viewdirs, featb, dens, normals,
                                               m0t, mb0, m1t, mb1, m2t, mb2, mw3, mb3,
                                               sbuf, total);
    reduce_kernel<<<N, 64, 0, stream>>>(sbuf, (float*)d_out);
}